// Round 1
// baseline (539.031 us; speedup 1.0000x reference)
//
#include <hip/hip_runtime.h>
#include <math.h>

#define B_ 8
#define C_ 64
#define H_ 256
#define W_ 256
#define WF 129
#define P_ (B_*C_)      // 512 planes
#define PI_F 3.14159265358979323846f

__device__ __forceinline__ unsigned rev8(unsigned x){ return __brev(x) >> 24u; }

// ---------------------------------------------------------------------------
// K1: row rfft (two-for-one). grid (P_, H_/16), block 256.
// Reads x[p][h0..h0+16][0..255]; writes S[p][kw][h] (transposed), scaled 1/256.
// ---------------------------------------------------------------------------
__global__ void k1_row_rfft(const float* __restrict__ x, float2* __restrict__ S){
    __shared__ float zr[8][256], zi[8][256];
    __shared__ float twc[128], tws[128];
    __shared__ float obr[WF][17], obi[WF][17];

    const int p = blockIdx.x, tile = blockIdx.y, t = threadIdx.x;
    const int h0 = tile * 16;
    const float* xp = x + (size_t)p*H_*W_ + (size_t)h0*W_;

    if (t < 128){
        float sv, cv; sincosf(-PI_F * (float)t / 128.f, &sv, &cv);
        twc[t] = cv; tws[t] = sv;
    }
    const unsigned br = rev8((unsigned)t);
    #pragma unroll
    for (int r = 0; r < 16; ++r){
        float v = xp[r*W_ + t];
        if (r & 1) zi[r>>1][br] = v; else zr[r>>1][br] = v;
    }
    __syncthreads();

    const int q = t >> 5, l = t & 31;
    for (int s = 0; s < 8; ++s){
        const int half = 1 << s;
        #pragma unroll
        for (int it = 0; it < 4; ++it){
            int b = l + 32*it;
            int j = b & (half-1);
            int i = ((b >> s) << (s+1)) + j;
            int k = j << (7 - s);
            float wr = twc[k], wi = tws[k];
            float ur = zr[q][i],      ui = zi[q][i];
            float vr = zr[q][i+half], vi = zi[q][i+half];
            float tr = vr*wr - vi*wi, ti = vr*wi + vi*wr;
            zr[q][i]      = ur + tr;  zi[q][i]      = ui + ti;
            zr[q][i+half] = ur - tr;  zi[q][i+half] = ui - ti;
        }
        __syncthreads();
    }

    // unpack: A = rfft(row 2q), B = rfft(row 2q+1); fold ortho forward 1/256
    const float sc = 0.5f / 256.f;
    for (int kw = l; kw < WF; kw += 32){
        int km = (256 - kw) & 255;
        float Zr = zr[q][kw], Zi = zi[q][kw];
        float Yr = zr[q][km], Yi = zi[q][km];
        obr[kw][2*q]   = sc*(Zr + Yr);
        obi[kw][2*q]   = sc*(Zi - Yi);
        obr[kw][2*q+1] = sc*(Zi + Yi);
        obi[kw][2*q+1] = sc*(Yr - Zr);
    }
    __syncthreads();

    float2* Sp = S + (size_t)p*WF*H_;
    for (int idx = t; idx < WF*16; idx += 256){
        int kw = idx >> 4, hh = idx & 15;
        Sp[(size_t)kw*H_ + h0 + hh] = make_float2(obr[kw][hh], obi[kw][hh]);
    }
}

// ---------------------------------------------------------------------------
// K2/K4: complex FFT along h, in-place on S. grid (P_, 9), block 256.
// INVERSE=false: forward (no scale). INVERSE=true: unnormalized inverse.
// WEIGHT=true: multiply (1 + Wgt) on load.
// ---------------------------------------------------------------------------
template<bool INVERSE, bool WEIGHT>
__global__ void k_col_fft(float2* __restrict__ S, const float* __restrict__ Wgt){
    __shared__ float zr[16][256], zi[16][256];
    __shared__ float twc[128], tws[128];

    const int p = blockIdx.x, tile = blockIdx.y, t = threadIdx.x;
    const int kw0 = tile * 16;
    const int nl = min(16, WF - kw0);
    float2* Sp = S + ((size_t)p*WF + kw0) * (size_t)H_;

    if (t < 128){
        float sv, cv;
        sincosf((INVERSE ? PI_F : -PI_F) * (float)t / 128.f, &sv, &cv);
        twc[t] = cv; tws[t] = sv;
    }
    for (int idx = t; idx < nl*256; idx += 256){
        int ln = idx >> 8, h = idx & 255;
        float2 v = Sp[(size_t)ln*H_ + h];
        float g = 1.f;
        if (WEIGHT) g = 1.f + Wgt[((size_t)p*WF + kw0 + ln)*H_ + h];
        unsigned bh = rev8((unsigned)h);
        zr[ln][bh] = v.x * g; zi[ln][bh] = v.y * g;
    }
    __syncthreads();

    for (int s = 0; s < 8; ++s){
        const int half = 1 << s;
        for (int idx = t; idx < nl*128; idx += 256){
            int ln = idx >> 7, b = idx & 127;
            int j = b & (half-1);
            int i = ((b >> s) << (s+1)) + j;
            int k = j << (7 - s);
            float wr = twc[k], wi = tws[k];
            float ur = zr[ln][i],      ui = zi[ln][i];
            float vr = zr[ln][i+half], vi = zi[ln][i+half];
            float tr = vr*wr - vi*wi,  ti = vr*wi + vi*wr;
            zr[ln][i]      = ur + tr;  zi[ln][i]      = ui + ti;
            zr[ln][i+half] = ur - tr;  zi[ln][i+half] = ui - ti;
        }
        __syncthreads();
    }
    for (int idx = t; idx < nl*256; idx += 256){
        int ln = idx >> 8, h = idx & 255;
        Sp[(size_t)ln*H_ + h] = make_float2(zr[ln][h], zi[ln][h]);
    }
}

// ---------------------------------------------------------------------------
// K3: freq weights = sigmoid(depthwise_conv1d(|S|, K=5, pad=2 over flat h*129+kw)).
// grid (P_, WF), block 256 (thread = h). Wgt[p][kw][h].
// ---------------------------------------------------------------------------
__global__ void k3_weights(const float2* __restrict__ S, const float* __restrict__ fw,
                           const float* __restrict__ fb, float* __restrict__ Wgt){
    const int p = blockIdx.x, kw = blockIdx.y, h = threadIdx.x;
    const int c = p & (C_-1);
    const float2* Sp = S + (size_t)p*WF*H_;

    float acc = fb[c];
    #pragma unroll
    for (int d = -2; d <= 2; ++d){
        int w2 = kw + d, h2 = h;
        if (w2 < 0)        { w2 += WF; h2 -= 1; }
        else if (w2 >= WF) { w2 -= WF; h2 += 1; }
        if (h2 >= 0 && h2 < H_){
            float2 v = Sp[(size_t)w2*H_ + h2];
            acc += sqrtf(v.x*v.x + v.y*v.y) * fw[c*5 + d + 2];
        }
    }
    float sg = 1.f / (1.f + __expf(-acc));
    Wgt[((size_t)p*WF + kw)*H_ + h] = sg;
}

// ---------------------------------------------------------------------------
// K5: inverse row transform (Hermitian two-for-one), writes enh into d_out.
// grid (P_, H_/16), block 256. Folds inverse ortho 1/256.
// ---------------------------------------------------------------------------
__global__ void k5_irow(const float2* __restrict__ S, float* __restrict__ out){
    __shared__ float sr[WF][17], si[WF][17];
    __shared__ float zr[8][256], zi[8][256];
    __shared__ float twc[128], tws[128];

    const int p = blockIdx.x, tile = blockIdx.y, t = threadIdx.x;
    const int h0 = tile * 16;
    const float2* Sp = S + (size_t)p*WF*H_;

    if (t < 128){
        float sv, cv; sincosf(PI_F * (float)t / 128.f, &sv, &cv);
        twc[t] = cv; tws[t] = sv;
    }
    for (int idx = t; idx < WF*16; idx += 256){
        int kw = idx >> 4, hh = idx & 15;
        float2 v = Sp[(size_t)kw*H_ + h0 + hh];
        sr[kw][hh] = v.x; si[kw][hh] = v.y;
    }
    __syncthreads();

    const int q = t >> 5, l = t & 31;
    #pragma unroll
    for (int it = 0; it < 8; ++it){
        int k = l + 32*it;
        float Ar, Ai, Br2, Bi;
        if (k <= 128){
            Ar = sr[k][2*q];  Ai = si[k][2*q];
            Br2 = sr[k][2*q+1]; Bi = si[k][2*q+1];
        } else {
            int kk = 256 - k;
            Ar = sr[kk][2*q];  Ai = -si[kk][2*q];
            Br2 = sr[kk][2*q+1]; Bi = -si[kk][2*q+1];
        }
        unsigned bk = rev8((unsigned)k);
        zr[q][bk] = Ar - Bi;   // Re(A + iB)
        zi[q][bk] = Ai + Br2;  // Im(A + iB)
    }
    __syncthreads();

    for (int s = 0; s < 8; ++s){
        const int half = 1 << s;
        #pragma unroll
        for (int it = 0; it < 4; ++it){
            int b = l + 32*it;
            int j = b & (half-1);
            int i = ((b >> s) << (s+1)) + j;
            int k = j << (7 - s);
            float wr = twc[k], wi = tws[k];
            float ur = zr[q][i],      ui = zi[q][i];
            float vr = zr[q][i+half], vi = zi[q][i+half];
            float tr = vr*wr - vi*wi, ti = vr*wi + vi*wr;
            zr[q][i]      = ur + tr;  zi[q][i]      = ui + ti;
            zr[q][i+half] = ur - tr;  zi[q][i+half] = ui - ti;
        }
        __syncthreads();
    }

    const float inv = 1.f / 256.f;
    float* op = out + (size_t)p*H_*W_ + (size_t)h0*W_;
    #pragma unroll
    for (int r = 0; r < 16; ++r){
        float v = (r & 1) ? zi[r>>1][t] : zr[r>>1][t];
        op[r*W_ + t] = v * inv;
    }
}

// ---------------------------------------------------------------------------
// K6: out = x + scale * (mix_w @ enh), in-place on d_out (enh lives there).
// grid (B_, H_*W_/128), block 256. Stages its own tile in LDS first -> race-free.
// ---------------------------------------------------------------------------
__global__ void k6_mix(const float* __restrict__ x, const float* __restrict__ mixw,
                       const float* __restrict__ scale, float* __restrict__ out){
    __shared__ float Ml[64][64];       // Ml[c][o] = mix_w[o][c]
    __shared__ float tile[64][129];    // tile[c][pix], padded

    const int b = blockIdx.x, pt = blockIdx.y, t = threadIdx.x;
    const int pix0 = pt * 128;
    float* op = out + (size_t)b*C_*H_*W_;
    const float* xp = x + (size_t)b*C_*H_*W_;

    for (int idx = t; idx < 64*64; idx += 256){
        int o = idx >> 6, c = idx & 63;
        Ml[c][o] = mixw[idx];
    }
    for (int idx = t; idx < 64*128; idx += 256){
        int c = idx >> 7, pp = idx & 127;
        tile[c][pp] = op[(size_t)c*H_*W_ + pix0 + pp];
    }
    __syncthreads();

    const int pp = t & 127, oh = t >> 7;  // oh in {0,1}
    float acc[32];
    #pragma unroll
    for (int i = 0; i < 32; ++i) acc[i] = 0.f;
    for (int c = 0; c < 64; ++c){
        float v = tile[c][pp];
        #pragma unroll
        for (int i = 0; i < 32; ++i) acc[i] += Ml[c][oh*32 + i] * v;
    }
    const float sc = scale[0];
    #pragma unroll
    for (int i = 0; i < 32; ++i){
        int o = oh*32 + i;
        size_t ix = (size_t)o*H_*W_ + pix0 + pp;
        op[ix] = xp[ix] + sc * acc[i];
    }
}

// ---------------------------------------------------------------------------
extern "C" void kernel_launch(void* const* d_in, const int* in_sizes, int n_in,
                              void* d_out, int out_size, void* d_ws, size_t ws_size,
                              hipStream_t stream){
    const float* x    = (const float*)d_in[0];
    const float* fw   = (const float*)d_in[1];
    const float* fb   = (const float*)d_in[2];
    const float* mixw = (const float*)d_in[3];
    const float* scal = (const float*)d_in[4];
    float* out = (float*)d_out;

    // ws layout: S (float2, P*WF*H) then Wgt (float, P*WF*H) ~= 194 MiB total
    float2* S  = (float2*)d_ws;
    float* Wgt = (float*)((char*)d_ws + (size_t)P_*WF*H_*sizeof(float2));

    dim3 blk(256);
    k1_row_rfft            <<<dim3(P_, H_/16),     blk, 0, stream>>>(x, S);
    k_col_fft<false,false> <<<dim3(P_, 9),         blk, 0, stream>>>(S, nullptr);
    k3_weights             <<<dim3(P_, WF),        blk, 0, stream>>>(S, fw, fb, Wgt);
    k_col_fft<true, true>  <<<dim3(P_, 9),         blk, 0, stream>>>(S, Wgt);
    k5_irow                <<<dim3(P_, H_/16),     blk, 0, stream>>>(S, out);
    k6_mix                 <<<dim3(B_, H_*W_/128), blk, 0, stream>>>(x, mixw, scal, out);
}

// Round 3
// 527.997 us; speedup vs baseline: 1.0209x; 1.0209x over previous
//
#include <hip/hip_runtime.h>
#include <math.h>

#define B_ 8
#define C_ 64
#define H_ 256
#define W_ 256
#define WF 129
#define P_ (B_*C_)      // 512 planes
#define PI_F 3.14159265358979323846f

__device__ __forceinline__ unsigned rev8(unsigned x){ return __brev(x) >> 24u; }
__device__ __forceinline__ bool halo_needed(int kw){
    int m = kw & 15; return (m < 2) || (m > 13);
}

// ---------------------------------------------------------------------------
// K1: row rfft (two-for-one). grid (P_, H_/16), block 256.
// Reads x[p][h0..h0+16][0..255]; writes S[p][kw][h] (transposed), scaled 1/256.
// ---------------------------------------------------------------------------
__global__ void k1_row_rfft(const float* __restrict__ x, float2* __restrict__ S){
    __shared__ float zr[8][256], zi[8][256];
    __shared__ float twc[128], tws[128];
    __shared__ float obr[WF][17], obi[WF][17];

    const int p = blockIdx.x, tile = blockIdx.y, t = threadIdx.x;
    const int h0 = tile * 16;
    const float* xp = x + (size_t)p*H_*W_ + (size_t)h0*W_;

    if (t < 128){
        float sv, cv; sincosf(-PI_F * (float)t / 128.f, &sv, &cv);
        twc[t] = cv; tws[t] = sv;
    }
    const unsigned br = rev8((unsigned)t);
    #pragma unroll
    for (int r = 0; r < 16; ++r){
        float v = xp[r*W_ + t];
        if (r & 1) zi[r>>1][br] = v; else zr[r>>1][br] = v;
    }
    __syncthreads();

    const int q = t >> 5, l = t & 31;
    for (int s = 0; s < 8; ++s){
        const int half = 1 << s;
        #pragma unroll
        for (int it = 0; it < 4; ++it){
            int b = l + 32*it;
            int j = b & (half-1);
            int i = ((b >> s) << (s+1)) + j;
            int k = j << (7 - s);
            float wr = twc[k], wi = tws[k];
            float ur = zr[q][i],      ui = zi[q][i];
            float vr = zr[q][i+half], vi = zi[q][i+half];
            float tr = vr*wr - vi*wi, ti = vr*wi + vi*wr;
            zr[q][i]      = ur + tr;  zi[q][i]      = ui + ti;
            zr[q][i+half] = ur - tr;  zi[q][i+half] = ui - ti;
        }
        __syncthreads();
    }

    // unpack: A = rfft(row 2q), B = rfft(row 2q+1); fold ortho forward 1/256
    const float sc = 0.5f / 256.f;
    for (int kw = l; kw < WF; kw += 32){
        int km = (256 - kw) & 255;
        float Zr = zr[q][kw], Zi = zi[q][kw];
        float Yr = zr[q][km], Yi = zi[q][km];
        obr[kw][2*q]   = sc*(Zr + Yr);
        obi[kw][2*q]   = sc*(Zi - Yi);
        obr[kw][2*q+1] = sc*(Zi + Yi);
        obi[kw][2*q+1] = sc*(Yr - Zr);
    }
    __syncthreads();

    float2* Sp = S + (size_t)p*WF*H_;
    for (int idx = t; idx < WF*16; idx += 256){
        int kw = idx >> 4, hh = idx & 15;
        Sp[(size_t)kw*H_ + h0 + hh] = make_float2(obr[kw][hh], obi[kw][hh]);
    }
}

// ---------------------------------------------------------------------------
// K2a: forward col-FFT along h, in-place on S (own lines only -> race-free).
// Also writes |mag| to Mg for boundary lines that serve as conv halos.
// grid (P_, 9), block 256.
// ---------------------------------------------------------------------------
__global__ void k2a_fwd(float2* __restrict__ S, float* __restrict__ Mg){
    __shared__ float zr[16][256], zi[16][256];
    __shared__ float twc[128], tws[128];

    const int p = blockIdx.x, tile = blockIdx.y, t = threadIdx.x;
    const int kw0 = tile * 16;
    const int nl = min(16, WF - kw0);
    float2* Sp = S + ((size_t)p*WF + kw0) * (size_t)H_;

    if (t < 128){
        float sv, cv; sincosf(-PI_F * (float)t / 128.f, &sv, &cv);
        twc[t] = cv; tws[t] = sv;
    }
    for (int idx = t; idx < nl*256; idx += 256){
        int ln = idx >> 8, h = idx & 255;
        float2 v = Sp[(size_t)ln*H_ + h];
        unsigned bh = rev8((unsigned)h);
        zr[ln][bh] = v.x; zi[ln][bh] = v.y;
    }
    __syncthreads();

    for (int s = 0; s < 8; ++s){
        const int half = 1 << s;
        for (int idx = t; idx < nl*128; idx += 256){
            int ln = idx >> 7, b = idx & 127;
            int j = b & (half-1);
            int i = ((b >> s) << (s+1)) + j;
            int k = j << (7 - s);
            float wr = twc[k], wi = tws[k];
            float ur = zr[ln][i],      ui = zi[ln][i];
            float vr = zr[ln][i+half], vi = zi[ln][i+half];
            float tr = vr*wr - vi*wi,  ti = vr*wi + vi*wr;
            zr[ln][i]      = ur + tr;  zi[ln][i]      = ui + ti;
            zr[ln][i+half] = ur - tr;  zi[ln][i+half] = ui - ti;
        }
        __syncthreads();
    }
    for (int idx = t; idx < nl*256; idx += 256){
        int ln = idx >> 8, h = idx & 255;
        float vr = zr[ln][h], vi = zi[ln][h];
        Sp[(size_t)ln*H_ + h] = make_float2(vr, vi);
        int kw = kw0 + ln;
        if (halo_needed(kw))
            Mg[((size_t)p*WF + kw)*H_ + h] = sqrtf(vr*vr + vi*vi);
    }
}

// ---------------------------------------------------------------------------
// K2b: mag + depthwise-conv(K=5 over flat h*129+kw) + sigmoid weighting +
//      inverse col-FFT (DIF: natural in, bitrev out), in-place on S.
// Own lines read from S; halo mags read from Mg (read-only) -> race-free.
// grid (P_, 9), block 256.
// ---------------------------------------------------------------------------
__global__ void k2b_inv(float2* __restrict__ S, const float* __restrict__ Mg,
                        const float* __restrict__ fw, const float* __restrict__ fb){
    __shared__ float zr[16][256], zi[16][256];   // 32 KB
    __shared__ float mag[20][256];               // 20 KB
    __shared__ float twc[128], tws[128];
    __shared__ float cw[5];
    __shared__ float cb;

    const int p = blockIdx.x, tile = blockIdx.y, t = threadIdx.x;
    const int kw0 = tile * 16;
    const int nl = min(16, WF - kw0);            // 16 (tiles 0..7) or 1 (tile 8)
    const int c = p & (C_-1);
    float2* Sp = S + (size_t)p*WF*H_;

    if (t < 128){
        float sv, cv; sincosf(-PI_F * (float)t / 128.f, &sv, &cv);
        twc[t] = cv; tws[t] = sv;   // forward table; inverse flips wi sign
    }
    if (t < 5)  cw[t] = fw[c*5 + t];
    if (t == 5) cb = fb[c];

    // halo mag lines: kwa = kw0-2, kw0-1, kw0+nl, kw0+nl+1 (wrap mod 129)
    for (int idx = t; idx < 4*256; idx += 256){
        int ln = idx >> 8, h = idx & 255;
        int kwa = (ln < 2) ? (kw0 - 2 + ln) : (kw0 + nl + ln - 2);
        int phys = kwa < 0 ? kwa + WF : (kwa > 128 ? kwa - WF : kwa);
        int L = (ln < 2) ? ln : (nl + ln);       // 0,1,nl+2,nl+3
        mag[L][h] = Mg[((size_t)p*WF + phys)*H_ + h];
    }
    // own lines: natural-order load (already spectrum), mag rows 2..nl+1
    for (int idx = t; idx < nl*256; idx += 256){
        int ln = idx >> 8, h = idx & 255;
        float2 v = Sp[(size_t)(kw0+ln)*H_ + h];
        zr[ln][h] = v.x; zi[ln][h] = v.y;
        mag[2+ln][h] = sqrtf(v.x*v.x + v.y*v.y);
    }
    __syncthreads();

    // conv(K=5) + sigmoid -> weight owned complex values in place
    for (int idx = t; idx < nl*256; idx += 256){
        int ln = idx >> 8, h = idx & 255;
        int kw = kw0 + ln;
        float acc = cb;
        #pragma unroll
        for (int d = 0; d < 5; ++d){
            int kwa = kw + d - 2;
            int L = ln + d;                      // mag row for this tap
            int sh = (kwa < 0) ? -1 : (kwa > 128 ? 1 : 0);
            int h2 = h + sh;
            if (h2 >= 0 && h2 < H_) acc += mag[L][h2] * cw[d];
        }
        float g = 1.f + 1.f/(1.f + __expf(-acc));
        zr[ln][h] *= g; zi[ln][h] *= g;
    }
    __syncthreads();

    // inverse FFT: DIF, natural in -> bitrev out (conj twiddles)
    for (int s = 7; s >= 0; --s){
        const int half = 1 << s;
        for (int idx = t; idx < nl*128; idx += 256){
            int ln = idx >> 7, b = idx & 127;
            int j = b & (half-1);
            int i = ((b >> s) << (s+1)) + j;
            int k = j << (7 - s);
            float wr = twc[k], wi = -tws[k];     // inverse sign
            float ur = zr[ln][i],      ui = zi[ln][i];
            float vr = zr[ln][i+half], vi = zi[ln][i+half];
            zr[ln][i]      = ur + vr;  zi[ln][i]      = ui + vi;
            float tr = ur - vr,        ti = ui - vi;
            zr[ln][i+half] = tr*wr - ti*wi;
            zi[ln][i+half] = tr*wi + ti*wr;
        }
        __syncthreads();
    }
    // store: X[h] = z[rev8(h)]
    for (int idx = t; idx < nl*256; idx += 256){
        int ln = idx >> 8, h = idx & 255;
        unsigned hb = rev8((unsigned)h);
        Sp[(size_t)(kw0+ln)*H_ + h] = make_float2(zr[ln][hb], zi[ln][hb]);
    }
}

// ---------------------------------------------------------------------------
// K5: inverse row transform (Hermitian two-for-one), writes enh into d_out.
// grid (P_, H_/16), block 256. Folds inverse ortho 1/256.
// ---------------------------------------------------------------------------
__global__ void k5_irow(const float2* __restrict__ S, float* __restrict__ out){
    __shared__ float sr[WF][17], si[WF][17];
    __shared__ float zr[8][256], zi[8][256];
    __shared__ float twc[128], tws[128];

    const int p = blockIdx.x, tile = blockIdx.y, t = threadIdx.x;
    const int h0 = tile * 16;
    const float2* Sp = S + (size_t)p*WF*H_;

    if (t < 128){
        float sv, cv; sincosf(PI_F * (float)t / 128.f, &sv, &cv);
        twc[t] = cv; tws[t] = sv;
    }
    for (int idx = t; idx < WF*16; idx += 256){
        int kw = idx >> 4, hh = idx & 15;
        float2 v = Sp[(size_t)kw*H_ + h0 + hh];
        sr[kw][hh] = v.x; si[kw][hh] = v.y;
    }
    __syncthreads();

    const int q = t >> 5, l = t & 31;
    #pragma unroll
    for (int it = 0; it < 8; ++it){
        int k = l + 32*it;
        float Ar, Ai, Br2, Bi;
        if (k <= 128){
            Ar = sr[k][2*q];  Ai = si[k][2*q];
            Br2 = sr[k][2*q+1]; Bi = si[k][2*q+1];
        } else {
            int kk = 256 - k;
            Ar = sr[kk][2*q];  Ai = -si[kk][2*q];
            Br2 = sr[kk][2*q+1]; Bi = -si[kk][2*q+1];
        }
        unsigned bk = rev8((unsigned)k);
        zr[q][bk] = Ar - Bi;   // Re(A + iB)
        zi[q][bk] = Ai + Br2;  // Im(A + iB)
    }
    __syncthreads();

    for (int s = 0; s < 8; ++s){
        const int half = 1 << s;
        #pragma unroll
        for (int it = 0; it < 4; ++it){
            int b = l + 32*it;
            int j = b & (half-1);
            int i = ((b >> s) << (s+1)) + j;
            int k = j << (7 - s);
            float wr = twc[k], wi = tws[k];
            float ur = zr[q][i],      ui = zi[q][i];
            float vr = zr[q][i+half], vi = zi[q][i+half];
            float tr = vr*wr - vi*wi, ti = vr*wi + vi*wr;
            zr[q][i]      = ur + tr;  zi[q][i]      = ui + ti;
            zr[q][i+half] = ur - tr;  zi[q][i+half] = ui - ti;
        }
        __syncthreads();
    }

    const float inv = 1.f / 256.f;
    float* op = out + (size_t)p*H_*W_ + (size_t)h0*W_;
    #pragma unroll
    for (int r = 0; r < 16; ++r){
        float v = (r & 1) ? zi[r>>1][t] : zr[r>>1][t];
        op[r*W_ + t] = v * inv;
    }
}

// ---------------------------------------------------------------------------
// K6: out = x + scale * (mix_w @ enh), in-place on d_out (enh lives there).
// grid (B_, 256), block 256. Thread owns ONE pixel, all 64 outputs in regs.
// Thread-private read/write columns -> race-free in-place.
// ---------------------------------------------------------------------------
__global__ void k6_mix(const float* __restrict__ x, const float* __restrict__ mixw,
                       const float* __restrict__ scale, float* __restrict__ out){
    __shared__ float Ml[64*64];        // Ml[c*64+o] = mix_w[o][c]

    const int b = blockIdx.x, pt = blockIdx.y, t = threadIdx.x;
    const int pix = pt * 256 + t;
    float* op = out + (size_t)b*C_*H_*W_;
    const float* xp = x + (size_t)b*C_*H_*W_;

    for (int idx = t; idx < 64*64; idx += 256){
        int c = idx >> 6, o = idx & 63;
        Ml[idx] = mixw[o*64 + c];
    }
    __syncthreads();

    float acc[64];
    #pragma unroll
    for (int o = 0; o < 64; ++o) acc[o] = 0.f;

    for (int c = 0; c < 64; ++c){
        float v = op[(size_t)c*H_*W_ + pix];           // coalesced, read once
        const float4* Mr = (const float4*)&Ml[c*64];   // broadcast rows
        #pragma unroll
        for (int o4 = 0; o4 < 16; ++o4){
            float4 m = Mr[o4];
            acc[o4*4+0] += m.x * v;
            acc[o4*4+1] += m.y * v;
            acc[o4*4+2] += m.z * v;
            acc[o4*4+3] += m.w * v;
        }
    }
    const float sc = scale[0];
    #pragma unroll
    for (int o = 0; o < 64; ++o){
        size_t ix = (size_t)o*H_*W_ + pix;
        op[ix] = xp[ix] + sc * acc[o];
    }
}

// ---------------------------------------------------------------------------
extern "C" void kernel_launch(void* const* d_in, const int* in_sizes, int n_in,
                              void* d_out, int out_size, void* d_ws, size_t ws_size,
                              hipStream_t stream){
    const float* x    = (const float*)d_in[0];
    const float* fw   = (const float*)d_in[1];
    const float* fb   = (const float*)d_in[2];
    const float* mixw = (const float*)d_in[3];
    const float* scal = (const float*)d_in[4];
    float* out = (float*)d_out;

    // ws: S (float2 P*WF*H = 135MB) + Mg (float P*WF*H slot = 68MB) = 203MB
    float2* S  = (float2*)d_ws;
    float*  Mg = (float*)((char*)d_ws + (size_t)P_*WF*H_*sizeof(float2));

    dim3 blk(256);
    k1_row_rfft <<<dim3(P_, H_/16), blk, 0, stream>>>(x, S);
    k2a_fwd     <<<dim3(P_, 9),     blk, 0, stream>>>(S, Mg);
    k2b_inv     <<<dim3(P_, 9),     blk, 0, stream>>>(S, Mg, fw, fb);
    k5_irow     <<<dim3(P_, H_/16), blk, 0, stream>>>(S, out);
    k6_mix      <<<dim3(B_, 256),   blk, 0, stream>>>(x, mixw, scal, out);
}

// Round 4
// 484.398 us; speedup vs baseline: 1.1128x; 1.0900x over previous
//
#include <hip/hip_runtime.h>
#include <math.h>

#define B_ 8
#define C_ 64
#define H_ 256
#define W_ 256
#define WF 129
#define P_ (B_*C_)      // 512 planes
#define PI_F 3.14159265358979323846f

__device__ __forceinline__ unsigned rev8(unsigned x){ return __brev(x) >> 24u; }

// ---------------------------------------------------------------------------
// K1: row rfft (two-for-one). grid (P_, H_/16), block 256.
// Reads x[p][h0..h0+16][0..255]; writes S[p][kw][h] (transposed), scaled 1/256.
// ---------------------------------------------------------------------------
__global__ void k1_row_rfft(const float* __restrict__ x, float2* __restrict__ S){
    __shared__ float zr[8][256], zi[8][256];
    __shared__ float twc[128], tws[128];
    __shared__ float obr[WF][17], obi[WF][17];

    const int p = blockIdx.x, tile = blockIdx.y, t = threadIdx.x;
    const int h0 = tile * 16;
    const float* xp = x + (size_t)p*H_*W_ + (size_t)h0*W_;

    if (t < 128){
        float sv, cv; sincosf(-PI_F * (float)t / 128.f, &sv, &cv);
        twc[t] = cv; tws[t] = sv;
    }
    const unsigned br = rev8((unsigned)t);
    #pragma unroll
    for (int r = 0; r < 16; ++r){
        float v = xp[r*W_ + t];
        if (r & 1) zi[r>>1][br] = v; else zr[r>>1][br] = v;
    }
    __syncthreads();

    const int q = t >> 5, l = t & 31;
    for (int s = 0; s < 8; ++s){
        const int half = 1 << s;
        #pragma unroll
        for (int it = 0; it < 4; ++it){
            int b = l + 32*it;
            int j = b & (half-1);
            int i = ((b >> s) << (s+1)) + j;
            int k = j << (7 - s);
            float wr = twc[k], wi = tws[k];
            float ur = zr[q][i],      ui = zi[q][i];
            float vr = zr[q][i+half], vi = zi[q][i+half];
            float tr = vr*wr - vi*wi, ti = vr*wi + vi*wr;
            zr[q][i]      = ur + tr;  zi[q][i]      = ui + ti;
            zr[q][i+half] = ur - tr;  zi[q][i+half] = ui - ti;
        }
        __syncthreads();
    }

    // unpack: A = rfft(row 2q), B = rfft(row 2q+1); fold ortho forward 1/256
    const float sc = 0.5f / 256.f;
    for (int kw = l; kw < WF; kw += 32){
        int km = (256 - kw) & 255;
        float Zr = zr[q][kw], Zi = zi[q][kw];
        float Yr = zr[q][km], Yi = zi[q][km];
        obr[kw][2*q]   = sc*(Zr + Yr);
        obi[kw][2*q]   = sc*(Zi - Yi);
        obr[kw][2*q+1] = sc*(Zi + Yi);
        obi[kw][2*q+1] = sc*(Yr - Zr);
    }
    __syncthreads();

    float2* Sp = S + (size_t)p*WF*H_;
    for (int idx = t; idx < WF*16; idx += 256){
        int kw = idx >> 4, hh = idx & 15;
        Sp[(size_t)kw*H_ + h0 + hh] = make_float2(obr[kw][hh], obi[kw][hh]);
    }
}

// ---------------------------------------------------------------------------
// K2F: fused col-FFT + mag + depthwise-conv(K=5 over flat h*129+kw) + sigmoid
//      weighting + inverse col-FFT (DIF: natural in, bitrev out).
// Reads S (k1 output) ONLY; writes kw<128 lines to D (d_out as float2) and
// the kw=128 line to Sx. No block reads another block's writes -> race-free.
// Halo mags come from 4 redundant forward line-FFTs (25% extra FFT compute).
// grid (P_, 9), block 256.
// ---------------------------------------------------------------------------
__global__ void k2f_fused(const float2* __restrict__ S, float2* __restrict__ D,
                          float2* __restrict__ Sx, const float* __restrict__ fw,
                          const float* __restrict__ fb){
    __shared__ float zr[16][256], zi[16][256];   // 32 KB
    __shared__ _Float16 mag[20][256];            // 10 KB
    __shared__ float twc[128], tws[128];
    __shared__ float cw[5];
    __shared__ float cb;

    const int p = blockIdx.x, tile = blockIdx.y, t = threadIdx.x;
    const int kw0 = tile * 16;
    const int nl = min(16, WF - kw0);            // 16 (tiles 0..7) or 1 (tile 8)
    const int c = p & (C_-1);
    const float2* Sp = S + (size_t)p*WF*H_;

    if (t < 128){
        float sv, cv; sincosf(-PI_F * (float)t / 128.f, &sv, &cv);
        twc[t] = cv; tws[t] = sv;   // forward table; inverse flips wi sign
    }
    if (t < 5)  cw[t] = fw[c*5 + t];
    if (t == 5) cb = fb[c];

    // ---- pass A: 4 halo lines -> mag rows 0,1,nl+2,nl+3 ----
    for (int idx = t; idx < 4*256; idx += 256){
        int ln = idx >> 8, h = idx & 255;
        int kwa = (ln < 2) ? (kw0 - 2 + ln) : (kw0 + nl + ln - 2);
        int phys = kwa < 0 ? kwa + WF : (kwa > 128 ? kwa - WF : kwa);
        float2 v = Sp[(size_t)phys*H_ + h];
        unsigned bh = rev8((unsigned)h);
        zr[ln][bh] = v.x; zi[ln][bh] = v.y;
    }
    __syncthreads();
    for (int s = 0; s < 8; ++s){
        const int half = 1 << s;
        for (int idx = t; idx < 4*128; idx += 256){
            int ln = idx >> 7, b = idx & 127;
            int j = b & (half-1);
            int i = ((b >> s) << (s+1)) + j;
            int k = j << (7 - s);
            float wr = twc[k], wi = tws[k];
            float ur = zr[ln][i],      ui = zi[ln][i];
            float vr = zr[ln][i+half], vi = zi[ln][i+half];
            float tr = vr*wr - vi*wi,  ti = vr*wi + vi*wr;
            zr[ln][i]      = ur + tr;  zi[ln][i]      = ui + ti;
            zr[ln][i+half] = ur - tr;  zi[ln][i+half] = ui - ti;
        }
        __syncthreads();
    }
    for (int idx = t; idx < 4*256; idx += 256){
        int ln = idx >> 8, h = idx & 255;
        int L = (ln < 2) ? ln : (nl + ln);       // 0,1,nl+2,nl+3
        mag[L][h] = (_Float16)sqrtf(zr[ln][h]*zr[ln][h] + zi[ln][h]*zi[ln][h]);
    }
    __syncthreads();                             // protect zr before pass B reuse

    // ---- pass B: nl owned lines -> forward FFT (keep complex) + mag[2..nl+1] ----
    for (int idx = t; idx < nl*256; idx += 256){
        int ln = idx >> 8, h = idx & 255;
        float2 v = Sp[(size_t)(kw0+ln)*H_ + h];
        unsigned bh = rev8((unsigned)h);
        zr[ln][bh] = v.x; zi[ln][bh] = v.y;
    }
    __syncthreads();
    for (int s = 0; s < 8; ++s){
        const int half = 1 << s;
        for (int idx = t; idx < nl*128; idx += 256){
            int ln = idx >> 7, b = idx & 127;
            int j = b & (half-1);
            int i = ((b >> s) << (s+1)) + j;
            int k = j << (7 - s);
            float wr = twc[k], wi = tws[k];
            float ur = zr[ln][i],      ui = zi[ln][i];
            float vr = zr[ln][i+half], vi = zi[ln][i+half];
            float tr = vr*wr - vi*wi,  ti = vr*wi + vi*wr;
            zr[ln][i]      = ur + tr;  zi[ln][i]      = ui + ti;
            zr[ln][i+half] = ur - tr;  zi[ln][i+half] = ui - ti;
        }
        __syncthreads();
    }
    for (int idx = t; idx < nl*256; idx += 256){
        int ln = idx >> 8, h = idx & 255;
        mag[2+ln][h] = (_Float16)sqrtf(zr[ln][h]*zr[ln][h] + zi[ln][h]*zi[ln][h]);
    }
    __syncthreads();

    // ---- conv(K=5) + sigmoid -> weight owned complex values in place ----
    for (int idx = t; idx < nl*256; idx += 256){
        int ln = idx >> 8, h = idx & 255;
        int kw = kw0 + ln;
        float acc = cb;
        #pragma unroll
        for (int d = 0; d < 5; ++d){
            int kwa = kw + d - 2;
            int L = ln + d;                      // mag row for this tap
            int sh = (kwa < 0) ? -1 : (kwa > 128 ? 1 : 0);
            int h2 = h + sh;
            if (h2 >= 0 && h2 < H_) acc += (float)mag[L][h2] * cw[d];
        }
        float g = 1.f + 1.f/(1.f + __expf(-acc));
        zr[ln][h] *= g; zi[ln][h] *= g;
    }
    __syncthreads();

    // ---- inverse FFT: DIF, natural in -> bitrev out (conj twiddles) ----
    for (int s = 7; s >= 0; --s){
        const int half = 1 << s;
        for (int idx = t; idx < nl*128; idx += 256){
            int ln = idx >> 7, b = idx & 127;
            int j = b & (half-1);
            int i = ((b >> s) << (s+1)) + j;
            int k = j << (7 - s);
            float wr = twc[k], wi = -tws[k];     // inverse sign
            float ur = zr[ln][i],      ui = zi[ln][i];
            float vr = zr[ln][i+half], vi = zi[ln][i+half];
            zr[ln][i]      = ur + vr;  zi[ln][i]      = ui + vi;
            float tr = ur - vr,        ti = ui - vi;
            zr[ln][i+half] = tr*wr - ti*wi;
            zi[ln][i+half] = tr*wi + ti*wr;
        }
        __syncthreads();
    }
    // store: X[h] = z[rev8(h)]; kw<128 -> D (d_out), kw==128 -> Sx
    float2* Dp  = D  + (size_t)p*128*H_;
    float2* Sxp = Sx + (size_t)p*H_;
    for (int idx = t; idx < nl*256; idx += 256){
        int ln = idx >> 8, h = idx & 255;
        unsigned hb = rev8((unsigned)h);
        float2 v = make_float2(zr[ln][hb], zi[ln][hb]);
        int kw = kw0 + ln;
        if (kw < 128) Dp[(size_t)kw*H_ + h] = v;
        else          Sxp[h] = v;
    }
}

// ---------------------------------------------------------------------------
// K5: inverse row transform (Hermitian two-for-one). Reads D (d_out) + Sx,
// writes enh into ws (plane-major float). grid (P_, H_/16), block 256.
// ---------------------------------------------------------------------------
__global__ void k5_irow(const float2* __restrict__ D, const float2* __restrict__ Sx,
                        float* __restrict__ enh){
    __shared__ float sr[WF][17], si[WF][17];
    __shared__ float zr[8][256], zi[8][256];
    __shared__ float twc[128], tws[128];

    const int p = blockIdx.x, tile = blockIdx.y, t = threadIdx.x;
    const int h0 = tile * 16;
    const float2* Dp  = D  + (size_t)p*128*H_;
    const float2* Sxp = Sx + (size_t)p*H_;

    if (t < 128){
        float sv, cv; sincosf(PI_F * (float)t / 128.f, &sv, &cv);
        twc[t] = cv; tws[t] = sv;
    }
    for (int idx = t; idx < WF*16; idx += 256){
        int kw = idx >> 4, hh = idx & 15;
        float2 v = (kw < 128) ? Dp[(size_t)kw*H_ + h0 + hh] : Sxp[h0 + hh];
        sr[kw][hh] = v.x; si[kw][hh] = v.y;
    }
    __syncthreads();

    const int q = t >> 5, l = t & 31;
    #pragma unroll
    for (int it = 0; it < 8; ++it){
        int k = l + 32*it;
        float Ar, Ai, Br2, Bi;
        if (k <= 128){
            Ar = sr[k][2*q];  Ai = si[k][2*q];
            Br2 = sr[k][2*q+1]; Bi = si[k][2*q+1];
        } else {
            int kk = 256 - k;
            Ar = sr[kk][2*q];  Ai = -si[kk][2*q];
            Br2 = sr[kk][2*q+1]; Bi = -si[kk][2*q+1];
        }
        unsigned bk = rev8((unsigned)k);
        zr[q][bk] = Ar - Bi;   // Re(A + iB)
        zi[q][bk] = Ai + Br2;  // Im(A + iB)
    }
    __syncthreads();

    for (int s = 0; s < 8; ++s){
        const int half = 1 << s;
        #pragma unroll
        for (int it = 0; it < 4; ++it){
            int b = l + 32*it;
            int j = b & (half-1);
            int i = ((b >> s) << (s+1)) + j;
            int k = j << (7 - s);
            float wr = twc[k], wi = tws[k];
            float ur = zr[q][i],      ui = zi[q][i];
            float vr = zr[q][i+half], vi = zi[q][i+half];
            float tr = vr*wr - vi*wi, ti = vr*wi + vi*wr;
            zr[q][i]      = ur + tr;  zi[q][i]      = ui + ti;
            zr[q][i+half] = ur - tr;  zi[q][i+half] = ui - ti;
        }
        __syncthreads();
    }

    const float inv = 1.f / 256.f;
    float* ep = enh + (size_t)p*H_*W_ + (size_t)h0*W_;
    #pragma unroll
    for (int r = 0; r < 16; ++r){
        float v = (r & 1) ? zi[r>>1][t] : zr[r>>1][t];
        ep[r*W_ + t] = v * inv;
    }
}

// ---------------------------------------------------------------------------
// K6: out = x + scale * (mix_w @ enh). enh from ws, out to d_out (no aliasing).
// grid (B_, 256), block 256. Thread owns ONE pixel, all 64 outputs in regs.
// ---------------------------------------------------------------------------
__global__ void k6_mix(const float* __restrict__ x, const float* __restrict__ mixw,
                       const float* __restrict__ scale, const float* __restrict__ enh,
                       float* __restrict__ out){
    __shared__ float Ml[64*64];        // Ml[c*64+o] = mix_w[o][c]

    const int b = blockIdx.x, pt = blockIdx.y, t = threadIdx.x;
    const int pix = pt * 256 + t;
    float* op = out + (size_t)b*C_*H_*W_;
    const float* xp = x + (size_t)b*C_*H_*W_;
    const float* ep = enh + (size_t)b*C_*H_*W_;

    for (int idx = t; idx < 64*64; idx += 256){
        int c = idx >> 6, o = idx & 63;
        Ml[idx] = mixw[o*64 + c];
    }
    __syncthreads();

    float acc[64];
    #pragma unroll
    for (int o = 0; o < 64; ++o) acc[o] = 0.f;

    for (int c = 0; c < 64; ++c){
        float v = ep[(size_t)c*H_*W_ + pix];           // coalesced, read once
        const float4* Mr = (const float4*)&Ml[c*64];   // broadcast rows
        #pragma unroll
        for (int o4 = 0; o4 < 16; ++o4){
            float4 m = Mr[o4];
            acc[o4*4+0] += m.x * v;
            acc[o4*4+1] += m.y * v;
            acc[o4*4+2] += m.z * v;
            acc[o4*4+3] += m.w * v;
        }
    }
    const float sc = scale[0];
    #pragma unroll
    for (int o = 0; o < 64; ++o){
        size_t ix = (size_t)o*H_*W_ + pix;
        op[ix] = xp[ix] + sc * acc[o];
    }
}

// ---------------------------------------------------------------------------
extern "C" void kernel_launch(void* const* d_in, const int* in_sizes, int n_in,
                              void* d_out, int out_size, void* d_ws, size_t ws_size,
                              hipStream_t stream){
    const float* x    = (const float*)d_in[0];
    const float* fw   = (const float*)d_in[1];
    const float* fb   = (const float*)d_in[2];
    const float* mixw = (const float*)d_in[3];
    const float* scal = (const float*)d_in[4];
    float* out = (float*)d_out;

    // ws: S (float2 P*WF*H = 135.3MB) + Sx (float2 P*H = 1MB) ~= 136.3MB.
    // The S region is reused by k5 as the enh buffer (128MB) after k2f is done.
    float2* S   = (float2*)d_ws;
    float2* Sx  = (float2*)((char*)d_ws + (size_t)P_*WF*H_*sizeof(float2));
    float*  enh = (float*)d_ws;

    dim3 blk(256);
    k1_row_rfft <<<dim3(P_, H_/16), blk, 0, stream>>>(x, S);
    k2f_fused   <<<dim3(P_, 9),     blk, 0, stream>>>(S, (float2*)out, Sx, fw, fb);
    k5_irow     <<<dim3(P_, H_/16), blk, 0, stream>>>((const float2*)out, Sx, enh);
    k6_mix      <<<dim3(B_, 256),   blk, 0, stream>>>(x, mixw, scal, enh, out);
}

// Round 5
// 474.790 us; speedup vs baseline: 1.1353x; 1.0202x over previous
//
#include <hip/hip_runtime.h>
#include <math.h>

#define B_ 8
#define C_ 64
#define H_ 256
#define W_ 256
#define WF 129
#define P_ (B_*C_)      // 512 planes
#define PI_F 3.14159265358979323846f

__device__ __forceinline__ unsigned rev8(unsigned x){ return __brev(x) >> 24u; }
// LDS bank-conflict swizzle for 256-long line arrays (involution: SW(SW(i))=i).
// Bank bits become {i[4:3], i[2:0]^i[7:5]} -> rev8 scatters spread over all banks.
#define SW(i) ((i) ^ ((i) >> 5))

// ---------------------------------------------------------------------------
// K1: row rfft (two-for-one). grid (P_, H_/16), block 256.
// Reads x[p][h0..h0+16][0..255]; writes S[p][kw][h] (transposed), scaled 1/256.
// ---------------------------------------------------------------------------
__global__ void k1_row_rfft(const float* __restrict__ x, float2* __restrict__ S){
    __shared__ float zr[8][256], zi[8][256];
    __shared__ float twc[128], tws[128];
    __shared__ float obr[WF][17], obi[WF][17];

    const int p = blockIdx.x, tile = blockIdx.y, t = threadIdx.x;
    const int h0 = tile * 16;
    const float* xp = x + (size_t)p*H_*W_ + (size_t)h0*W_;

    if (t < 128){
        float sv, cv; sincosf(-PI_F * (float)t / 128.f, &sv, &cv);
        twc[t] = cv; tws[t] = sv;
    }
    const unsigned br = SW(rev8((unsigned)t));
    #pragma unroll
    for (int r = 0; r < 16; ++r){
        float v = xp[r*W_ + t];
        if (r & 1) zi[r>>1][br] = v; else zr[r>>1][br] = v;
    }
    __syncthreads();

    const int q = t >> 5, l = t & 31;
    for (int s = 0; s < 8; ++s){
        const int half = 1 << s;
        #pragma unroll
        for (int it = 0; it < 4; ++it){
            int b = l + 32*it;
            int j = b & (half-1);
            int i = ((b >> s) << (s+1)) + j;
            int k = j << (7 - s);
            int i0 = SW(i), i1 = SW(i+half);
            float wr = twc[k], wi = tws[k];
            float ur = zr[q][i0], ui = zi[q][i0];
            float vr = zr[q][i1], vi = zi[q][i1];
            float tr = vr*wr - vi*wi, ti = vr*wi + vi*wr;
            zr[q][i0] = ur + tr;  zi[q][i0] = ui + ti;
            zr[q][i1] = ur - tr;  zi[q][i1] = ui - ti;
        }
        __syncthreads();
    }

    // unpack: A = rfft(row 2q), B = rfft(row 2q+1); fold ortho forward 1/256
    const float sc = 0.5f / 256.f;
    for (int kw = l; kw < WF; kw += 32){
        int km = (256 - kw) & 255;
        int kws = SW(kw), kms = SW(km);
        float Zr = zr[q][kws], Zi = zi[q][kws];
        float Yr = zr[q][kms], Yi = zi[q][kms];
        obr[kw][2*q]   = sc*(Zr + Yr);
        obi[kw][2*q]   = sc*(Zi - Yi);
        obr[kw][2*q+1] = sc*(Zi + Yi);
        obi[kw][2*q+1] = sc*(Yr - Zr);
    }
    __syncthreads();

    float2* Sp = S + (size_t)p*WF*H_;
    for (int idx = t; idx < WF*16; idx += 256){
        int kw = idx >> 4, hh = idx & 15;
        Sp[(size_t)kw*H_ + h0 + hh] = make_float2(obr[kw][hh], obi[kw][hh]);
    }
}

// ---------------------------------------------------------------------------
// K2F: fused col-FFT + mag + depthwise-conv(K=5 over flat h*129+kw) + sigmoid
//      weighting + inverse col-FFT (DIF: natural in, bitrev out).
// Reads S (k1 output) ONLY; writes kw<128 lines to D (d_out as float2) and
// the kw=128 line to Sx. No block reads another block's writes -> race-free.
// grid (P_, 9), block 256.
// ---------------------------------------------------------------------------
__global__ void k2f_fused(const float2* __restrict__ S, float2* __restrict__ D,
                          float2* __restrict__ Sx, const float* __restrict__ fw,
                          const float* __restrict__ fb){
    __shared__ float zr[16][256], zi[16][256];   // 32 KB
    __shared__ _Float16 mag[20][256];            // 10 KB
    __shared__ float twc[128], tws[128];
    __shared__ float cw[5];
    __shared__ float cb;

    const int p = blockIdx.x, tile = blockIdx.y, t = threadIdx.x;
    const int kw0 = tile * 16;
    const int nl = min(16, WF - kw0);            // 16 (tiles 0..7) or 1 (tile 8)
    const int c = p & (C_-1);
    const float2* Sp = S + (size_t)p*WF*H_;

    if (t < 128){
        float sv, cv; sincosf(-PI_F * (float)t / 128.f, &sv, &cv);
        twc[t] = cv; tws[t] = sv;   // forward table; inverse flips wi sign
    }
    if (t < 5)  cw[t] = fw[c*5 + t];
    if (t == 5) cb = fb[c];

    // ---- pass A: 4 halo lines -> mag rows 0,1,nl+2,nl+3 ----
    for (int idx = t; idx < 4*256; idx += 256){
        int ln = idx >> 8, h = idx & 255;
        int kwa = (ln < 2) ? (kw0 - 2 + ln) : (kw0 + nl + ln - 2);
        int phys = kwa < 0 ? kwa + WF : (kwa > 128 ? kwa - WF : kwa);
        float2 v = Sp[(size_t)phys*H_ + h];
        unsigned bh = SW(rev8((unsigned)h));
        zr[ln][bh] = v.x; zi[ln][bh] = v.y;
    }
    __syncthreads();
    for (int s = 0; s < 8; ++s){
        const int half = 1 << s;
        for (int idx = t; idx < 4*128; idx += 256){
            int ln = idx >> 7, b = idx & 127;
            int j = b & (half-1);
            int i = ((b >> s) << (s+1)) + j;
            int k = j << (7 - s);
            int i0 = SW(i), i1 = SW(i+half);
            float wr = twc[k], wi = tws[k];
            float ur = zr[ln][i0], ui = zi[ln][i0];
            float vr = zr[ln][i1], vi = zi[ln][i1];
            float tr = vr*wr - vi*wi,  ti = vr*wi + vi*wr;
            zr[ln][i0] = ur + tr;  zi[ln][i0] = ui + ti;
            zr[ln][i1] = ur - tr;  zi[ln][i1] = ui - ti;
        }
        __syncthreads();
    }
    for (int idx = t; idx < 4*256; idx += 256){
        int ln = idx >> 8, h = idx & 255;
        int L = (ln < 2) ? ln : (nl + ln);       // 0,1,nl+2,nl+3
        int hs = SW(h);
        mag[L][h] = (_Float16)sqrtf(zr[ln][hs]*zr[ln][hs] + zi[ln][hs]*zi[ln][hs]);
    }
    __syncthreads();                             // protect zr before pass B reuse

    // ---- pass B: nl owned lines -> forward FFT (keep complex) + mag[2..nl+1] ----
    for (int idx = t; idx < nl*256; idx += 256){
        int ln = idx >> 8, h = idx & 255;
        float2 v = Sp[(size_t)(kw0+ln)*H_ + h];
        unsigned bh = SW(rev8((unsigned)h));
        zr[ln][bh] = v.x; zi[ln][bh] = v.y;
    }
    __syncthreads();
    for (int s = 0; s < 8; ++s){
        const int half = 1 << s;
        for (int idx = t; idx < nl*128; idx += 256){
            int ln = idx >> 7, b = idx & 127;
            int j = b & (half-1);
            int i = ((b >> s) << (s+1)) + j;
            int k = j << (7 - s);
            int i0 = SW(i), i1 = SW(i+half);
            float wr = twc[k], wi = tws[k];
            float ur = zr[ln][i0], ui = zi[ln][i0];
            float vr = zr[ln][i1], vi = zi[ln][i1];
            float tr = vr*wr - vi*wi,  ti = vr*wi + vi*wr;
            zr[ln][i0] = ur + tr;  zi[ln][i0] = ui + ti;
            zr[ln][i1] = ur - tr;  zi[ln][i1] = ui - ti;
        }
        __syncthreads();
    }
    for (int idx = t; idx < nl*256; idx += 256){
        int ln = idx >> 8, h = idx & 255;
        int hs = SW(h);
        mag[2+ln][h] = (_Float16)sqrtf(zr[ln][hs]*zr[ln][hs] + zi[ln][hs]*zi[ln][hs]);
    }
    __syncthreads();

    // ---- conv(K=5) + sigmoid -> weight owned complex values in place ----
    for (int idx = t; idx < nl*256; idx += 256){
        int ln = idx >> 8, h = idx & 255;
        int kw = kw0 + ln;
        float acc = cb;
        #pragma unroll
        for (int d = 0; d < 5; ++d){
            int kwa = kw + d - 2;
            int L = ln + d;                      // mag row for this tap
            int sh = (kwa < 0) ? -1 : (kwa > 128 ? 1 : 0);
            int h2 = h + sh;
            if (h2 >= 0 && h2 < H_) acc += (float)mag[L][h2] * cw[d];
        }
        float g = 1.f + 1.f/(1.f + __expf(-acc));
        int hs = SW(h);
        zr[ln][hs] *= g; zi[ln][hs] *= g;
    }
    __syncthreads();

    // ---- inverse FFT: DIF, natural in -> bitrev out (conj twiddles) ----
    for (int s = 7; s >= 0; --s){
        const int half = 1 << s;
        for (int idx = t; idx < nl*128; idx += 256){
            int ln = idx >> 7, b = idx & 127;
            int j = b & (half-1);
            int i = ((b >> s) << (s+1)) + j;
            int k = j << (7 - s);
            int i0 = SW(i), i1 = SW(i+half);
            float wr = twc[k], wi = -tws[k];     // inverse sign
            float ur = zr[ln][i0], ui = zi[ln][i0];
            float vr = zr[ln][i1], vi = zi[ln][i1];
            zr[ln][i0] = ur + vr;  zi[ln][i0] = ui + vi;
            float tr = ur - vr,    ti = ui - vi;
            zr[ln][i1] = tr*wr - ti*wi;
            zi[ln][i1] = tr*wi + ti*wr;
        }
        __syncthreads();
    }
    // store: X[h] = z[rev8(h)]; kw<128 -> D (d_out), kw==128 -> Sx
    float2* Dp  = D  + (size_t)p*128*H_;
    float2* Sxp = Sx + (size_t)p*H_;
    for (int idx = t; idx < nl*256; idx += 256){
        int ln = idx >> 8, h = idx & 255;
        unsigned hb = SW(rev8((unsigned)h));
        float2 v = make_float2(zr[ln][hb], zi[ln][hb]);
        int kw = kw0 + ln;
        if (kw < 128) Dp[(size_t)kw*H_ + h] = v;
        else          Sxp[h] = v;
    }
}

// ---------------------------------------------------------------------------
// K5: inverse row transform (Hermitian two-for-one). Reads D (d_out) + Sx,
// writes enh into ws (plane-major float). grid (P_, H_/16), block 256.
// ---------------------------------------------------------------------------
__global__ void k5_irow(const float2* __restrict__ D, const float2* __restrict__ Sx,
                        float* __restrict__ enh){
    __shared__ float sr[WF][17], si[WF][17];
    __shared__ float zr[8][256], zi[8][256];
    __shared__ float twc[128], tws[128];

    const int p = blockIdx.x, tile = blockIdx.y, t = threadIdx.x;
    const int h0 = tile * 16;
    const float2* Dp  = D  + (size_t)p*128*H_;
    const float2* Sxp = Sx + (size_t)p*H_;

    if (t < 128){
        float sv, cv; sincosf(PI_F * (float)t / 128.f, &sv, &cv);
        twc[t] = cv; tws[t] = sv;
    }
    for (int idx = t; idx < WF*16; idx += 256){
        int kw = idx >> 4, hh = idx & 15;
        float2 v = (kw < 128) ? Dp[(size_t)kw*H_ + h0 + hh] : Sxp[h0 + hh];
        sr[kw][hh] = v.x; si[kw][hh] = v.y;
    }
    __syncthreads();

    const int q = t >> 5, l = t & 31;
    #pragma unroll
    for (int it = 0; it < 8; ++it){
        int k = l + 32*it;
        float Ar, Ai, Br2, Bi;
        if (k <= 128){
            Ar = sr[k][2*q];  Ai = si[k][2*q];
            Br2 = sr[k][2*q+1]; Bi = si[k][2*q+1];
        } else {
            int kk = 256 - k;
            Ar = sr[kk][2*q];  Ai = -si[kk][2*q];
            Br2 = sr[kk][2*q+1]; Bi = -si[kk][2*q+1];
        }
        unsigned bk = SW(rev8((unsigned)k));
        zr[q][bk] = Ar - Bi;   // Re(A + iB)
        zi[q][bk] = Ai + Br2;  // Im(A + iB)
    }
    __syncthreads();

    for (int s = 0; s < 8; ++s){
        const int half = 1 << s;
        #pragma unroll
        for (int it = 0; it < 4; ++it){
            int b = l + 32*it;
            int j = b & (half-1);
            int i = ((b >> s) << (s+1)) + j;
            int k = j << (7 - s);
            int i0 = SW(i), i1 = SW(i+half);
            float wr = twc[k], wi = tws[k];
            float ur = zr[q][i0], ui = zi[q][i0];
            float vr = zr[q][i1], vi = zi[q][i1];
            float tr = vr*wr - vi*wi, ti = vr*wi + vi*wr;
            zr[q][i0] = ur + tr;  zi[q][i0] = ui + ti;
            zr[q][i1] = ur - tr;  zi[q][i1] = ui - ti;
        }
        __syncthreads();
    }

    const float inv = 1.f / 256.f;
    float* ep = enh + (size_t)p*H_*W_ + (size_t)h0*W_;
    const int ts = SW(t);
    #pragma unroll
    for (int r = 0; r < 16; ++r){
        float v = (r & 1) ? zi[r>>1][ts] : zr[r>>1][ts];
        ep[r*W_ + t] = v * inv;
    }
}

// ---------------------------------------------------------------------------
// K6: out = x + scale * (mix_w @ enh). enh from ws, out to d_out (no aliasing).
// grid (B_, 256), block 256. Thread owns ONE pixel, all 64 outputs in regs.
// ---------------------------------------------------------------------------
__global__ void k6_mix(const float* __restrict__ x, const float* __restrict__ mixw,
                       const float* __restrict__ scale, const float* __restrict__ enh,
                       float* __restrict__ out){
    __shared__ float Ml[64*64];        // Ml[c*64+o] = mix_w[o][c]

    const int b = blockIdx.x, pt = blockIdx.y, t = threadIdx.x;
    const int pix = pt * 256 + t;
    float* op = out + (size_t)b*C_*H_*W_;
    const float* xp = x + (size_t)b*C_*H_*W_;
    const float* ep = enh + (size_t)b*C_*H_*W_;

    for (int idx = t; idx < 64*64; idx += 256){
        int c = idx >> 6, o = idx & 63;
        Ml[idx] = mixw[o*64 + c];
    }
    __syncthreads();

    float acc[64];
    #pragma unroll
    for (int o = 0; o < 64; ++o) acc[o] = 0.f;

    for (int c = 0; c < 64; ++c){
        float v = ep[(size_t)c*H_*W_ + pix];           // coalesced, read once
        const float4* Mr = (const float4*)&Ml[c*64];   // broadcast rows
        #pragma unroll
        for (int o4 = 0; o4 < 16; ++o4){
            float4 m = Mr[o4];
            acc[o4*4+0] += m.x * v;
            acc[o4*4+1] += m.y * v;
            acc[o4*4+2] += m.z * v;
            acc[o4*4+3] += m.w * v;
        }
    }
    const float sc = scale[0];
    #pragma unroll
    for (int o = 0; o < 64; ++o){
        size_t ix = (size_t)o*H_*W_ + pix;
        op[ix] = xp[ix] + sc * acc[o];
    }
}

// ---------------------------------------------------------------------------
extern "C" void kernel_launch(void* const* d_in, const int* in_sizes, int n_in,
                              void* d_out, int out_size, void* d_ws, size_t ws_size,
                              hipStream_t stream){
    const float* x    = (const float*)d_in[0];
    const float* fw   = (const float*)d_in[1];
    const float* fb   = (const float*)d_in[2];
    const float* mixw = (const float*)d_in[3];
    const float* scal = (const float*)d_in[4];
    float* out = (float*)d_out;

    // ws: S (float2 P*WF*H = 135.3MB) + Sx (float2 P*H = 1MB) ~= 136.3MB.
    // The S region is reused by k5 as the enh buffer (128MB) after k2f is done.
    float2* S   = (float2*)d_ws;
    float2* Sx  = (float2*)((char*)d_ws + (size_t)P_*WF*H_*sizeof(float2));
    float*  enh = (float*)d_ws;

    dim3 blk(256);
    k1_row_rfft <<<dim3(P_, H_/16), blk, 0, stream>>>(x, S);
    k2f_fused   <<<dim3(P_, 9),     blk, 0, stream>>>(S, (float2*)out, Sx, fw, fb);
    k5_irow     <<<dim3(P_, H_/16), blk, 0, stream>>>((const float2*)out, Sx, enh);
    k6_mix      <<<dim3(B_, 256),   blk, 0, stream>>>(x, mixw, scal, enh, out);
}

// Round 6
// 446.611 us; speedup vs baseline: 1.2069x; 1.0631x over previous
//
#include <hip/hip_runtime.h>
#include <math.h>

#define B_ 8
#define C_ 64
#define H_ 256
#define W_ 256
#define WF 129
#define P_ (B_*C_)      // 512 planes
#define PI_F 3.14159265358979323846f

__device__ __forceinline__ unsigned rev8(unsigned x){ return __brev(x) >> 24u; }
// radix-2 kernels (k1/k5) keep the SW swizzle
#define SW(i) ((i) ^ ((i) >> 5))
// radix-4 physical LDS swizzle: XOR p[5:4] into p[3:2]; keeps p[1:0] intact
// (so 4-consecutive float2 stay contiguous for b128), spreads all stage
// strides to the b64 bank floor.
#define PI4(i) ((i) ^ ((((i) >> 4) & 3) << 2))
// base-4 digit reversal of 8-bit index
__device__ __forceinline__ int dr4(int h){
    return ((h & 3) << 6) | (((h >> 2) & 3) << 4) | (((h >> 4) & 3) << 2) | ((h >> 6) & 3);
}
__device__ __forceinline__ float2 cmulf(float2 a, float2 w){
    return make_float2(a.x*w.x - a.y*w.y, a.x*w.y + a.y*w.x);
}
__device__ __forceinline__ float2 cmulcf(float2 a, float2 w){  // a * conj(w)
    return make_float2(a.x*w.x + a.y*w.y, a.y*w.x - a.x*w.y);
}

// ---------------------------------------------------------------------------
// K1: row rfft (two-for-one). grid (P_, H_/16), block 256.  (unchanged R5)
// ---------------------------------------------------------------------------
__global__ void k1_row_rfft(const float* __restrict__ x, float2* __restrict__ S){
    __shared__ float zr[8][256], zi[8][256];
    __shared__ float twc[128], tws[128];
    __shared__ float obr[WF][17], obi[WF][17];

    const int p = blockIdx.x, tile = blockIdx.y, t = threadIdx.x;
    const int h0 = tile * 16;
    const float* xp = x + (size_t)p*H_*W_ + (size_t)h0*W_;

    if (t < 128){
        float sv, cv; sincosf(-PI_F * (float)t / 128.f, &sv, &cv);
        twc[t] = cv; tws[t] = sv;
    }
    const unsigned br = SW(rev8((unsigned)t));
    #pragma unroll
    for (int r = 0; r < 16; ++r){
        float v = xp[r*W_ + t];
        if (r & 1) zi[r>>1][br] = v; else zr[r>>1][br] = v;
    }
    __syncthreads();

    const int q = t >> 5, l = t & 31;
    for (int s = 0; s < 8; ++s){
        const int half = 1 << s;
        #pragma unroll
        for (int it = 0; it < 4; ++it){
            int b = l + 32*it;
            int j = b & (half-1);
            int i = ((b >> s) << (s+1)) + j;
            int k = j << (7 - s);
            int i0 = SW(i), i1 = SW(i+half);
            float wr = twc[k], wi = tws[k];
            float ur = zr[q][i0], ui = zi[q][i0];
            float vr = zr[q][i1], vi = zi[q][i1];
            float tr = vr*wr - vi*wi, ti = vr*wi + vi*wr;
            zr[q][i0] = ur + tr;  zi[q][i0] = ui + ti;
            zr[q][i1] = ur - tr;  zi[q][i1] = ui - ti;
        }
        __syncthreads();
    }

    const float sc = 0.5f / 256.f;
    for (int kw = l; kw < WF; kw += 32){
        int km = (256 - kw) & 255;
        int kws = SW(kw), kms = SW(km);
        float Zr = zr[q][kws], Zi = zi[q][kws];
        float Yr = zr[q][kms], Yi = zi[q][kms];
        obr[kw][2*q]   = sc*(Zr + Yr);
        obi[kw][2*q]   = sc*(Zi - Yi);
        obr[kw][2*q+1] = sc*(Zi + Yi);
        obi[kw][2*q+1] = sc*(Yr - Zr);
    }
    __syncthreads();

    float2* Sp = S + (size_t)p*WF*H_;
    for (int idx = t; idx < WF*16; idx += 256){
        int kw = idx >> 4, hh = idx & 15;
        Sp[(size_t)kw*H_ + h0 + hh] = make_float2(obr[kw][hh], obi[kw][hh]);
    }
}

// ---------------------------------------------------------------------------
// K2F: fused col-FFT + mag + depthwise-conv + sigmoid weighting + inverse
//      col-FFT. RADIX-4, float2-packed LDS, b128 stage-0, SoA twiddles.
// Reads S only; writes kw<128 -> D (d_out), kw==128 -> Sx. Race-free.
// grid (P_, 9), block 256.
// ---------------------------------------------------------------------------
__global__ void k2f_fused(const float2* __restrict__ S, float2* __restrict__ D,
                          float2* __restrict__ Sx, const float* __restrict__ fw,
                          const float* __restrict__ fb){
    __shared__ float2 zc[16][256];               // 32 KB (physical idx = PI4(logical))
    __shared__ _Float16 mag[20][256];            // 10 KB
    __shared__ float2 tw1[84], tw2[84], tw3[84]; // 2 KB  (w, w^2, w^3 per j)
    __shared__ float cw[5];
    __shared__ float cb;

    const int p = blockIdx.x, tile = blockIdx.y, t = threadIdx.x;
    const int kw0 = tile * 16;
    const int nl = min(16, WF - kw0);            // 16 (tiles 0..7) or 1 (tile 8)
    const int c = p & (C_-1);
    const float2* Sp = S + (size_t)p*WF*H_;

    // twiddle tables: stage L in {4,16,64}, base offsets {0,4,20}
    for (int i = t; i < 84; i += 256){
        int L, j;
        if (i < 4)       { L = 4;  j = i; }
        else if (i < 20) { L = 16; j = i - 4; }
        else             { L = 64; j = i - 20; }
        float ang = -2.f * PI_F * (float)j / (float)(4*L);
        float s1,c1,s2,c2,s3,c3;
        sincosf(ang, &s1, &c1);
        sincosf(2.f*ang, &s2, &c2);
        sincosf(3.f*ang, &s3, &c3);
        tw1[i] = make_float2(c1,s1); tw2[i] = make_float2(c2,s2); tw3[i] = make_float2(c3,s3);
    }
    if (t < 5)  cw[t] = fw[c*5 + t];
    if (t == 5) cb = fb[c];

    // ================= forward FFT of 4 halo lines (rows 0..3) =============
    for (int idx = t; idx < 4*256; idx += 256){
        int ln = idx >> 8, u = idx & 255;
        int h = ((u & 3) << 6) | (u >> 2);
        int kwa = (ln < 2) ? (kw0 - 2 + ln) : (kw0 + nl + ln - 2);
        int phys = kwa < 0 ? kwa + WF : (kwa > 128 ? kwa - WF : kwa);
        zc[ln][PI4(dr4(h))] = Sp[(size_t)phys*H_ + h];
    }
    __syncthreads();
    #pragma unroll
    for (int s = 0; s < 4; ++s){
        const int L = 1 << (2*s);
        const int tb = (s==1) ? 0 : (s==2) ? 4 : 20;
        for (int idx = t; idx < 4*64; idx += 256){
            int ln = idx >> 6, b = idx & 63;
            float2 y0, y1, y2, y3;
            if (s == 0){
                int pb = 4*(b ^ ((b >> 2) & 3));
                float4 lo = *(const float4*)&zc[ln][pb];
                float4 hi = *(const float4*)&zc[ln][pb+2];
                float2 u0 = make_float2(lo.x,lo.y), u1 = make_float2(lo.z,lo.w);
                float2 u2 = make_float2(hi.x,hi.y), u3 = make_float2(hi.z,hi.w);
                float2 P = make_float2(u0.x+u2.x, u0.y+u2.y);
                float2 M = make_float2(u0.x-u2.x, u0.y-u2.y);
                float2 Q = make_float2(u1.x+u3.x, u1.y+u3.y);
                float2 R = make_float2(u1.x-u3.x, u1.y-u3.y);
                y0 = make_float2(P.x+Q.x, P.y+Q.y);
                y2 = make_float2(P.x-Q.x, P.y-Q.y);
                y1 = make_float2(M.x+R.y, M.y-R.x);   // M + (-i)R
                y3 = make_float2(M.x-R.y, M.y+R.x);   // M + (+i)R
                *(float4*)&zc[ln][pb]   = make_float4(y0.x,y0.y,y1.x,y1.y);
                *(float4*)&zc[ln][pb+2] = make_float4(y2.x,y2.y,y3.x,y3.y);
            } else {
                int j = b & (L-1);
                int p0 = ((b >> (2*s)) << (2*s+2)) + j;
                float2 u0 = zc[ln][PI4(p0)];
                float2 a1 = zc[ln][PI4(p0+L)];
                float2 a2 = zc[ln][PI4(p0+2*L)];
                float2 a3 = zc[ln][PI4(p0+3*L)];
                float2 v1 = cmulf(a1, tw1[tb+j]);
                float2 v2 = cmulf(a2, tw2[tb+j]);
                float2 v3 = cmulf(a3, tw3[tb+j]);
                float2 P = make_float2(u0.x+v2.x, u0.y+v2.y);
                float2 M = make_float2(u0.x-v2.x, u0.y-v2.y);
                float2 Q = make_float2(v1.x+v3.x, v1.y+v3.y);
                float2 R = make_float2(v1.x-v3.x, v1.y-v3.y);
                y0 = make_float2(P.x+Q.x, P.y+Q.y);
                y2 = make_float2(P.x-Q.x, P.y-Q.y);
                y1 = make_float2(M.x+R.y, M.y-R.x);
                y3 = make_float2(M.x-R.y, M.y+R.x);
                zc[ln][PI4(p0)]     = y0;
                zc[ln][PI4(p0+L)]   = y1;
                zc[ln][PI4(p0+2*L)] = y2;
                zc[ln][PI4(p0+3*L)] = y3;
            }
        }
        __syncthreads();
    }
    for (int idx = t; idx < 4*256; idx += 256){
        int ln = idx >> 8, h = idx & 255;
        int L = (ln < 2) ? ln : (nl + ln);       // mag rows 0,1,nl+2,nl+3
        float2 v = zc[ln][PI4(h)];
        mag[L][h] = (_Float16)sqrtf(v.x*v.x + v.y*v.y);
    }
    __syncthreads();

    // ================= forward FFT of nl owned lines ========================
    for (int idx = t; idx < nl*256; idx += 256){
        int ln = idx >> 8, u = idx & 255;
        int h = ((u & 3) << 6) | (u >> 2);
        zc[ln][PI4(dr4(h))] = Sp[(size_t)(kw0+ln)*H_ + h];
    }
    __syncthreads();
    #pragma unroll
    for (int s = 0; s < 4; ++s){
        const int L = 1 << (2*s);
        const int tb = (s==1) ? 0 : (s==2) ? 4 : 20;
        for (int idx = t; idx < nl*64; idx += 256){
            int ln = idx >> 6, b = idx & 63;
            float2 y0, y1, y2, y3;
            if (s == 0){
                int pb = 4*(b ^ ((b >> 2) & 3));
                float4 lo = *(const float4*)&zc[ln][pb];
                float4 hi = *(const float4*)&zc[ln][pb+2];
                float2 u0 = make_float2(lo.x,lo.y), u1 = make_float2(lo.z,lo.w);
                float2 u2 = make_float2(hi.x,hi.y), u3 = make_float2(hi.z,hi.w);
                float2 P = make_float2(u0.x+u2.x, u0.y+u2.y);
                float2 M = make_float2(u0.x-u2.x, u0.y-u2.y);
                float2 Q = make_float2(u1.x+u3.x, u1.y+u3.y);
                float2 R = make_float2(u1.x-u3.x, u1.y-u3.y);
                y0 = make_float2(P.x+Q.x, P.y+Q.y);
                y2 = make_float2(P.x-Q.x, P.y-Q.y);
                y1 = make_float2(M.x+R.y, M.y-R.x);
                y3 = make_float2(M.x-R.y, M.y+R.x);
                *(float4*)&zc[ln][pb]   = make_float4(y0.x,y0.y,y1.x,y1.y);
                *(float4*)&zc[ln][pb+2] = make_float4(y2.x,y2.y,y3.x,y3.y);
            } else {
                int j = b & (L-1);
                int p0 = ((b >> (2*s)) << (2*s+2)) + j;
                float2 u0 = zc[ln][PI4(p0)];
                float2 a1 = zc[ln][PI4(p0+L)];
                float2 a2 = zc[ln][PI4(p0+2*L)];
                float2 a3 = zc[ln][PI4(p0+3*L)];
                float2 v1 = cmulf(a1, tw1[tb+j]);
                float2 v2 = cmulf(a2, tw2[tb+j]);
                float2 v3 = cmulf(a3, tw3[tb+j]);
                float2 P = make_float2(u0.x+v2.x, u0.y+v2.y);
                float2 M = make_float2(u0.x-v2.x, u0.y-v2.y);
                float2 Q = make_float2(v1.x+v3.x, v1.y+v3.y);
                float2 R = make_float2(v1.x-v3.x, v1.y-v3.y);
                y0 = make_float2(P.x+Q.x, P.y+Q.y);
                y2 = make_float2(P.x-Q.x, P.y-Q.y);
                y1 = make_float2(M.x+R.y, M.y-R.x);
                y3 = make_float2(M.x-R.y, M.y+R.x);
                zc[ln][PI4(p0)]     = y0;
                zc[ln][PI4(p0+L)]   = y1;
                zc[ln][PI4(p0+2*L)] = y2;
                zc[ln][PI4(p0+3*L)] = y3;
            }
        }
        __syncthreads();
    }
    for (int idx = t; idx < nl*256; idx += 256){
        int ln = idx >> 8, h = idx & 255;
        float2 v = zc[ln][PI4(h)];
        mag[2+ln][h] = (_Float16)sqrtf(v.x*v.x + v.y*v.y);
    }
    __syncthreads();

    // ================= conv(K=5) + sigmoid -> weight in place ===============
    for (int idx = t; idx < nl*256; idx += 256){
        int ln = idx >> 8, h = idx & 255;
        int kw = kw0 + ln;
        float acc = cb;
        #pragma unroll
        for (int d = 0; d < 5; ++d){
            int kwa = kw + d - 2;
            int L = ln + d;
            int sh = (kwa < 0) ? -1 : (kwa > 128 ? 1 : 0);
            int h2 = h + sh;
            if (h2 >= 0 && h2 < H_) acc += (float)mag[L][h2] * cw[d];
        }
        float g = 1.f + 1.f/(1.f + __expf(-acc));
        int hp = PI4(h);
        float2 v = zc[ln][hp];
        zc[ln][hp] = make_float2(v.x*g, v.y*g);
    }
    __syncthreads();

    // ================= inverse FFT: radix-4 DIF, natural in -> dr4 out ======
    #pragma unroll
    for (int s = 3; s >= 0; --s){
        const int L = 1 << (2*s);
        const int tb = (s==1) ? 0 : (s==2) ? 4 : 20;
        for (int idx = t; idx < nl*64; idx += 256){
            int ln = idx >> 6, b = idx & 63;
            if (s == 0){
                int pb = 4*(b ^ ((b >> 2) & 3));
                float4 lo = *(const float4*)&zc[ln][pb];
                float4 hi = *(const float4*)&zc[ln][pb+2];
                float2 u0 = make_float2(lo.x,lo.y), u1 = make_float2(lo.z,lo.w);
                float2 u2 = make_float2(hi.x,hi.y), u3 = make_float2(hi.z,hi.w);
                float2 P = make_float2(u0.x+u2.x, u0.y+u2.y);
                float2 M = make_float2(u0.x-u2.x, u0.y-u2.y);
                float2 Q = make_float2(u1.x+u3.x, u1.y+u3.y);
                float2 R = make_float2(u1.x-u3.x, u1.y-u3.y);
                float2 t0 = make_float2(P.x+Q.x, P.y+Q.y);
                float2 t2 = make_float2(P.x-Q.x, P.y-Q.y);
                float2 t1 = make_float2(M.x-R.y, M.y+R.x);   // M + iR
                float2 t3 = make_float2(M.x+R.y, M.y-R.x);   // M - iR
                *(float4*)&zc[ln][pb]   = make_float4(t0.x,t0.y,t1.x,t1.y);
                *(float4*)&zc[ln][pb+2] = make_float4(t2.x,t2.y,t3.x,t3.y);
            } else {
                int j = b & (L-1);
                int p0 = ((b >> (2*s)) << (2*s+2)) + j;
                float2 u0 = zc[ln][PI4(p0)];
                float2 u1 = zc[ln][PI4(p0+L)];
                float2 u2 = zc[ln][PI4(p0+2*L)];
                float2 u3 = zc[ln][PI4(p0+3*L)];
                float2 P = make_float2(u0.x+u2.x, u0.y+u2.y);
                float2 M = make_float2(u0.x-u2.x, u0.y-u2.y);
                float2 Q = make_float2(u1.x+u3.x, u1.y+u3.y);
                float2 R = make_float2(u1.x-u3.x, u1.y-u3.y);
                float2 t0 = make_float2(P.x+Q.x, P.y+Q.y);
                float2 t2 = make_float2(P.x-Q.x, P.y-Q.y);
                float2 t1 = make_float2(M.x-R.y, M.y+R.x);   // M + iR
                float2 t3 = make_float2(M.x+R.y, M.y-R.x);   // M - iR
                zc[ln][PI4(p0)]     = t0;
                zc[ln][PI4(p0+L)]   = cmulcf(t1, tw1[tb+j]);
                zc[ln][PI4(p0+2*L)] = cmulcf(t2, tw2[tb+j]);
                zc[ln][PI4(p0+3*L)] = cmulcf(t3, tw3[tb+j]);
            }
        }
        __syncthreads();
    }

    // store: out[h] = z[dr4(h)]; kw<128 -> D, kw==128 -> Sx
    float2* Dp  = D  + (size_t)p*128*H_;
    float2* Sxp = Sx + (size_t)p*H_;
    for (int idx = t; idx < nl*256; idx += 256){
        int ln = idx >> 8, u = idx & 255;
        int h = ((u & 3) << 6) | (u >> 2);
        float2 v = zc[ln][PI4(dr4(h))];
        int kw = kw0 + ln;
        if (kw < 128) Dp[(size_t)kw*H_ + h] = v;
        else          Sxp[h] = v;
    }
}

// ---------------------------------------------------------------------------
// K5: inverse row transform (Hermitian two-for-one). (unchanged R5)
// ---------------------------------------------------------------------------
__global__ void k5_irow(const float2* __restrict__ D, const float2* __restrict__ Sx,
                        float* __restrict__ enh){
    __shared__ float sr[WF][17], si[WF][17];
    __shared__ float zr[8][256], zi[8][256];
    __shared__ float twc[128], tws[128];

    const int p = blockIdx.x, tile = blockIdx.y, t = threadIdx.x;
    const int h0 = tile * 16;
    const float2* Dp  = D  + (size_t)p*128*H_;
    const float2* Sxp = Sx + (size_t)p*H_;

    if (t < 128){
        float sv, cv; sincosf(PI_F * (float)t / 128.f, &sv, &cv);
        twc[t] = cv; tws[t] = sv;
    }
    for (int idx = t; idx < WF*16; idx += 256){
        int kw = idx >> 4, hh = idx & 15;
        float2 v = (kw < 128) ? Dp[(size_t)kw*H_ + h0 + hh] : Sxp[h0 + hh];
        sr[kw][hh] = v.x; si[kw][hh] = v.y;
    }
    __syncthreads();

    const int q = t >> 5, l = t & 31;
    #pragma unroll
    for (int it = 0; it < 8; ++it){
        int k = l + 32*it;
        float Ar, Ai, Br2, Bi;
        if (k <= 128){
            Ar = sr[k][2*q];  Ai = si[k][2*q];
            Br2 = sr[k][2*q+1]; Bi = si[k][2*q+1];
        } else {
            int kk = 256 - k;
            Ar = sr[kk][2*q];  Ai = -si[kk][2*q];
            Br2 = sr[kk][2*q+1]; Bi = -si[kk][2*q+1];
        }
        unsigned bk = SW(rev8((unsigned)k));
        zr[q][bk] = Ar - Bi;
        zi[q][bk] = Ai + Br2;
    }
    __syncthreads();

    for (int s = 0; s < 8; ++s){
        const int half = 1 << s;
        #pragma unroll
        for (int it = 0; it < 4; ++it){
            int b = l + 32*it;
            int j = b & (half-1);
            int i = ((b >> s) << (s+1)) + j;
            int k = j << (7 - s);
            int i0 = SW(i), i1 = SW(i+half);
            float wr = twc[k], wi = tws[k];
            float ur = zr[q][i0], ui = zi[q][i0];
            float vr = zr[q][i1], vi = zi[q][i1];
            float tr = vr*wr - vi*wi, ti = vr*wi + vi*wr;
            zr[q][i0] = ur + tr;  zi[q][i0] = ui + ti;
            zr[q][i1] = ur - tr;  zi[q][i1] = ui - ti;
        }
        __syncthreads();
    }

    const float inv = 1.f / 256.f;
    float* ep = enh + (size_t)p*H_*W_ + (size_t)h0*W_;
    const int ts = SW(t);
    #pragma unroll
    for (int r = 0; r < 16; ++r){
        float v = (r & 1) ? zi[r>>1][ts] : zr[r>>1][ts];
        ep[r*W_ + t] = v * inv;
    }
}

// ---------------------------------------------------------------------------
// K6: out = x + scale * (mix_w @ enh). (unchanged R5)
// ---------------------------------------------------------------------------
__global__ void k6_mix(const float* __restrict__ x, const float* __restrict__ mixw,
                       const float* __restrict__ scale, const float* __restrict__ enh,
                       float* __restrict__ out){
    __shared__ float Ml[64*64];

    const int b = blockIdx.x, pt = blockIdx.y, t = threadIdx.x;
    const int pix = pt * 256 + t;
    float* op = out + (size_t)b*C_*H_*W_;
    const float* xp = x + (size_t)b*C_*H_*W_;
    const float* ep = enh + (size_t)b*C_*H_*W_;

    for (int idx = t; idx < 64*64; idx += 256){
        int c = idx >> 6, o = idx & 63;
        Ml[idx] = mixw[o*64 + c];
    }
    __syncthreads();

    float acc[64];
    #pragma unroll
    for (int o = 0; o < 64; ++o) acc[o] = 0.f;

    for (int c = 0; c < 64; ++c){
        float v = ep[(size_t)c*H_*W_ + pix];
        const float4* Mr = (const float4*)&Ml[c*64];
        #pragma unroll
        for (int o4 = 0; o4 < 16; ++o4){
            float4 m = Mr[o4];
            acc[o4*4+0] += m.x * v;
            acc[o4*4+1] += m.y * v;
            acc[o4*4+2] += m.z * v;
            acc[o4*4+3] += m.w * v;
        }
    }
    const float sc = scale[0];
    #pragma unroll
    for (int o = 0; o < 64; ++o){
        size_t ix = (size_t)o*H_*W_ + pix;
        op[ix] = xp[ix] + sc * acc[o];
    }
}

// ---------------------------------------------------------------------------
extern "C" void kernel_launch(void* const* d_in, const int* in_sizes, int n_in,
                              void* d_out, int out_size, void* d_ws, size_t ws_size,
                              hipStream_t stream){
    const float* x    = (const float*)d_in[0];
    const float* fw   = (const float*)d_in[1];
    const float* fb   = (const float*)d_in[2];
    const float* mixw = (const float*)d_in[3];
    const float* scal = (const float*)d_in[4];
    float* out = (float*)d_out;

    float2* S   = (float2*)d_ws;
    float2* Sx  = (float2*)((char*)d_ws + (size_t)P_*WF*H_*sizeof(float2));
    float*  enh = (float*)d_ws;   // reuses S region after k2f

    dim3 blk(256);
    k1_row_rfft <<<dim3(P_, H_/16), blk, 0, stream>>>(x, S);
    k2f_fused   <<<dim3(P_, 9),     blk, 0, stream>>>(S, (float2*)out, Sx, fw, fb);
    k5_irow     <<<dim3(P_, H_/16), blk, 0, stream>>>((const float2*)out, Sx, enh);
    k6_mix      <<<dim3(B_, 256),   blk, 0, stream>>>(x, mixw, scal, enh, out);
}

// Round 7
// 436.704 us; speedup vs baseline: 1.2343x; 1.0227x over previous
//
#include <hip/hip_runtime.h>
#include <math.h>

#define B_ 8
#define C_ 64
#define H_ 256
#define W_ 256
#define WF 129
#define P_ (B_*C_)      // 512 planes
#define PI_F 3.14159265358979323846f

__device__ __forceinline__ unsigned rev8(unsigned x){ return __brev(x) >> 24u; }
// radix-2 kernels (k1/k5) keep the SW swizzle
#define SW(i) ((i) ^ ((i) >> 5))
// radix-4 physical LDS swizzle (k2f): XOR p[5:4] into p[3:2]
#define PI4(i) ((i) ^ ((((i) >> 4) & 3) << 2))
// base-4 digit reversal of 8-bit index
__device__ __forceinline__ int dr4(int h){
    return ((h & 3) << 6) | (((h >> 2) & 3) << 4) | (((h >> 4) & 3) << 2) | ((h >> 6) & 3);
}
__device__ __forceinline__ float2 cmulf(float2 a, float2 w){
    return make_float2(a.x*w.x - a.y*w.y, a.x*w.y + a.y*w.x);
}
__device__ __forceinline__ float2 cmulcf(float2 a, float2 w){  // a * conj(w)
    return make_float2(a.x*w.x + a.y*w.y, a.y*w.x - a.x*w.y);
}
// forward radix-4 butterfly: y = DFT4(u0,v1,v2,v3) with (-i) rotation
__device__ __forceinline__ void bf4f(float2 u0, float2 v1, float2 v2, float2 v3,
                                     float2& y0, float2& y1, float2& y2, float2& y3){
    float2 P = make_float2(u0.x+v2.x, u0.y+v2.y);
    float2 M = make_float2(u0.x-v2.x, u0.y-v2.y);
    float2 Q = make_float2(v1.x+v3.x, v1.y+v3.y);
    float2 R = make_float2(v1.x-v3.x, v1.y-v3.y);
    y0 = make_float2(P.x+Q.x, P.y+Q.y);
    y2 = make_float2(P.x-Q.x, P.y-Q.y);
    y1 = make_float2(M.x+R.y, M.y-R.x);   // M + (-i)R
    y3 = make_float2(M.x-R.y, M.y+R.x);   // M + (+i)R
}
// inverse radix-4 butterfly (conj rotation), twiddle applied by caller AFTER
__device__ __forceinline__ void bf4i(float2 u0, float2 u1, float2 u2, float2 u3,
                                     float2& t0, float2& t1, float2& t2, float2& t3){
    float2 P = make_float2(u0.x+u2.x, u0.y+u2.y);
    float2 M = make_float2(u0.x-u2.x, u0.y-u2.y);
    float2 Q = make_float2(u1.x+u3.x, u1.y+u3.y);
    float2 R = make_float2(u1.x-u3.x, u1.y-u3.y);
    t0 = make_float2(P.x+Q.x, P.y+Q.y);
    t2 = make_float2(P.x-Q.x, P.y-Q.y);
    t1 = make_float2(M.x-R.y, M.y+R.x);   // M + iR
    t3 = make_float2(M.x+R.y, M.y-R.x);   // M - iR
}

// ---------------------------------------------------------------------------
// K1: row rfft (two-for-one). grid (P_, H_/16), block 256.
// (R6 + float2-packed twiddle table)
// ---------------------------------------------------------------------------
__global__ void k1_row_rfft(const float* __restrict__ x, float2* __restrict__ S){
    __shared__ float zr[8][256], zi[8][256];
    __shared__ float2 twf[128];
    __shared__ float obr[WF][17], obi[WF][17];

    const int p = blockIdx.x, tile = blockIdx.y, t = threadIdx.x;
    const int h0 = tile * 16;
    const float* xp = x + (size_t)p*H_*W_ + (size_t)h0*W_;

    if (t < 128){
        float sv, cv; sincosf(-PI_F * (float)t / 128.f, &sv, &cv);
        twf[t] = make_float2(cv, sv);
    }
    const unsigned br = SW(rev8((unsigned)t));
    #pragma unroll
    for (int r = 0; r < 16; ++r){
        float v = xp[r*W_ + t];
        if (r & 1) zi[r>>1][br] = v; else zr[r>>1][br] = v;
    }
    __syncthreads();

    const int q = t >> 5, l = t & 31;
    for (int s = 0; s < 8; ++s){
        const int half = 1 << s;
        #pragma unroll
        for (int it = 0; it < 4; ++it){
            int b = l + 32*it;
            int j = b & (half-1);
            int i = ((b >> s) << (s+1)) + j;
            int k = j << (7 - s);
            int i0 = SW(i), i1 = SW(i+half);
            float2 w = twf[k];
            float ur = zr[q][i0], ui = zi[q][i0];
            float vr = zr[q][i1], vi = zi[q][i1];
            float tr = vr*w.x - vi*w.y, ti = vr*w.y + vi*w.x;
            zr[q][i0] = ur + tr;  zi[q][i0] = ui + ti;
            zr[q][i1] = ur - tr;  zi[q][i1] = ui - ti;
        }
        __syncthreads();
    }

    const float sc = 0.5f / 256.f;
    for (int kw = l; kw < WF; kw += 32){
        int km = (256 - kw) & 255;
        int kws = SW(kw), kms = SW(km);
        float Zr = zr[q][kws], Zi = zi[q][kws];
        float Yr = zr[q][kms], Yi = zi[q][kms];
        obr[kw][2*q]   = sc*(Zr + Yr);
        obi[kw][2*q]   = sc*(Zi - Yi);
        obr[kw][2*q+1] = sc*(Zi + Yi);
        obi[kw][2*q+1] = sc*(Yr - Zr);
    }
    __syncthreads();

    float2* Sp = S + (size_t)p*WF*H_;
    for (int idx = t; idx < WF*16; idx += 256){
        int kw = idx >> 4, hh = idx & 15;
        Sp[(size_t)kw*H_ + h0 + hh] = make_float2(obr[kw][hh], obi[kw][hh]);
    }
}

// ---------------------------------------------------------------------------
// K2F: fused col-FFT + mag + conv(K=5) + sigmoid + inverse col-FFT.
// Radix-4, float2 LDS, REGISTER twiddles (per-lane constants since b==t&63
// is loop-invariant), mag fused into forward stage 3.
// Reads S only; writes kw<128 -> D (d_out), kw==128 -> Sx. Race-free.
// grid (P_, 9), block 256.
// ---------------------------------------------------------------------------
__global__ void k2f_fused(const float2* __restrict__ S, float2* __restrict__ D,
                          float2* __restrict__ Sx, const float* __restrict__ fw,
                          const float* __restrict__ fb){
    __shared__ float2 zc[16][256];               // 32 KB (physical idx = PI4(logical))
    __shared__ _Float16 mag[20][256];            // 10 KB
    __shared__ float cw[5];
    __shared__ float cb;

    const int p = blockIdx.x, tile = blockIdx.y, t = threadIdx.x;
    const int kw0 = tile * 16;
    const int nl = min(16, WF - kw0);            // 16 (tiles 0..7) or 1 (tile 8)
    const int c = p & (C_-1);
    const float2* Sp = S + (size_t)p*WF*H_;

    // per-lane register twiddles: stage s L in {4,16,64}, j = bq & (L-1)
    const int bq = t & 63;
    float2 w1a,w2a,w3a, w1b,w2b,w3b, w1c,w2c,w3c;
    {
        float sv, cv;
        float a1 = -2.f*PI_F*(float)(bq & 3)  / 16.f;
        float a2 = -2.f*PI_F*(float)(bq & 15) / 64.f;
        float a3 = -2.f*PI_F*(float)(bq & 63) / 256.f;
        sincosf(a1,      &sv,&cv); w1a = make_float2(cv,sv);
        sincosf(2.f*a1,  &sv,&cv); w2a = make_float2(cv,sv);
        sincosf(3.f*a1,  &sv,&cv); w3a = make_float2(cv,sv);
        sincosf(a2,      &sv,&cv); w1b = make_float2(cv,sv);
        sincosf(2.f*a2,  &sv,&cv); w2b = make_float2(cv,sv);
        sincosf(3.f*a2,  &sv,&cv); w3b = make_float2(cv,sv);
        sincosf(a3,      &sv,&cv); w1c = make_float2(cv,sv);
        sincosf(2.f*a3,  &sv,&cv); w2c = make_float2(cv,sv);
        sincosf(3.f*a3,  &sv,&cv); w3c = make_float2(cv,sv);
    }
    if (t < 5)  cw[t] = fw[c*5 + t];
    if (t == 5) cb = fb[c];

    // forward stage macros -----------------------------------------------
    #define FWD_S0(NL)                                                        \
    for (int idx = t; idx < (NL)*64; idx += 256){                             \
        int ln = idx >> 6, b = idx & 63;                                      \
        int pb = 4*(b ^ ((b >> 2) & 3));                                      \
        float4 lo = *(const float4*)&zc[ln][pb];                              \
        float4 hi = *(const float4*)&zc[ln][pb+2];                            \
        float2 y0,y1,y2,y3;                                                   \
        bf4f(make_float2(lo.x,lo.y), make_float2(lo.z,lo.w),                  \
             make_float2(hi.x,hi.y), make_float2(hi.z,hi.w), y0,y1,y2,y3);    \
        *(float4*)&zc[ln][pb]   = make_float4(y0.x,y0.y,y1.x,y1.y);           \
        *(float4*)&zc[ln][pb+2] = make_float4(y2.x,y2.y,y3.x,y3.y);           \
    }                                                                         \
    __syncthreads();

    #define FWD_SMID(NL, LL, W1, W2, W3)                                      \
    for (int idx = t; idx < (NL)*64; idx += 256){                             \
        int ln = idx >> 6;                                                    \
        int j = bq & ((LL)-1);                                                \
        int p0 = ((bq / (LL)) * (4*(LL))) + j;                                \
        float2 u0 = zc[ln][PI4(p0)];                                          \
        float2 v1 = cmulf(zc[ln][PI4(p0+(LL))],   W1);                        \
        float2 v2 = cmulf(zc[ln][PI4(p0+2*(LL))], W2);                        \
        float2 v3 = cmulf(zc[ln][PI4(p0+3*(LL))], W3);                        \
        float2 y0,y1,y2,y3; bf4f(u0,v1,v2,v3,y0,y1,y2,y3);                    \
        zc[ln][PI4(p0)]          = y0;                                        \
        zc[ln][PI4(p0+(LL))]     = y1;                                        \
        zc[ln][PI4(p0+2*(LL))]   = y2;                                        \
        zc[ln][PI4(p0+3*(LL))]   = y3;                                        \
    }                                                                         \
    __syncthreads();

    // stage 3 (L=64): p0 = bq, outputs land at natural h = bq + 64r -> fuse mag
    #define FWD_S3_MAG(NL, MROW)                                              \
    for (int idx = t; idx < (NL)*64; idx += 256){                             \
        int ln = idx >> 6;                                                    \
        float2 u0 = zc[ln][PI4(bq)];                                          \
        float2 v1 = cmulf(zc[ln][PI4(bq+64)],  w1c);                          \
        float2 v2 = cmulf(zc[ln][PI4(bq+128)], w2c);                          \
        float2 v3 = cmulf(zc[ln][PI4(bq+192)], w3c);                          \
        float2 y0,y1,y2,y3; bf4f(u0,v1,v2,v3,y0,y1,y2,y3);                    \
        zc[ln][PI4(bq)]     = y0;                                             \
        zc[ln][PI4(bq+64)]  = y1;                                             \
        zc[ln][PI4(bq+128)] = y2;                                             \
        zc[ln][PI4(bq+192)] = y3;                                             \
        int mrow = (MROW);                                                    \
        mag[mrow][bq]     = (_Float16)sqrtf(y0.x*y0.x + y0.y*y0.y);           \
        mag[mrow][bq+64]  = (_Float16)sqrtf(y1.x*y1.x + y1.y*y1.y);           \
        mag[mrow][bq+128] = (_Float16)sqrtf(y2.x*y2.x + y2.y*y2.y);           \
        mag[mrow][bq+192] = (_Float16)sqrtf(y3.x*y3.x + y3.y*y3.y);           \
    }                                                                         \
    __syncthreads();

    // ================= forward FFT of 4 halo lines =========================
    for (int idx = t; idx < 4*256; idx += 256){
        int ln = idx >> 8, u = idx & 255;
        int h = ((u & 3) << 6) | (u >> 2);
        int kwa = (ln < 2) ? (kw0 - 2 + ln) : (kw0 + nl + ln - 2);
        int phys = kwa < 0 ? kwa + WF : (kwa > 128 ? kwa - WF : kwa);
        zc[ln][PI4(dr4(h))] = Sp[(size_t)phys*H_ + h];
    }
    __syncthreads();
    FWD_S0(4)
    FWD_SMID(4, 4,  w1a, w2a, w3a)
    FWD_SMID(4, 16, w1b, w2b, w3b)
    FWD_S3_MAG(4, (ln < 2) ? ln : (nl + ln))

    // ================= forward FFT of nl owned lines =======================
    for (int idx = t; idx < nl*256; idx += 256){
        int ln = idx >> 8, u = idx & 255;
        int h = ((u & 3) << 6) | (u >> 2);
        zc[ln][PI4(dr4(h))] = Sp[(size_t)(kw0+ln)*H_ + h];
    }
    __syncthreads();
    FWD_S0(nl)
    FWD_SMID(nl, 4,  w1a, w2a, w3a)
    FWD_SMID(nl, 16, w1b, w2b, w3b)
    FWD_S3_MAG(nl, 2 + ln)

    // ================= conv(K=5) + sigmoid -> weight in place ==============
    for (int idx = t; idx < nl*256; idx += 256){
        int ln = idx >> 8, h = idx & 255;
        int kw = kw0 + ln;
        float acc = cb;
        #pragma unroll
        for (int d = 0; d < 5; ++d){
            int kwa = kw + d - 2;
            int L = ln + d;
            int sh = (kwa < 0) ? -1 : (kwa > 128 ? 1 : 0);
            int h2 = h + sh;
            if (h2 >= 0 && h2 < H_) acc += (float)mag[L][h2] * cw[d];
        }
        float g = 1.f + 1.f/(1.f + __expf(-acc));
        int hp = PI4(h);
        float2 v = zc[ln][hp];
        zc[ln][hp] = make_float2(v.x*g, v.y*g);
    }
    __syncthreads();

    // ================= inverse FFT: radix-4 DIF, natural in -> dr4 out =====
    #define INV_SMID(NL, LL, W1, W2, W3)                                      \
    for (int idx = t; idx < (NL)*64; idx += 256){                             \
        int ln = idx >> 6;                                                    \
        int j = bq & ((LL)-1);                                                \
        int p0 = ((bq / (LL)) * (4*(LL))) + j;                                \
        float2 u0 = zc[ln][PI4(p0)];                                          \
        float2 u1 = zc[ln][PI4(p0+(LL))];                                     \
        float2 u2 = zc[ln][PI4(p0+2*(LL))];                                   \
        float2 u3 = zc[ln][PI4(p0+3*(LL))];                                   \
        float2 t0,t1,t2,t3; bf4i(u0,u1,u2,u3,t0,t1,t2,t3);                    \
        zc[ln][PI4(p0)]        = t0;                                          \
        zc[ln][PI4(p0+(LL))]   = cmulcf(t1, W1);                              \
        zc[ln][PI4(p0+2*(LL))] = cmulcf(t2, W2);                              \
        zc[ln][PI4(p0+3*(LL))] = cmulcf(t3, W3);                              \
    }                                                                         \
    __syncthreads();

    INV_SMID(nl, 64, w1c, w2c, w3c)
    INV_SMID(nl, 16, w1b, w2b, w3b)
    INV_SMID(nl, 4,  w1a, w2a, w3a)
    // s=0: b128, no twiddle
    for (int idx = t; idx < nl*64; idx += 256){
        int ln = idx >> 6, b = idx & 63;
        int pb = 4*(b ^ ((b >> 2) & 3));
        float4 lo = *(const float4*)&zc[ln][pb];
        float4 hi = *(const float4*)&zc[ln][pb+2];
        float2 t0,t1,t2,t3;
        bf4i(make_float2(lo.x,lo.y), make_float2(lo.z,lo.w),
             make_float2(hi.x,hi.y), make_float2(hi.z,hi.w), t0,t1,t2,t3);
        *(float4*)&zc[ln][pb]   = make_float4(t0.x,t0.y,t1.x,t1.y);
        *(float4*)&zc[ln][pb+2] = make_float4(t2.x,t2.y,t3.x,t3.y);
    }
    __syncthreads();

    // store: out[h] = z[dr4(h)]; kw<128 -> D, kw==128 -> Sx
    float2* Dp  = D  + (size_t)p*128*H_;
    float2* Sxp = Sx + (size_t)p*H_;
    for (int idx = t; idx < nl*256; idx += 256){
        int ln = idx >> 8, u = idx & 255;
        int h = ((u & 3) << 6) | (u >> 2);
        float2 v = zc[ln][PI4(dr4(h))];
        int kw = kw0 + ln;
        if (kw < 128) Dp[(size_t)kw*H_ + h] = v;
        else          Sxp[h] = v;
    }
    #undef FWD_S0
    #undef FWD_SMID
    #undef FWD_S3_MAG
    #undef INV_SMID
}

// ---------------------------------------------------------------------------
// K5: inverse row transform (Hermitian two-for-one).
// (R6 + float2-packed twiddle table)
// ---------------------------------------------------------------------------
__global__ void k5_irow(const float2* __restrict__ D, const float2* __restrict__ Sx,
                        float* __restrict__ enh){
    __shared__ float sr[WF][17], si[WF][17];
    __shared__ float zr[8][256], zi[8][256];
    __shared__ float2 twf[128];

    const int p = blockIdx.x, tile = blockIdx.y, t = threadIdx.x;
    const int h0 = tile * 16;
    const float2* Dp  = D  + (size_t)p*128*H_;
    const float2* Sxp = Sx + (size_t)p*H_;

    if (t < 128){
        float sv, cv; sincosf(PI_F * (float)t / 128.f, &sv, &cv);
        twf[t] = make_float2(cv, sv);
    }
    for (int idx = t; idx < WF*16; idx += 256){
        int kw = idx >> 4, hh = idx & 15;
        float2 v = (kw < 128) ? Dp[(size_t)kw*H_ + h0 + hh] : Sxp[h0 + hh];
        sr[kw][hh] = v.x; si[kw][hh] = v.y;
    }
    __syncthreads();

    const int q = t >> 5, l = t & 31;
    #pragma unroll
    for (int it = 0; it < 8; ++it){
        int k = l + 32*it;
        float Ar, Ai, Br2, Bi;
        if (k <= 128){
            Ar = sr[k][2*q];  Ai = si[k][2*q];
            Br2 = sr[k][2*q+1]; Bi = si[k][2*q+1];
        } else {
            int kk = 256 - k;
            Ar = sr[kk][2*q];  Ai = -si[kk][2*q];
            Br2 = sr[kk][2*q+1]; Bi = -si[kk][2*q+1];
        }
        unsigned bk = SW(rev8((unsigned)k));
        zr[q][bk] = Ar - Bi;
        zi[q][bk] = Ai + Br2;
    }
    __syncthreads();

    for (int s = 0; s < 8; ++s){
        const int half = 1 << s;
        #pragma unroll
        for (int it = 0; it < 4; ++it){
            int b = l + 32*it;
            int j = b & (half-1);
            int i = ((b >> s) << (s+1)) + j;
            int k = j << (7 - s);
            int i0 = SW(i), i1 = SW(i+half);
            float2 w = twf[k];
            float ur = zr[q][i0], ui = zi[q][i0];
            float vr = zr[q][i1], vi = zi[q][i1];
            float tr = vr*w.x - vi*w.y, ti = vr*w.y + vi*w.x;
            zr[q][i0] = ur + tr;  zi[q][i0] = ui + ti;
            zr[q][i1] = ur - tr;  zi[q][i1] = ui - ti;
        }
        __syncthreads();
    }

    const float inv = 1.f / 256.f;
    float* ep = enh + (size_t)p*H_*W_ + (size_t)h0*W_;
    const int ts = SW(t);
    #pragma unroll
    for (int r = 0; r < 16; ++r){
        float v = (r & 1) ? zi[r>>1][ts] : zr[r>>1][ts];
        ep[r*W_ + t] = v * inv;
    }
}

// ---------------------------------------------------------------------------
// K6: out = x + scale * (mix_w @ enh). (unchanged R6)
// ---------------------------------------------------------------------------
__global__ void k6_mix(const float* __restrict__ x, const float* __restrict__ mixw,
                       const float* __restrict__ scale, const float* __restrict__ enh,
                       float* __restrict__ out){
    __shared__ float Ml[64*64];

    const int b = blockIdx.x, pt = blockIdx.y, t = threadIdx.x;
    const int pix = pt * 256 + t;
    float* op = out + (size_t)b*C_*H_*W_;
    const float* xp = x + (size_t)b*C_*H_*W_;
    const float* ep = enh + (size_t)b*C_*H_*W_;

    for (int idx = t; idx < 64*64; idx += 256){
        int c = idx >> 6, o = idx & 63;
        Ml[idx] = mixw[o*64 + c];
    }
    __syncthreads();

    float acc[64];
    #pragma unroll
    for (int o = 0; o < 64; ++o) acc[o] = 0.f;

    for (int c = 0; c < 64; ++c){
        float v = ep[(size_t)c*H_*W_ + pix];
        const float4* Mr = (const float4*)&Ml[c*64];
        #pragma unroll
        for (int o4 = 0; o4 < 16; ++o4){
            float4 m = Mr[o4];
            acc[o4*4+0] += m.x * v;
            acc[o4*4+1] += m.y * v;
            acc[o4*4+2] += m.z * v;
            acc[o4*4+3] += m.w * v;
        }
    }
    const float sc = scale[0];
    #pragma unroll
    for (int o = 0; o < 64; ++o){
        size_t ix = (size_t)o*H_*W_ + pix;
        op[ix] = xp[ix] + sc * acc[o];
    }
}

// ---------------------------------------------------------------------------
extern "C" void kernel_launch(void* const* d_in, const int* in_sizes, int n_in,
                              void* d_out, int out_size, void* d_ws, size_t ws_size,
                              hipStream_t stream){
    const float* x    = (const float*)d_in[0];
    const float* fw   = (const float*)d_in[1];
    const float* fb   = (const float*)d_in[2];
    const float* mixw = (const float*)d_in[3];
    const float* scal = (const float*)d_in[4];
    float* out = (float*)d_out;

    float2* S   = (float2*)d_ws;
    float2* Sx  = (float2*)((char*)d_ws + (size_t)P_*WF*H_*sizeof(float2));
    float*  enh = (float*)d_ws;   // reuses S region after k2f

    dim3 blk(256);
    k1_row_rfft <<<dim3(P_, H_/16), blk, 0, stream>>>(x, S);
    k2f_fused   <<<dim3(P_, 9),     blk, 0, stream>>>(S, (float2*)out, Sx, fw, fb);
    k5_irow     <<<dim3(P_, H_/16), blk, 0, stream>>>((const float2*)out, Sx, enh);
    k6_mix      <<<dim3(B_, 256),   blk, 0, stream>>>(x, mixw, scal, enh, out);
}

// Round 8
// 413.181 us; speedup vs baseline: 1.3046x; 1.0569x over previous
//
#include <hip/hip_runtime.h>
#include <math.h>

#define B_ 8
#define C_ 64
#define H_ 256
#define W_ 256
#define WF 129
#define P_ (B_*C_)      // 512 planes
#define PI_F 3.14159265358979323846f

__device__ __forceinline__ unsigned rev8(unsigned x){ return __brev(x) >> 24u; }
// radix-2 kernels (k1/k5) keep the SW swizzle
#define SW(i) ((i) ^ ((i) >> 5))

__device__ __forceinline__ float2 cmulf(float2 a, float2 w){
    return make_float2(a.x*w.x - a.y*w.y, a.x*w.y + a.y*w.x);
}
__device__ __forceinline__ float2 cmulK(float2 a, float wr, float wi){
    return make_float2(a.x*wr - a.y*wi, a.x*wi + a.y*wr);
}
// forward DFT4 butterfly (W4 = -i rotation)
__device__ __forceinline__ void bf4f(float2 u0, float2 u1, float2 u2, float2 u3,
                                     float2& y0, float2& y1, float2& y2, float2& y3){
    float2 P = make_float2(u0.x+u2.x, u0.y+u2.y);
    float2 M = make_float2(u0.x-u2.x, u0.y-u2.y);
    float2 Q = make_float2(u1.x+u3.x, u1.y+u3.y);
    float2 R = make_float2(u1.x-u3.x, u1.y-u3.y);
    y0 = make_float2(P.x+Q.x, P.y+Q.y);
    y2 = make_float2(P.x-Q.x, P.y-Q.y);
    y1 = make_float2(M.x+R.y, M.y-R.x);   // M + (-i)R
    y3 = make_float2(M.x-R.y, M.y+R.x);   // M + (+i)R
}
// inverse DFT4 butterfly (+i rotation)
__device__ __forceinline__ void bf4i(float2 u0, float2 u1, float2 u2, float2 u3,
                                     float2& y0, float2& y1, float2& y2, float2& y3){
    float2 P = make_float2(u0.x+u2.x, u0.y+u2.y);
    float2 M = make_float2(u0.x-u2.x, u0.y-u2.y);
    float2 Q = make_float2(u1.x+u3.x, u1.y+u3.y);
    float2 R = make_float2(u1.x-u3.x, u1.y-u3.y);
    y0 = make_float2(P.x+Q.x, P.y+Q.y);
    y2 = make_float2(P.x-Q.x, P.y-Q.y);
    y1 = make_float2(M.x-R.y, M.y+R.x);   // M + iR
    y3 = make_float2(M.x+R.y, M.y-R.x);   // M - iR
}

// full 16-point FFT in registers; radix-4 x 2, constant W16 twiddles.
// Verified: delta tests reproduce DFT16/IDFT16 exactly.
template<bool INV>
__device__ __forceinline__ void fft16r(float2* a){
    const float C1 = 0.92387953251128674f;   // cos(pi/8)
    const float S1 = 0.38268343236508978f;   // sin(pi/8)
    const float R2 = 0.70710678118654752f;
    float2 b[16];
    #pragma unroll
    for (int m0 = 0; m0 < 4; ++m0){
        float2 y0,y1,y2,y3;
        if (!INV) bf4f(a[m0], a[m0+4], a[m0+8], a[m0+12], y0,y1,y2,y3);
        else      bf4i(a[m0], a[m0+4], a[m0+8], a[m0+12], y0,y1,y2,y3);
        b[m0*4+0]=y0; b[m0*4+1]=y1; b[m0*4+2]=y2; b[m0*4+3]=y3;
    }
    const float sg = INV ? 1.f : -1.f;       // W16^k = (cos, sg*sin)
    b[5]  = cmulK(b[5],  C1,  sg*S1);        // W^1
    b[6]  = cmulK(b[6],  R2,  sg*R2);        // W^2
    b[7]  = cmulK(b[7],  S1,  sg*C1);        // W^3
    b[9]  = cmulK(b[9],  R2,  sg*R2);        // W^2
    b[10] = cmulK(b[10], 0.f, sg*1.f);       // W^4
    b[11] = cmulK(b[11], -R2, sg*R2);        // W^6
    b[13] = cmulK(b[13], S1,  sg*C1);        // W^3
    b[14] = cmulK(b[14], -R2, sg*R2);        // W^6
    b[15] = cmulK(b[15], -C1, -sg*S1);       // W^9
    #pragma unroll
    for (int r0 = 0; r0 < 4; ++r0){
        float2 y0,y1,y2,y3;
        if (!INV) bf4f(b[r0], b[4+r0], b[8+r0], b[12+r0], y0,y1,y2,y3);
        else      bf4i(b[r0], b[4+r0], b[8+r0], b[12+r0], y0,y1,y2,y3);
        a[r0]    = y0;
        a[r0+4]  = y1;
        a[r0+8]  = y2;
        a[r0+12] = y3;
    }
}

// ---------------------------------------------------------------------------
// K1: row rfft (two-for-one). grid (P_, H_/16), block 256. (unchanged R7)
// ---------------------------------------------------------------------------
__global__ void k1_row_rfft(const float* __restrict__ x, float2* __restrict__ S){
    __shared__ float zr[8][256], zi[8][256];
    __shared__ float2 twf[128];
    __shared__ float obr[WF][17], obi[WF][17];

    const int p = blockIdx.x, tile = blockIdx.y, t = threadIdx.x;
    const int h0 = tile * 16;
    const float* xp = x + (size_t)p*H_*W_ + (size_t)h0*W_;

    if (t < 128){
        float sv, cv; sincosf(-PI_F * (float)t / 128.f, &sv, &cv);
        twf[t] = make_float2(cv, sv);
    }
    const unsigned br = SW(rev8((unsigned)t));
    #pragma unroll
    for (int r = 0; r < 16; ++r){
        float v = xp[r*W_ + t];
        if (r & 1) zi[r>>1][br] = v; else zr[r>>1][br] = v;
    }
    __syncthreads();

    const int q = t >> 5, l = t & 31;
    for (int s = 0; s < 8; ++s){
        const int half = 1 << s;
        #pragma unroll
        for (int it = 0; it < 4; ++it){
            int b = l + 32*it;
            int j = b & (half-1);
            int i = ((b >> s) << (s+1)) + j;
            int k = j << (7 - s);
            int i0 = SW(i), i1 = SW(i+half);
            float2 w = twf[k];
            float ur = zr[q][i0], ui = zi[q][i0];
            float vr = zr[q][i1], vi = zi[q][i1];
            float tr = vr*w.x - vi*w.y, ti = vr*w.y + vi*w.x;
            zr[q][i0] = ur + tr;  zi[q][i0] = ui + ti;
            zr[q][i1] = ur - tr;  zi[q][i1] = ui - ti;
        }
        __syncthreads();
    }

    const float sc = 0.5f / 256.f;
    for (int kw = l; kw < WF; kw += 32){
        int km = (256 - kw) & 255;
        int kws = SW(kw), kms = SW(km);
        float Zr = zr[q][kws], Zi = zi[q][kws];
        float Yr = zr[q][kms], Yi = zi[q][kms];
        obr[kw][2*q]   = sc*(Zr + Yr);
        obi[kw][2*q]   = sc*(Zi - Yi);
        obr[kw][2*q+1] = sc*(Zi + Yi);
        obi[kw][2*q+1] = sc*(Yr - Zr);
    }
    __syncthreads();

    float2* Sp = S + (size_t)p*WF*H_;
    for (int idx = t; idx < WF*16; idx += 256){
        int kw = idx >> 4, hh = idx & 15;
        Sp[(size_t)kw*H_ + h0 + hh] = make_float2(obr[kw][hh], obi[kw][hh]);
    }
}

// ---------------------------------------------------------------------------
// K2F: fused col-FFT + mag + conv(K=5) + sigmoid + inverse col-FFT.
// 256 = 16x16 Cooley-Tukey: per-thread FFT16 in registers, LDS only for
// the two transposes per direction. All LDS patterns at bank floor
// (row pad 258; k0-block XOR swizzle on the transposed store).
// Reads S only; writes kw<128 -> D (d_out), kw==128 -> Sx. Race-free.
// grid (P_, 9), block 256.
// ---------------------------------------------------------------------------
__global__ void __launch_bounds__(256) k2f_fused(
        const float2* __restrict__ S, float2* __restrict__ D,
        float2* __restrict__ Sx, const float* __restrict__ fw,
        const float* __restrict__ fb){
    __shared__ float2 zc[16][258];        // 33.0 KB, padded rows
    __shared__ _Float16 mag[20][272];     // 10.9 KB, padded rows (+8 banks/row)
    __shared__ float cw[5];
    __shared__ float cb;

    const int p = blockIdx.x, tile = blockIdx.y, t = threadIdx.x;
    const int kw0 = tile*16;
    const int nl = min(16, WF - kw0);     // 16 (tiles 0..7) or 1 (tile 8)
    const int c = p & (C_-1);
    const float2* Sp = S + (size_t)p*WF*H_;
    if (t < 5)  cw[t] = fw[c*5 + t];
    if (t == 5) cb = fb[c];

    const int lhi = t >> 4;               // line (0..15)
    const int lo  = t & 15;               // sub-index within line

    // ======== halo: 4 lines -> mag rows 0,1,nl+2,nl+3 =======================
    for (int idx = t; idx < 4*256; idx += 256){
        int ln = idx >> 8, h = idx & 255;
        int kwa = (ln < 2) ? (kw0 - 2 + ln) : (kw0 + nl + ln - 2);
        int phys = kwa < 0 ? kwa + WF : (kwa > 128 ? kwa - WF : kwa);
        zc[ln][h] = Sp[(size_t)phys*H_ + h];
    }
    __syncthreads();
    {   // halo P1 (only 64 threads active; barriers block-wide)
        float2 a[16];
        const bool act = t < 64;
        if (act){
            #pragma unroll
            for (int n1 = 0; n1 < 16; ++n1) a[n1] = zc[lhi][lo + 16*n1];
            fft16r<false>(a);
            float sv, cv; sincosf(-2.f*PI_F*(float)lo/256.f, &sv, &cv);
            float2 wst = make_float2(cv, sv), w = make_float2(1.f, 0.f);
            #pragma unroll
            for (int k0 = 1; k0 < 16; ++k0){ w = cmulf(w, wst); a[k0] = cmulf(a[k0], w); }
        }
        __syncthreads();
        if (act){
            #pragma unroll
            for (int k0 = 0; k0 < 16; ++k0)
                zc[lhi][16*lo + (k0 ^ ((lo&3)<<2))] = a[k0];
        }
        __syncthreads();
    }
    {   // halo P2: FFT over n0 -> mag only
        float2 a[16];
        const bool act = t < 64;
        if (act){
            #pragma unroll
            for (int n0 = 0; n0 < 16; ++n0)
                a[n0] = zc[lhi][16*n0 + (lo ^ ((n0&3)<<2))];
            fft16r<false>(a);
            int mrow = (lhi < 2) ? lhi : (nl + lhi);
            #pragma unroll
            for (int k1 = 0; k1 < 16; ++k1)
                mag[mrow][lo + 16*k1] = (_Float16)sqrtf(a[k1].x*a[k1].x + a[k1].y*a[k1].y);
        }
        __syncthreads();                  // zc halo reads done before reuse
    }

    // ======== own nl lines: forward, conv, inverse ==========================
    for (int idx = t; idx < nl*256; idx += 256){
        int ln = idx >> 8, h = idx & 255;
        zc[ln][h] = Sp[(size_t)(kw0+ln)*H_ + h];
    }
    __syncthreads();
    {   // own P1: FFT16 over n1 (stride-16 read), twiddle, transposed write
        float2 a[16];
        const bool act = lhi < nl;
        if (act){
            #pragma unroll
            for (int n1 = 0; n1 < 16; ++n1) a[n1] = zc[lhi][lo + 16*n1];
            fft16r<false>(a);
            float sv, cv; sincosf(-2.f*PI_F*(float)lo/256.f, &sv, &cv);
            float2 wst = make_float2(cv, sv), w = make_float2(1.f, 0.f);
            #pragma unroll
            for (int k0 = 1; k0 < 16; ++k0){ w = cmulf(w, wst); a[k0] = cmulf(a[k0], w); }
        }
        __syncthreads();
        if (act){
            #pragma unroll
            for (int k0 = 0; k0 < 16; ++k0)
                zc[lhi][16*lo + (k0 ^ ((lo&3)<<2))] = a[k0];
        }
        __syncthreads();
    }
    {   // own P2: FFT16 over n0 -> X natural + mag
        float2 a[16];
        const bool act = lhi < nl;
        if (act){
            #pragma unroll
            for (int n0 = 0; n0 < 16; ++n0)
                a[n0] = zc[lhi][16*n0 + (lo ^ ((n0&3)<<2))];
            fft16r<false>(a);
        }
        __syncthreads();
        if (act){
            #pragma unroll
            for (int k1 = 0; k1 < 16; ++k1){
                zc[lhi][lo + 16*k1] = a[k1];
                mag[2+lhi][lo + 16*k1] =
                    (_Float16)sqrtf(a[k1].x*a[k1].x + a[k1].y*a[k1].y);
            }
        }
        __syncthreads();
    }

    // conv(K=5 over flat h*129+kw) + sigmoid -> weight in place
    for (int idx = t; idx < nl*256; idx += 256){
        int ln = idx >> 8, h = idx & 255;
        int kw = kw0 + ln;
        float acc = cb;
        #pragma unroll
        for (int d = 0; d < 5; ++d){
            int kwa = kw + d - 2;
            int L = ln + d;
            int sh = (kwa < 0) ? -1 : (kwa > 128 ? 1 : 0);
            int h2 = h + sh;
            if (h2 >= 0 && h2 < H_) acc += (float)mag[L][h2] * cw[d];
        }
        float g = 1.f + 1.f/(1.f + __expf(-acc));
        float2 v = zc[ln][h];
        zc[ln][h] = make_float2(v.x*g, v.y*g);
    }
    __syncthreads();

    {   // inv P1: IFFT16 over k1, conj twiddle, transposed write
        float2 a[16];
        const bool act = lhi < nl;
        if (act){
            #pragma unroll
            for (int k1 = 0; k1 < 16; ++k1) a[k1] = zc[lhi][lo + 16*k1];
            fft16r<true>(a);
            float sv, cv; sincosf(2.f*PI_F*(float)lo/256.f, &sv, &cv);
            float2 wst = make_float2(cv, sv), w = make_float2(1.f, 0.f);
            #pragma unroll
            for (int n0 = 1; n0 < 16; ++n0){ w = cmulf(w, wst); a[n0] = cmulf(a[n0], w); }
        }
        __syncthreads();
        if (act){
            #pragma unroll
            for (int n0 = 0; n0 < 16; ++n0)
                zc[lhi][16*lo + (n0 ^ ((lo&3)<<2))] = a[n0];
        }
        __syncthreads();
    }
    {   // inv P2: IFFT16 over k0 -> x[n0+16n1], store DIRECT to global
        float2 a[16];
        const bool act = lhi < nl;
        if (act){
            #pragma unroll
            for (int k0 = 0; k0 < 16; ++k0)
                a[k0] = zc[lhi][16*k0 + (lo ^ ((k0&3)<<2))];
            fft16r<true>(a);
            int kw = kw0 + lhi;
            if (kw < 128){
                float2* Dp = D + ((size_t)p*128 + kw)*H_;
                #pragma unroll
                for (int n1 = 0; n1 < 16; ++n1) Dp[lo + 16*n1] = a[n1];
            } else {
                float2* Sxp = Sx + (size_t)p*H_;
                #pragma unroll
                for (int n1 = 0; n1 < 16; ++n1) Sxp[lo + 16*n1] = a[n1];
            }
        }
    }
}

// ---------------------------------------------------------------------------
// K5: inverse row transform (Hermitian two-for-one). (unchanged R7)
// ---------------------------------------------------------------------------
__global__ void k5_irow(const float2* __restrict__ D, const float2* __restrict__ Sx,
                        float* __restrict__ enh){
    __shared__ float sr[WF][17], si[WF][17];
    __shared__ float zr[8][256], zi[8][256];
    __shared__ float2 twf[128];

    const int p = blockIdx.x, tile = blockIdx.y, t = threadIdx.x;
    const int h0 = tile * 16;
    const float2* Dp  = D  + (size_t)p*128*H_;
    const float2* Sxp = Sx + (size_t)p*H_;

    if (t < 128){
        float sv, cv; sincosf(PI_F * (float)t / 128.f, &sv, &cv);
        twf[t] = make_float2(cv, sv);
    }
    for (int idx = t; idx < WF*16; idx += 256){
        int kw = idx >> 4, hh = idx & 15;
        float2 v = (kw < 128) ? Dp[(size_t)kw*H_ + h0 + hh] : Sxp[h0 + hh];
        sr[kw][hh] = v.x; si[kw][hh] = v.y;
    }
    __syncthreads();

    const int q = t >> 5, l = t & 31;
    #pragma unroll
    for (int it = 0; it < 8; ++it){
        int k = l + 32*it;
        float Ar, Ai, Br2, Bi;
        if (k <= 128){
            Ar = sr[k][2*q];  Ai = si[k][2*q];
            Br2 = sr[k][2*q+1]; Bi = si[k][2*q+1];
        } else {
            int kk = 256 - k;
            Ar = sr[kk][2*q];  Ai = -si[kk][2*q];
            Br2 = sr[kk][2*q+1]; Bi = -si[kk][2*q+1];
        }
        unsigned bk = SW(rev8((unsigned)k));
        zr[q][bk] = Ar - Bi;
        zi[q][bk] = Ai + Br2;
    }
    __syncthreads();

    for (int s = 0; s < 8; ++s){
        const int half = 1 << s;
        #pragma unroll
        for (int it = 0; it < 4; ++it){
            int b = l + 32*it;
            int j = b & (half-1);
            int i = ((b >> s) << (s+1)) + j;
            int k = j << (7 - s);
            int i0 = SW(i), i1 = SW(i+half);
            float2 w = twf[k];
            float ur = zr[q][i0], ui = zi[q][i0];
            float vr = zr[q][i1], vi = zi[q][i1];
            float tr = vr*w.x - vi*w.y, ti = vr*w.y + vi*w.x;
            zr[q][i0] = ur + tr;  zi[q][i0] = ui + ti;
            zr[q][i1] = ur - tr;  zi[q][i1] = ui - ti;
        }
        __syncthreads();
    }

    const float inv = 1.f / 256.f;
    float* ep = enh + (size_t)p*H_*W_ + (size_t)h0*W_;
    const int ts = SW(t);
    #pragma unroll
    for (int r = 0; r < 16; ++r){
        float v = (r & 1) ? zi[r>>1][ts] : zr[r>>1][ts];
        ep[r*W_ + t] = v * inv;
    }
}

// ---------------------------------------------------------------------------
// K6: out = x + scale * (mix_w @ enh). (unchanged R7)
// ---------------------------------------------------------------------------
__global__ void k6_mix(const float* __restrict__ x, const float* __restrict__ mixw,
                       const float* __restrict__ scale, const float* __restrict__ enh,
                       float* __restrict__ out){
    __shared__ float Ml[64*64];

    const int b = blockIdx.x, pt = blockIdx.y, t = threadIdx.x;
    const int pix = pt * 256 + t;
    float* op = out + (size_t)b*C_*H_*W_;
    const float* xp = x + (size_t)b*C_*H_*W_;
    const float* ep = enh + (size_t)b*C_*H_*W_;

    for (int idx = t; idx < 64*64; idx += 256){
        int c = idx >> 6, o = idx & 63;
        Ml[idx] = mixw[o*64 + c];
    }
    __syncthreads();

    float acc[64];
    #pragma unroll
    for (int o = 0; o < 64; ++o) acc[o] = 0.f;

    for (int c = 0; c < 64; ++c){
        float v = ep[(size_t)c*H_*W_ + pix];
        const float4* Mr = (const float4*)&Ml[c*64];
        #pragma unroll
        for (int o4 = 0; o4 < 16; ++o4){
            float4 m = Mr[o4];
            acc[o4*4+0] += m.x * v;
            acc[o4*4+1] += m.y * v;
            acc[o4*4+2] += m.z * v;
            acc[o4*4+3] += m.w * v;
        }
    }
    const float sc = scale[0];
    #pragma unroll
    for (int o = 0; o < 64; ++o){
        size_t ix = (size_t)o*H_*W_ + pix;
        op[ix] = xp[ix] + sc * acc[o];
    }
}

// ---------------------------------------------------------------------------
extern "C" void kernel_launch(void* const* d_in, const int* in_sizes, int n_in,
                              void* d_out, int out_size, void* d_ws, size_t ws_size,
                              hipStream_t stream){
    const float* x    = (const float*)d_in[0];
    const float* fw   = (const float*)d_in[1];
    const float* fb   = (const float*)d_in[2];
    const float* mixw = (const float*)d_in[3];
    const float* scal = (const float*)d_in[4];
    float* out = (float*)d_out;

    float2* S   = (float2*)d_ws;
    float2* Sx  = (float2*)((char*)d_ws + (size_t)P_*WF*H_*sizeof(float2));
    float*  enh = (float*)d_ws;   // reuses S region after k2f

    dim3 blk(256);
    k1_row_rfft <<<dim3(P_, H_/16), blk, 0, stream>>>(x, S);
    k2f_fused   <<<dim3(P_, 9),     blk, 0, stream>>>(S, (float2*)out, Sx, fw, fb);
    k5_irow     <<<dim3(P_, H_/16), blk, 0, stream>>>((const float2*)out, Sx, enh);
    k6_mix      <<<dim3(B_, 256),   blk, 0, stream>>>(x, mixw, scal, enh, out);
}

// Round 9
// 357.799 us; speedup vs baseline: 1.5065x; 1.1548x over previous
//
#include <hip/hip_runtime.h>
#include <math.h>

#define B_ 8
#define C_ 64
#define H_ 256
#define W_ 256
#define WF 129
#define P_ (B_*C_)      // 512 planes
#define PI_F 3.14159265358979323846f

__device__ __forceinline__ float2 cmulf(float2 a, float2 w){
    return make_float2(a.x*w.x - a.y*w.y, a.x*w.y + a.y*w.x);
}
__device__ __forceinline__ float2 cmulK(float2 a, float wr, float wi){
    return make_float2(a.x*wr - a.y*wi, a.x*wi + a.y*wr);
}
// forward DFT4 butterfly (W4 = -i rotation)
__device__ __forceinline__ void bf4f(float2 u0, float2 u1, float2 u2, float2 u3,
                                     float2& y0, float2& y1, float2& y2, float2& y3){
    float2 P = make_float2(u0.x+u2.x, u0.y+u2.y);
    float2 M = make_float2(u0.x-u2.x, u0.y-u2.y);
    float2 Q = make_float2(u1.x+u3.x, u1.y+u3.y);
    float2 R = make_float2(u1.x-u3.x, u1.y-u3.y);
    y0 = make_float2(P.x+Q.x, P.y+Q.y);
    y2 = make_float2(P.x-Q.x, P.y-Q.y);
    y1 = make_float2(M.x+R.y, M.y-R.x);   // M + (-i)R
    y3 = make_float2(M.x-R.y, M.y+R.x);   // M + (+i)R
}
// inverse DFT4 butterfly (+i rotation)
__device__ __forceinline__ void bf4i(float2 u0, float2 u1, float2 u2, float2 u3,
                                     float2& y0, float2& y1, float2& y2, float2& y3){
    float2 P = make_float2(u0.x+u2.x, u0.y+u2.y);
    float2 M = make_float2(u0.x-u2.x, u0.y-u2.y);
    float2 Q = make_float2(u1.x+u3.x, u1.y+u3.y);
    float2 R = make_float2(u1.x-u3.x, u1.y-u3.y);
    y0 = make_float2(P.x+Q.x, P.y+Q.y);
    y2 = make_float2(P.x-Q.x, P.y-Q.y);
    y1 = make_float2(M.x-R.y, M.y+R.x);   // M + iR
    y3 = make_float2(M.x+R.y, M.y-R.x);   // M - iR
}

// full 16-point FFT in registers; radix-4 x 2, constant W16 twiddles.
template<bool INV>
__device__ __forceinline__ void fft16r(float2* a){
    const float C1 = 0.92387953251128674f;   // cos(pi/8)
    const float S1 = 0.38268343236508978f;   // sin(pi/8)
    const float R2 = 0.70710678118654752f;
    float2 b[16];
    #pragma unroll
    for (int m0 = 0; m0 < 4; ++m0){
        float2 y0,y1,y2,y3;
        if (!INV) bf4f(a[m0], a[m0+4], a[m0+8], a[m0+12], y0,y1,y2,y3);
        else      bf4i(a[m0], a[m0+4], a[m0+8], a[m0+12], y0,y1,y2,y3);
        b[m0*4+0]=y0; b[m0*4+1]=y1; b[m0*4+2]=y2; b[m0*4+3]=y3;
    }
    const float sg = INV ? 1.f : -1.f;       // W16^k = (cos, sg*sin)
    b[5]  = cmulK(b[5],  C1,  sg*S1);
    b[6]  = cmulK(b[6],  R2,  sg*R2);
    b[7]  = cmulK(b[7],  S1,  sg*C1);
    b[9]  = cmulK(b[9],  R2,  sg*R2);
    b[10] = cmulK(b[10], 0.f, sg*1.f);
    b[11] = cmulK(b[11], -R2, sg*R2);
    b[13] = cmulK(b[13], S1,  sg*C1);
    b[14] = cmulK(b[14], -R2, sg*R2);
    b[15] = cmulK(b[15], -C1, -sg*S1);
    #pragma unroll
    for (int r0 = 0; r0 < 4; ++r0){
        float2 y0,y1,y2,y3;
        if (!INV) bf4f(b[r0], b[4+r0], b[8+r0], b[12+r0], y0,y1,y2,y3);
        else      bf4i(b[r0], b[4+r0], b[8+r0], b[12+r0], y0,y1,y2,y3);
        a[r0]    = y0;
        a[r0+4]  = y1;
        a[r0+8]  = y2;
        a[r0+12] = y3;
    }
}

// outer twiddle chain: a[k] *= W256^{±lo*k}
template<bool INV>
__device__ __forceinline__ void twchain(float2* a, int lo){
    float sv, cv; sincosf((INV ? 2.f : -2.f)*PI_F*(float)lo/256.f, &sv, &cv);
    float2 wst = make_float2(cv, sv), w = make_float2(1.f, 0.f);
    #pragma unroll
    for (int k = 1; k < 16; ++k){ w = cmulf(w, wst); a[k] = cmulf(a[k], w); }
}

// ---------------------------------------------------------------------------
// K1: row rfft (two-for-one), 16x16 register FFT. grid (P_, H_/32), block 256.
// Block owns 32 rows = 16 complex lines. Writes S[p][kw][h] (A,B as float4).
// ---------------------------------------------------------------------------
__global__ void __launch_bounds__(256) k1_row_rfft(const float* __restrict__ x,
                                                   float2* __restrict__ S){
    __shared__ float2 zc[16][258];   // 33 KB

    const int p = blockIdx.x, tile = blockIdx.y, t = threadIdx.x;
    const int h0 = tile * 32;
    const float* xp = x + (size_t)p*H_*W_ + (size_t)h0*W_;

    // load 32 rows as 16 complex lines: zc[q][n] = (row 2q, row 2q+1)
    #pragma unroll
    for (int q = 0; q < 16; ++q)
        zc[q][t] = make_float2(xp[(2*q)*W_ + t], xp[(2*q+1)*W_ + t]);
    __syncthreads();

    const int q = t >> 4, lo = t & 15;
    float2 a[16];
    // P1: FFT16 over n1, outer twiddle, transposed write
    #pragma unroll
    for (int n1 = 0; n1 < 16; ++n1) a[n1] = zc[q][lo + 16*n1];
    fft16r<false>(a);
    twchain<false>(a, lo);
    __syncthreads();
    #pragma unroll
    for (int k0 = 0; k0 < 16; ++k0) zc[q][16*lo + (k0 ^ ((lo&3)<<2))] = a[k0];
    __syncthreads();
    // P2: FFT16 over n0 -> Z[lo + 16k1]
    #pragma unroll
    for (int n0 = 0; n0 < 16; ++n0) a[n0] = zc[q][16*n0 + (lo ^ ((n0&3)<<2))];
    fft16r<false>(a);
    __syncthreads();
    #pragma unroll
    for (int k1 = 0; k1 < 16; ++k1) zc[q][lo + 16*k1] = a[k1];   // natural order
    __syncthreads();

    // unpack two-for-one + store (A,B) pairs as float4; fold ortho 1/256
    const float sc = 0.5f / 256.f;
    float2* Sp = S + (size_t)p*WF*H_;
    for (int idx = t; idx < WF*16; idx += 256){
        int kw = idx >> 4, qq = idx & 15;
        float2 Z = zc[qq][kw];
        float2 Y = zc[qq][(256-kw)&255];
        float4 o;
        o.x = sc*(Z.x + Y.x);   // A.re  (row 2qq)
        o.y = sc*(Z.y - Y.y);   // A.im
        o.z = sc*(Z.y + Y.y);   // B.re  (row 2qq+1)
        o.w = sc*(Y.x - Z.x);   // B.im
        *(float4*)&Sp[(size_t)kw*H_ + h0 + 2*qq] = o;
    }
}

// ---------------------------------------------------------------------------
// K2F: fused col-FFT + mag + conv(K=5) + sigmoid + inverse col-FFT.
// 16x16 register FFT; halo lines merged into the main pass (wave 0 carries a
// second register task; lo identical for both tasks). Reads S only; writes
// kw<128 -> D (d_out), kw==128 -> Sx. Race-free. grid (P_, 9), block 256.
// ---------------------------------------------------------------------------
__global__ void __launch_bounds__(256) k2f_fused(
        const float2* __restrict__ S, float2* __restrict__ D,
        float2* __restrict__ Sx, const float* __restrict__ fw,
        const float* __restrict__ fb){
    __shared__ float2 zc[20][258];        // 41.3 KB
    __shared__ _Float16 mag[20][272];     // 10.9 KB
    __shared__ float cw[5];
    __shared__ float cb;

    const int p = blockIdx.x, tile = blockIdx.y, t = threadIdx.x;
    const int kw0 = tile*16;
    const int nl = min(16, WF - kw0);     // 16 (tiles 0..7) or 1 (tile 8)
    const int NL = nl + 4;                // own + 4 halo lines
    const int c = p & (C_-1);
    const float2* Sp = S + (size_t)p*WF*H_;
    if (t < 5)  cw[t] = fw[c*5 + t];
    if (t == 5) cb = fb[c];

    // load NL lines: line ll <-> kwa = kw0 + ll - 2 (wrap mod 129)
    for (int idx = t; idx < NL*256; idx += 256){
        int ll = idx >> 8, h = idx & 255;
        int kwa = kw0 + ll - 2;
        int phys = kwa < 0 ? kwa + WF : (kwa > 128 ? kwa - WF : kwa);
        zc[ll][h] = Sp[(size_t)phys*H_ + h];
    }
    __syncthreads();

    const int lo = t & 15;
    const int lA = t >> 4;                // 0..15
    const int lB = 16 + (t >> 4);         // 16..31
    const bool hA = lA < NL;
    const bool hB = lB < NL;              // only wave 0 (t<64) when NL=20

    float2 aA[16], aB[16];
    // ---- forward P1: FFT16 over n1 + outer twiddle + transposed write ----
    if (hA){
        #pragma unroll
        for (int n1 = 0; n1 < 16; ++n1) aA[n1] = zc[lA][lo + 16*n1];
        fft16r<false>(aA); twchain<false>(aA, lo);
    }
    if (hB){
        #pragma unroll
        for (int n1 = 0; n1 < 16; ++n1) aB[n1] = zc[lB][lo + 16*n1];
        fft16r<false>(aB); twchain<false>(aB, lo);
    }
    __syncthreads();
    if (hA){
        #pragma unroll
        for (int k0 = 0; k0 < 16; ++k0) zc[lA][16*lo + (k0 ^ ((lo&3)<<2))] = aA[k0];
    }
    if (hB){
        #pragma unroll
        for (int k0 = 0; k0 < 16; ++k0) zc[lB][16*lo + (k0 ^ ((lo&3)<<2))] = aB[k0];
    }
    __syncthreads();
    // ---- forward P2: FFT16 over n0 -> spectrum (natural) + mag ----
    if (hA){
        #pragma unroll
        for (int n0 = 0; n0 < 16; ++n0) aA[n0] = zc[lA][16*n0 + (lo ^ ((n0&3)<<2))];
        fft16r<false>(aA);
    }
    if (hB){
        #pragma unroll
        for (int n0 = 0; n0 < 16; ++n0) aB[n0] = zc[lB][16*n0 + (lo ^ ((n0&3)<<2))];
        fft16r<false>(aB);
    }
    __syncthreads();
    if (hA){
        #pragma unroll
        for (int k1 = 0; k1 < 16; ++k1){
            zc[lA][lo + 16*k1] = aA[k1];
            mag[lA][lo + 16*k1] = (_Float16)sqrtf(aA[k1].x*aA[k1].x + aA[k1].y*aA[k1].y);
        }
    }
    if (hB){
        #pragma unroll
        for (int k1 = 0; k1 < 16; ++k1){
            zc[lB][lo + 16*k1] = aB[k1];
            mag[lB][lo + 16*k1] = (_Float16)sqrtf(aB[k1].x*aB[k1].x + aB[k1].y*aB[k1].y);
        }
    }
    __syncthreads();

    // ---- conv(K=5 over flat h*129+kw) + sigmoid -> weight own lines ----
    // own line ln lives at zc/mag row ln+2; taps hit mag rows ln..ln+4.
    for (int idx = t; idx < nl*256; idx += 256){
        int ln = idx >> 8, h = idx & 255;
        int kw = kw0 + ln;
        float acc = cb;
        #pragma unroll
        for (int d = 0; d < 5; ++d){
            int kwa = kw + d - 2;
            int L = ln + d;
            int sh = (kwa < 0) ? -1 : (kwa > 128 ? 1 : 0);
            int h2 = h + sh;
            if (h2 >= 0 && h2 < H_) acc += (float)mag[L][h2] * cw[d];
        }
        float g = 1.f + 1.f/(1.f + __expf(-acc));
        float2 v = zc[ln+2][h];
        zc[ln+2][h] = make_float2(v.x*g, v.y*g);
    }
    __syncthreads();

    // ---- inverse: own lines only (<=16 -> single task/thread) ----
    const bool hI = (t >> 4) < nl;
    const int  lI = (t >> 4) + 2;
    if (hI){
        #pragma unroll
        for (int k1 = 0; k1 < 16; ++k1) aA[k1] = zc[lI][lo + 16*k1];
        fft16r<true>(aA); twchain<true>(aA, lo);
    }
    __syncthreads();
    if (hI){
        #pragma unroll
        for (int n0 = 0; n0 < 16; ++n0) zc[lI][16*lo + (n0 ^ ((lo&3)<<2))] = aA[n0];
    }
    __syncthreads();
    if (hI){
        #pragma unroll
        for (int k0 = 0; k0 < 16; ++k0) aA[k0] = zc[lI][16*k0 + (lo ^ ((k0&3)<<2))];
        fft16r<true>(aA);
        int kw = kw0 + (t >> 4);
        if (kw < 128){
            float2* Dp = D + ((size_t)p*128 + kw)*H_;
            #pragma unroll
            for (int n1 = 0; n1 < 16; ++n1) Dp[lo + 16*n1] = aA[n1];
        } else {
            float2* Sxp = Sx + (size_t)p*H_;
            #pragma unroll
            for (int n1 = 0; n1 < 16; ++n1) Sxp[lo + 16*n1] = aA[n1];
        }
    }
}

// ---------------------------------------------------------------------------
// K5: inverse row transform (Hermitian two-for-one), 16x16 register FFT.
// grid (P_, H_/32), block 256. Reads D (d_out) + Sx, writes enh (ws).
// ---------------------------------------------------------------------------
__global__ void __launch_bounds__(256) k5_irow(const float2* __restrict__ D,
                                               const float2* __restrict__ Sx,
                                               float* __restrict__ enh){
    __shared__ float2 zc[16][258];   // 33 KB

    const int p = blockIdx.x, tile = blockIdx.y, t = threadIdx.x;
    const int h0 = tile * 32;
    const float2* Dp  = D  + (size_t)p*128*H_;
    const float2* Sxp = Sx + (size_t)p*H_;

    // pack: z[kw] = A + iB, z[256-kw] = conj(A) + i conj(B)
    for (int idx = t; idx < WF*16; idx += 256){
        int kw = idx >> 4, qq = idx & 15;
        const float2* src = (kw < 128) ? (Dp + (size_t)kw*H_) : Sxp;
        float4 ab = *(const float4*)&src[h0 + 2*qq];   // A=(x,y) B=(z,w)
        zc[qq][kw] = make_float2(ab.x - ab.w, ab.y + ab.z);
        if (kw > 0 && kw < 128)
            zc[qq][256-kw] = make_float2(ab.x + ab.w, ab.z - ab.y);
    }
    __syncthreads();

    const int q = t >> 4, lo = t & 15;
    float2 a[16];
    // P1: IFFT16 over k1 + conj outer twiddle + transposed write
    #pragma unroll
    for (int k1 = 0; k1 < 16; ++k1) a[k1] = zc[q][lo + 16*k1];
    fft16r<true>(a);
    twchain<true>(a, lo);
    __syncthreads();
    #pragma unroll
    for (int n0 = 0; n0 < 16; ++n0) zc[q][16*lo + (n0 ^ ((lo&3)<<2))] = a[n0];
    __syncthreads();
    // P2: IFFT16 over k0 -> x[lo + 16n1] (rows 2q / 2q+1 in re/im)
    #pragma unroll
    for (int k0 = 0; k0 < 16; ++k0) a[k0] = zc[q][16*k0 + (lo ^ ((k0&3)<<2))];
    fft16r<true>(a);
    __syncthreads();
    #pragma unroll
    for (int n1 = 0; n1 < 16; ++n1) zc[q][lo + 16*n1] = a[n1];   // natural order
    __syncthreads();

    const float inv = 1.f / 256.f;
    float* ep = enh + (size_t)p*H_*W_ + (size_t)h0*W_;
    #pragma unroll
    for (int qq = 0; qq < 16; ++qq){
        float2 v = zc[qq][t];
        ep[(2*qq)*W_ + t]   = v.x * inv;
        ep[(2*qq+1)*W_ + t] = v.y * inv;
    }
}

// ---------------------------------------------------------------------------
// K6: out = x + scale * (mix_w @ enh). (unchanged R8)
// ---------------------------------------------------------------------------
__global__ void k6_mix(const float* __restrict__ x, const float* __restrict__ mixw,
                       const float* __restrict__ scale, const float* __restrict__ enh,
                       float* __restrict__ out){
    __shared__ float Ml[64*64];

    const int b = blockIdx.x, pt = blockIdx.y, t = threadIdx.x;
    const int pix = pt * 256 + t;
    float* op = out + (size_t)b*C_*H_*W_;
    const float* xp = x + (size_t)b*C_*H_*W_;
    const float* ep = enh + (size_t)b*C_*H_*W_;

    for (int idx = t; idx < 64*64; idx += 256){
        int c = idx >> 6, o = idx & 63;
        Ml[idx] = mixw[o*64 + c];
    }
    __syncthreads();

    float acc[64];
    #pragma unroll
    for (int o = 0; o < 64; ++o) acc[o] = 0.f;

    for (int c = 0; c < 64; ++c){
        float v = ep[(size_t)c*H_*W_ + pix];
        const float4* Mr = (const float4*)&Ml[c*64];
        #pragma unroll
        for (int o4 = 0; o4 < 16; ++o4){
            float4 m = Mr[o4];
            acc[o4*4+0] += m.x * v;
            acc[o4*4+1] += m.y * v;
            acc[o4*4+2] += m.z * v;
            acc[o4*4+3] += m.w * v;
        }
    }
    const float sc = scale[0];
    #pragma unroll
    for (int o = 0; o < 64; ++o){
        size_t ix = (size_t)o*H_*W_ + pix;
        op[ix] = xp[ix] + sc * acc[o];
    }
}

// ---------------------------------------------------------------------------
extern "C" void kernel_launch(void* const* d_in, const int* in_sizes, int n_in,
                              void* d_out, int out_size, void* d_ws, size_t ws_size,
                              hipStream_t stream){
    const float* x    = (const float*)d_in[0];
    const float* fw   = (const float*)d_in[1];
    const float* fb   = (const float*)d_in[2];
    const float* mixw = (const float*)d_in[3];
    const float* scal = (const float*)d_in[4];
    float* out = (float*)d_out;

    float2* S   = (float2*)d_ws;
    float2* Sx  = (float2*)((char*)d_ws + (size_t)P_*WF*H_*sizeof(float2));
    float*  enh = (float*)d_ws;   // reuses S region after k2f

    dim3 blk(256);
    k1_row_rfft <<<dim3(P_, H_/32), blk, 0, stream>>>(x, S);
    k2f_fused   <<<dim3(P_, 9),     blk, 0, stream>>>(S, (float2*)out, Sx, fw, fb);
    k5_irow     <<<dim3(P_, H_/32), blk, 0, stream>>>((const float2*)out, Sx, enh);
    k6_mix      <<<dim3(B_, 256),   blk, 0, stream>>>(x, mixw, scal, enh, out);
}

// Round 10
// 295.505 us; speedup vs baseline: 1.8241x; 1.2108x over previous
//
#include <hip/hip_runtime.h>
#include <math.h>

#define B_ 8
#define C_ 64
#define H_ 256
#define W_ 256
#define WF 129
#define P_ (B_*C_)      // 512 planes
#define PI_F 3.14159265358979323846f

typedef _Float16 f16;
struct h2 { f16 x, y; };          // 4 B
struct h4 { f16 x, y, z, w; };    // 8 B

__device__ __forceinline__ float2 cmulf(float2 a, float2 w){
    return make_float2(a.x*w.x - a.y*w.y, a.x*w.y + a.y*w.x);
}
__device__ __forceinline__ float2 cmulK(float2 a, float wr, float wi){
    return make_float2(a.x*wr - a.y*wi, a.x*wi + a.y*wr);
}
// forward DFT4 butterfly (W4 = -i rotation)
__device__ __forceinline__ void bf4f(float2 u0, float2 u1, float2 u2, float2 u3,
                                     float2& y0, float2& y1, float2& y2, float2& y3){
    float2 P = make_float2(u0.x+u2.x, u0.y+u2.y);
    float2 M = make_float2(u0.x-u2.x, u0.y-u2.y);
    float2 Q = make_float2(u1.x+u3.x, u1.y+u3.y);
    float2 R = make_float2(u1.x-u3.x, u1.y-u3.y);
    y0 = make_float2(P.x+Q.x, P.y+Q.y);
    y2 = make_float2(P.x-Q.x, P.y-Q.y);
    y1 = make_float2(M.x+R.y, M.y-R.x);   // M + (-i)R
    y3 = make_float2(M.x-R.y, M.y+R.x);   // M + (+i)R
}
// inverse DFT4 butterfly (+i rotation)
__device__ __forceinline__ void bf4i(float2 u0, float2 u1, float2 u2, float2 u3,
                                     float2& y0, float2& y1, float2& y2, float2& y3){
    float2 P = make_float2(u0.x+u2.x, u0.y+u2.y);
    float2 M = make_float2(u0.x-u2.x, u0.y-u2.y);
    float2 Q = make_float2(u1.x+u3.x, u1.y+u3.y);
    float2 R = make_float2(u1.x-u3.x, u1.y-u3.y);
    y0 = make_float2(P.x+Q.x, P.y+Q.y);
    y2 = make_float2(P.x-Q.x, P.y-Q.y);
    y1 = make_float2(M.x-R.y, M.y+R.x);   // M + iR
    y3 = make_float2(M.x+R.y, M.y-R.x);   // M - iR
}

// full 16-point FFT in registers; radix-4 x 2, constant W16 twiddles.
template<bool INV>
__device__ __forceinline__ void fft16r(float2* a){
    const float C1 = 0.92387953251128674f;   // cos(pi/8)
    const float S1 = 0.38268343236508978f;   // sin(pi/8)
    const float R2 = 0.70710678118654752f;
    float2 b[16];
    #pragma unroll
    for (int m0 = 0; m0 < 4; ++m0){
        float2 y0,y1,y2,y3;
        if (!INV) bf4f(a[m0], a[m0+4], a[m0+8], a[m0+12], y0,y1,y2,y3);
        else      bf4i(a[m0], a[m0+4], a[m0+8], a[m0+12], y0,y1,y2,y3);
        b[m0*4+0]=y0; b[m0*4+1]=y1; b[m0*4+2]=y2; b[m0*4+3]=y3;
    }
    const float sg = INV ? 1.f : -1.f;       // W16^k = (cos, sg*sin)
    b[5]  = cmulK(b[5],  C1,  sg*S1);
    b[6]  = cmulK(b[6],  R2,  sg*R2);
    b[7]  = cmulK(b[7],  S1,  sg*C1);
    b[9]  = cmulK(b[9],  R2,  sg*R2);
    b[10] = cmulK(b[10], 0.f, sg*1.f);
    b[11] = cmulK(b[11], -R2, sg*R2);
    b[13] = cmulK(b[13], S1,  sg*C1);
    b[14] = cmulK(b[14], -R2, sg*R2);
    b[15] = cmulK(b[15], -C1, -sg*S1);
    #pragma unroll
    for (int r0 = 0; r0 < 4; ++r0){
        float2 y0,y1,y2,y3;
        if (!INV) bf4f(b[r0], b[4+r0], b[8+r0], b[12+r0], y0,y1,y2,y3);
        else      bf4i(b[r0], b[4+r0], b[8+r0], b[12+r0], y0,y1,y2,y3);
        a[r0]    = y0;
        a[r0+4]  = y1;
        a[r0+8]  = y2;
        a[r0+12] = y3;
    }
}

// outer twiddle chain: a[k] *= W256^{±lo*k}
template<bool INV>
__device__ __forceinline__ void twchain(float2* a, int lo){
    float sv, cv; sincosf((INV ? 2.f : -2.f)*PI_F*(float)lo/256.f, &sv, &cv);
    float2 wst = make_float2(cv, sv), w = make_float2(1.f, 0.f);
    #pragma unroll
    for (int k = 1; k < 16; ++k){ w = cmulf(w, wst); a[k] = cmulf(a[k], w); }
}

// ---------------------------------------------------------------------------
// K1: row rfft (two-for-one), 16x16 register FFT. grid (P_, H_/32), block 256.
// Writes S[p][kw][h] as f16 pairs (A,B packed as h4), folds ortho 1/256.
// ---------------------------------------------------------------------------
__global__ void __launch_bounds__(256) k1_row_rfft(const float* __restrict__ x,
                                                   h2* __restrict__ S){
    __shared__ float2 zc[16][258];   // 33 KB

    const int p = blockIdx.x, tile = blockIdx.y, t = threadIdx.x;
    const int h0 = tile * 32;
    const float* xp = x + (size_t)p*H_*W_ + (size_t)h0*W_;

    #pragma unroll
    for (int q = 0; q < 16; ++q)
        zc[q][t] = make_float2(xp[(2*q)*W_ + t], xp[(2*q+1)*W_ + t]);
    __syncthreads();

    const int q = t >> 4, lo = t & 15;
    float2 a[16];
    // P1: FFT16 over n1, outer twiddle, transposed write
    #pragma unroll
    for (int n1 = 0; n1 < 16; ++n1) a[n1] = zc[q][lo + 16*n1];
    fft16r<false>(a);
    twchain<false>(a, lo);
    __syncthreads();
    #pragma unroll
    for (int k0 = 0; k0 < 16; ++k0) zc[q][16*lo + (k0 ^ ((lo&3)<<2))] = a[k0];
    __syncthreads();
    // P2: FFT16 over n0 -> Z[lo + 16k1]
    #pragma unroll
    for (int n0 = 0; n0 < 16; ++n0) a[n0] = zc[q][16*n0 + (lo ^ ((n0&3)<<2))];
    fft16r<false>(a);
    __syncthreads();
    #pragma unroll
    for (int k1 = 0; k1 < 16; ++k1) zc[q][lo + 16*k1] = a[k1];   // natural order
    __syncthreads();

    const float sc = 0.5f / 256.f;
    h2* Sp = S + (size_t)p*WF*H_;
    for (int idx = t; idx < WF*16; idx += 256){
        int kw = idx >> 4, qq = idx & 15;
        float2 Z = zc[qq][kw];
        float2 Y = zc[qq][(256-kw)&255];
        h4 o;
        o.x = (f16)(sc*(Z.x + Y.x));   // A.re  (row 2qq)
        o.y = (f16)(sc*(Z.y - Y.y));   // A.im
        o.z = (f16)(sc*(Z.y + Y.y));   // B.re  (row 2qq+1)
        o.w = (f16)(sc*(Y.x - Z.x));   // B.im
        *(h4*)&Sp[(size_t)kw*H_ + h0 + 2*qq] = o;
    }
}

// ---------------------------------------------------------------------------
// K2F: fused col-FFT + mag + conv(K=5) + sigmoid + inverse col-FFT.
// 16x16 register FFT; halo merged (wave0 second task). S in f16, D/Sx out f16.
// grid (P_, 9), block 256.
// ---------------------------------------------------------------------------
__global__ void __launch_bounds__(256) k2f_fused(
        const h2* __restrict__ S, h2* __restrict__ D,
        h2* __restrict__ Sx, const float* __restrict__ fw,
        const float* __restrict__ fb){
    __shared__ float2 zc[20][258];        // 41.3 KB
    __shared__ f16 mag[20][272];          // 10.9 KB
    __shared__ float cw[5];
    __shared__ float cb;

    const int p = blockIdx.x, tile = blockIdx.y, t = threadIdx.x;
    const int kw0 = tile*16;
    const int nl = min(16, WF - kw0);     // 16 (tiles 0..7) or 1 (tile 8)
    const int NL = nl + 4;
    const int c = p & (C_-1);
    const h2* Sp = S + (size_t)p*WF*H_;
    if (t < 5)  cw[t] = fw[c*5 + t];
    if (t == 5) cb = fb[c];

    for (int idx = t; idx < NL*256; idx += 256){
        int ll = idx >> 8, h = idx & 255;
        int kwa = kw0 + ll - 2;
        int phys = kwa < 0 ? kwa + WF : (kwa > 128 ? kwa - WF : kwa);
        h2 v = Sp[(size_t)phys*H_ + h];
        zc[ll][h] = make_float2((float)v.x, (float)v.y);
    }
    __syncthreads();

    const int lo = t & 15;
    const int lA = t >> 4;
    const int lB = 16 + (t >> 4);
    const bool hA = lA < NL;
    const bool hB = lB < NL;              // wave 0 only when NL=20

    float2 aA[16], aB[16];
    // ---- forward P1 ----
    if (hA){
        #pragma unroll
        for (int n1 = 0; n1 < 16; ++n1) aA[n1] = zc[lA][lo + 16*n1];
        fft16r<false>(aA); twchain<false>(aA, lo);
    }
    if (hB){
        #pragma unroll
        for (int n1 = 0; n1 < 16; ++n1) aB[n1] = zc[lB][lo + 16*n1];
        fft16r<false>(aB); twchain<false>(aB, lo);
    }
    __syncthreads();
    if (hA){
        #pragma unroll
        for (int k0 = 0; k0 < 16; ++k0) zc[lA][16*lo + (k0 ^ ((lo&3)<<2))] = aA[k0];
    }
    if (hB){
        #pragma unroll
        for (int k0 = 0; k0 < 16; ++k0) zc[lB][16*lo + (k0 ^ ((lo&3)<<2))] = aB[k0];
    }
    __syncthreads();
    // ---- forward P2 + mag ----
    if (hA){
        #pragma unroll
        for (int n0 = 0; n0 < 16; ++n0) aA[n0] = zc[lA][16*n0 + (lo ^ ((n0&3)<<2))];
        fft16r<false>(aA);
    }
    if (hB){
        #pragma unroll
        for (int n0 = 0; n0 < 16; ++n0) aB[n0] = zc[lB][16*n0 + (lo ^ ((n0&3)<<2))];
        fft16r<false>(aB);
    }
    __syncthreads();
    if (hA){
        #pragma unroll
        for (int k1 = 0; k1 < 16; ++k1){
            zc[lA][lo + 16*k1] = aA[k1];
            mag[lA][lo + 16*k1] = (f16)sqrtf(aA[k1].x*aA[k1].x + aA[k1].y*aA[k1].y);
        }
    }
    if (hB){
        #pragma unroll
        for (int k1 = 0; k1 < 16; ++k1){
            zc[lB][lo + 16*k1] = aB[k1];
            mag[lB][lo + 16*k1] = (f16)sqrtf(aB[k1].x*aB[k1].x + aB[k1].y*aB[k1].y);
        }
    }
    __syncthreads();

    // ---- conv(K=5) + sigmoid -> weight own lines (rows 2..nl+1) ----
    for (int idx = t; idx < nl*256; idx += 256){
        int ln = idx >> 8, h = idx & 255;
        int kw = kw0 + ln;
        float acc = cb;
        #pragma unroll
        for (int d = 0; d < 5; ++d){
            int kwa = kw + d - 2;
            int L = ln + d;
            int sh = (kwa < 0) ? -1 : (kwa > 128 ? 1 : 0);
            int h2i = h + sh;
            if (h2i >= 0 && h2i < H_) acc += (float)mag[L][h2i] * cw[d];
        }
        float g = 1.f + 1.f/(1.f + __expf(-acc));
        float2 v = zc[ln+2][h];
        zc[ln+2][h] = make_float2(v.x*g, v.y*g);
    }
    __syncthreads();

    // ---- inverse (own lines) ----
    const bool hI = (t >> 4) < nl;
    const int  lI = (t >> 4) + 2;
    if (hI){
        #pragma unroll
        for (int k1 = 0; k1 < 16; ++k1) aA[k1] = zc[lI][lo + 16*k1];
        fft16r<true>(aA); twchain<true>(aA, lo);
    }
    __syncthreads();
    if (hI){
        #pragma unroll
        for (int n0 = 0; n0 < 16; ++n0) zc[lI][16*lo + (n0 ^ ((lo&3)<<2))] = aA[n0];
    }
    __syncthreads();
    if (hI){
        #pragma unroll
        for (int k0 = 0; k0 < 16; ++k0) aA[k0] = zc[lI][16*k0 + (lo ^ ((k0&3)<<2))];
        fft16r<true>(aA);
        int kw = kw0 + (t >> 4);
        h2* dst = (kw < 128) ? (D + ((size_t)p*128 + kw)*H_) : (Sx + (size_t)p*H_);
        #pragma unroll
        for (int n1 = 0; n1 < 16; ++n1){
            h2 o; o.x = (f16)aA[n1].x; o.y = (f16)aA[n1].y;
            dst[lo + 16*n1] = o;
        }
    }
}

// ---------------------------------------------------------------------------
// K5: inverse row transform (Hermitian two-for-one), 16x16 register FFT.
// Reads D/Sx (f16 pairs), writes enh (f16, plane-major). grid (P_, H_/32).
// ---------------------------------------------------------------------------
__global__ void __launch_bounds__(256) k5_irow(const h2* __restrict__ D,
                                               const h2* __restrict__ Sx,
                                               f16* __restrict__ enh){
    __shared__ float2 zc[16][258];   // 33 KB

    const int p = blockIdx.x, tile = blockIdx.y, t = threadIdx.x;
    const int h0 = tile * 32;
    const h2* Dp  = D  + (size_t)p*128*H_;
    const h2* Sxp = Sx + (size_t)p*H_;

    // pack: z[kw] = A + iB, z[256-kw] = conj(A) + i conj(B)
    for (int idx = t; idx < WF*16; idx += 256){
        int kw = idx >> 4, qq = idx & 15;
        const h2* src = (kw < 128) ? (Dp + (size_t)kw*H_) : Sxp;
        h4 ab = *(const h4*)&src[h0 + 2*qq];   // A=(x,y) B=(z,w)
        float Ar = (float)ab.x, Ai = (float)ab.y;
        float Br = (float)ab.z, Bi = (float)ab.w;
        zc[qq][kw] = make_float2(Ar - Bi, Ai + Br);
        if (kw > 0 && kw < 128)
            zc[qq][256-kw] = make_float2(Ar + Bi, Br - Ai);
    }
    __syncthreads();

    const int q = t >> 4, lo = t & 15;
    float2 a[16];
    // P1: IFFT16 over k1 + conj outer twiddle + transposed write
    #pragma unroll
    for (int k1 = 0; k1 < 16; ++k1) a[k1] = zc[q][lo + 16*k1];
    fft16r<true>(a);
    twchain<true>(a, lo);
    __syncthreads();
    #pragma unroll
    for (int n0 = 0; n0 < 16; ++n0) zc[q][16*lo + (n0 ^ ((lo&3)<<2))] = a[n0];
    __syncthreads();
    // P2: IFFT16 over k0 -> x[lo + 16n1]
    #pragma unroll
    for (int k0 = 0; k0 < 16; ++k0) a[k0] = zc[q][16*k0 + (lo ^ ((k0&3)<<2))];
    fft16r<true>(a);
    __syncthreads();
    #pragma unroll
    for (int n1 = 0; n1 < 16; ++n1) zc[q][lo + 16*n1] = a[n1];   // natural order
    __syncthreads();

    const float inv = 1.f / 256.f;
    f16* ep = enh + (size_t)p*H_*W_ + (size_t)h0*W_;
    #pragma unroll
    for (int qq = 0; qq < 16; ++qq){
        float2 v = zc[qq][t];
        ep[(2*qq)*W_ + t]   = (f16)(v.x * inv);
        ep[(2*qq+1)*W_ + t] = (f16)(v.y * inv);
    }
}

// ---------------------------------------------------------------------------
// K6: out = x + scale * (mix_w @ enh). enh f16, accum f32.
// grid (B_, 256), block 256.
// ---------------------------------------------------------------------------
__global__ void k6_mix(const float* __restrict__ x, const float* __restrict__ mixw,
                       const float* __restrict__ scale, const f16* __restrict__ enh,
                       float* __restrict__ out){
    __shared__ float Ml[64*64];

    const int b = blockIdx.x, pt = blockIdx.y, t = threadIdx.x;
    const int pix = pt * 256 + t;
    float* op = out + (size_t)b*C_*H_*W_;
    const float* xp = x + (size_t)b*C_*H_*W_;
    const f16* ep = enh + (size_t)b*C_*H_*W_;

    for (int idx = t; idx < 64*64; idx += 256){
        int c = idx >> 6, o = idx & 63;
        Ml[idx] = mixw[o*64 + c];
    }
    __syncthreads();

    float acc[64];
    #pragma unroll
    for (int o = 0; o < 64; ++o) acc[o] = 0.f;

    for (int c = 0; c < 64; ++c){
        float v = (float)ep[(size_t)c*H_*W_ + pix];
        const float4* Mr = (const float4*)&Ml[c*64];
        #pragma unroll
        for (int o4 = 0; o4 < 16; ++o4){
            float4 m = Mr[o4];
            acc[o4*4+0] += m.x * v;
            acc[o4*4+1] += m.y * v;
            acc[o4*4+2] += m.z * v;
            acc[o4*4+3] += m.w * v;
        }
    }
    const float sc = scale[0];
    #pragma unroll
    for (int o = 0; o < 64; ++o){
        size_t ix = (size_t)o*H_*W_ + pix;
        op[ix] = xp[ix] + sc * acc[o];
    }
}

// ---------------------------------------------------------------------------
extern "C" void kernel_launch(void* const* d_in, const int* in_sizes, int n_in,
                              void* d_out, int out_size, void* d_ws, size_t ws_size,
                              hipStream_t stream){
    const float* x    = (const float*)d_in[0];
    const float* fw   = (const float*)d_in[1];
    const float* fb   = (const float*)d_in[2];
    const float* mixw = (const float*)d_in[3];
    const float* scal = (const float*)d_in[4];
    float* out = (float*)d_out;

    // ws: S (h2, P*WF*H = 67.7MB) + Sx (h2, P*H = 0.5MB).
    // enh (f16, 64MB) reuses the S region after k2f is done.
    h2* S   = (h2*)d_ws;
    h2* Sx  = (h2*)((char*)d_ws + (size_t)P_*WF*H_*sizeof(h2));
    f16* enh = (f16*)d_ws;
    // D (h2, 67MB) lives in d_out during the middle of the pipeline.
    h2* Dmid = (h2*)out;

    dim3 blk(256);
    k1_row_rfft <<<dim3(P_, H_/32), blk, 0, stream>>>(x, S);
    k2f_fused   <<<dim3(P_, 9),     blk, 0, stream>>>(S, Dmid, Sx, fw, fb);
    k5_irow     <<<dim3(P_, H_/32), blk, 0, stream>>>(Dmid, Sx, enh);
    k6_mix      <<<dim3(B_, 256),   blk, 0, stream>>>(x, mixw, scal, enh, out);
}

// Round 12
// 274.775 us; speedup vs baseline: 1.9617x; 1.0754x over previous
//
#include <hip/hip_runtime.h>
#include <math.h>

#define B_ 8
#define C_ 64
#define H_ 256
#define W_ 256
#define WF 129
#define P_ (B_*C_)      // 512 planes
#define PI_F 3.14159265358979323846f

typedef _Float16 f16;
struct h2 { f16 x, y; };          // 4 B
struct h4 { f16 x, y, z, w; };    // 8 B

__device__ __forceinline__ float2 cmulf(float2 a, float2 w){
    return make_float2(a.x*w.x - a.y*w.y, a.x*w.y + a.y*w.x);
}
__device__ __forceinline__ float2 cmulK(float2 a, float wr, float wi){
    return make_float2(a.x*wr - a.y*wi, a.x*wi + a.y*wr);
}
// forward DFT4 butterfly (W4 = -i rotation)
__device__ __forceinline__ void bf4f(float2 u0, float2 u1, float2 u2, float2 u3,
                                     float2& y0, float2& y1, float2& y2, float2& y3){
    float2 P = make_float2(u0.x+u2.x, u0.y+u2.y);
    float2 M = make_float2(u0.x-u2.x, u0.y-u2.y);
    float2 Q = make_float2(u1.x+u3.x, u1.y+u3.y);
    float2 R = make_float2(u1.x-u3.x, u1.y-u3.y);
    y0 = make_float2(P.x+Q.x, P.y+Q.y);
    y2 = make_float2(P.x-Q.x, P.y-Q.y);
    y1 = make_float2(M.x+R.y, M.y-R.x);   // M + (-i)R
    y3 = make_float2(M.x-R.y, M.y+R.x);   // M + (+i)R
}
// inverse DFT4 butterfly (+i rotation)
__device__ __forceinline__ void bf4i(float2 u0, float2 u1, float2 u2, float2 u3,
                                     float2& y0, float2& y1, float2& y2, float2& y3){
    float2 P = make_float2(u0.x+u2.x, u0.y+u2.y);
    float2 M = make_float2(u0.x-u2.x, u0.y-u2.y);
    float2 Q = make_float2(u1.x+u3.x, u1.y+u3.y);
    float2 R = make_float2(u1.x-u3.x, u1.y-u3.y);
    y0 = make_float2(P.x+Q.x, P.y+Q.y);
    y2 = make_float2(P.x-Q.x, P.y-Q.y);
    y1 = make_float2(M.x-R.y, M.y+R.x);   // M + iR
    y3 = make_float2(M.x+R.y, M.y-R.x);   // M - iR
}

// full 16-point FFT in registers; radix-4 x 2, constant W16 twiddles.
template<bool INV>
__device__ __forceinline__ void fft16r(float2* a){
    const float C1 = 0.92387953251128674f;   // cos(pi/8)
    const float S1 = 0.38268343236508978f;   // sin(pi/8)
    const float R2 = 0.70710678118654752f;
    float2 b[16];
    #pragma unroll
    for (int m0 = 0; m0 < 4; ++m0){
        float2 y0,y1,y2,y3;
        if (!INV) bf4f(a[m0], a[m0+4], a[m0+8], a[m0+12], y0,y1,y2,y3);
        else      bf4i(a[m0], a[m0+4], a[m0+8], a[m0+12], y0,y1,y2,y3);
        b[m0*4+0]=y0; b[m0*4+1]=y1; b[m0*4+2]=y2; b[m0*4+3]=y3;
    }
    const float sg = INV ? 1.f : -1.f;       // W16^k = (cos, sg*sin)
    b[5]  = cmulK(b[5],  C1,  sg*S1);
    b[6]  = cmulK(b[6],  R2,  sg*R2);
    b[7]  = cmulK(b[7],  S1,  sg*C1);
    b[9]  = cmulK(b[9],  R2,  sg*R2);
    b[10] = cmulK(b[10], 0.f, sg*1.f);
    b[11] = cmulK(b[11], -R2, sg*R2);
    b[13] = cmulK(b[13], S1,  sg*C1);
    b[14] = cmulK(b[14], -R2, sg*R2);
    b[15] = cmulK(b[15], -C1, -sg*S1);
    #pragma unroll
    for (int r0 = 0; r0 < 4; ++r0){
        float2 y0,y1,y2,y3;
        if (!INV) bf4f(b[r0], b[4+r0], b[8+r0], b[12+r0], y0,y1,y2,y3);
        else      bf4i(b[r0], b[4+r0], b[8+r0], b[12+r0], y0,y1,y2,y3);
        a[r0]    = y0;
        a[r0+4]  = y1;
        a[r0+8]  = y2;
        a[r0+12] = y3;
    }
}

// outer twiddle chain: a[k] *= W256^{±lo*k}
template<bool INV>
__device__ __forceinline__ void twchain(float2* a, int lo){
    float sv, cv; sincosf((INV ? 2.f : -2.f)*PI_F*(float)lo/256.f, &sv, &cv);
    float2 wst = make_float2(cv, sv), w = make_float2(1.f, 0.f);
    #pragma unroll
    for (int k = 1; k < 16; ++k){ w = cmulf(w, wst); a[k] = cmulf(a[k], w); }
}

// ---------------------------------------------------------------------------
// K1: row rfft (two-for-one), 16x16 register FFT. grid (P_, H_/32), block 256.
// Writes S[p][kw][h] as f16 pairs (A,B packed as h4), folds ortho 1/256.
// ---------------------------------------------------------------------------
__global__ void __launch_bounds__(256) k1_row_rfft(const float* __restrict__ x,
                                                   h2* __restrict__ S){
    __shared__ float2 zc[16][258];   // 33 KB

    const int p = blockIdx.x, tile = blockIdx.y, t = threadIdx.x;
    const int h0 = tile * 32;
    const float* xp = x + (size_t)p*H_*W_ + (size_t)h0*W_;

    #pragma unroll
    for (int q = 0; q < 16; ++q)
        zc[q][t] = make_float2(xp[(2*q)*W_ + t], xp[(2*q+1)*W_ + t]);
    __syncthreads();

    const int q = t >> 4, lo = t & 15;
    float2 a[16];
    // P1: FFT16 over n1, outer twiddle, transposed write
    #pragma unroll
    for (int n1 = 0; n1 < 16; ++n1) a[n1] = zc[q][lo + 16*n1];
    fft16r<false>(a);
    twchain<false>(a, lo);
    __syncthreads();
    #pragma unroll
    for (int k0 = 0; k0 < 16; ++k0) zc[q][16*lo + (k0 ^ ((lo&3)<<2))] = a[k0];
    __syncthreads();
    // P2: FFT16 over n0 -> Z[lo + 16k1]
    #pragma unroll
    for (int n0 = 0; n0 < 16; ++n0) a[n0] = zc[q][16*n0 + (lo ^ ((n0&3)<<2))];
    fft16r<false>(a);
    __syncthreads();
    #pragma unroll
    for (int k1 = 0; k1 < 16; ++k1) zc[q][lo + 16*k1] = a[k1];   // natural order
    __syncthreads();

    const float sc = 0.5f / 256.f;
    h2* Sp = S + (size_t)p*WF*H_;
    for (int idx = t; idx < WF*16; idx += 256){
        int kw = idx >> 4, qq = idx & 15;
        float2 Z = zc[qq][kw];
        float2 Y = zc[qq][(256-kw)&255];
        h4 o;
        o.x = (f16)(sc*(Z.x + Y.x));   // A.re  (row 2qq)
        o.y = (f16)(sc*(Z.y - Y.y));   // A.im
        o.z = (f16)(sc*(Z.y + Y.y));   // B.re  (row 2qq+1)
        o.w = (f16)(sc*(Y.x - Z.x));   // B.im
        *(h4*)&Sp[(size_t)kw*H_ + h0 + 2*qq] = o;
    }
}

// ---------------------------------------------------------------------------
// K2F: fused col-FFT + mag + conv(K=5) + sigmoid + inverse col-FFT.
// 11 tiles x (12 own + 4 halo) = 16 lines = exactly 1 FFT task per thread
// per phase (balanced). Spectrum register-carried through conv.
// 5 barriers. Reads S (f16); writes kw<128 -> D (d_out), kw==128 -> Sx.
// grid (P_, 11), block 256.
// ---------------------------------------------------------------------------
__global__ void __launch_bounds__(256) k2f_fused(
        const h2* __restrict__ S, h2* __restrict__ D,
        h2* __restrict__ Sx, const float* __restrict__ fw,
        const float* __restrict__ fb){
    __shared__ float2 zc[16][258];        // 33 KB
    __shared__ f16 mag[16][272];          // 8.7 KB
    __shared__ float cw[5];
    __shared__ float cb;

    const int p = blockIdx.x, tile = blockIdx.y, t = threadIdx.x;
    const int kw0 = tile*12;
    const int nl = min(12, WF - kw0);     // 12 (tiles 0..9) or 9 (tile 10)
    const int NL = nl + 4;                // own + 4 halo lines (<=16)
    const int c = p & (C_-1);
    const h2* Sp = S + (size_t)p*WF*H_;
    if (t < 5)  cw[t] = fw[c*5 + t];
    if (t == 5) cb = fb[c];

    // load NL lines (vectorized h4 = 2 complex): row ll <-> kwa = kw0+ll-2
    for (int idx = t; idx < NL*128; idx += 256){
        int ll = idx >> 7, hh = (idx & 127) << 1;
        int kwa = kw0 + ll - 2;
        int phys = kwa < 0 ? kwa + WF : (kwa > 128 ? kwa - WF : kwa);
        h4 v = *(const h4*)&Sp[(size_t)phys*H_ + hh];
        zc[ll][hh]   = make_float2((float)v.x, (float)v.y);
        zc[ll][hh+1] = make_float2((float)v.z, (float)v.w);
    }
    __syncthreads();

    const int lo = t & 15;
    const int lA = t >> 4;                // 0..15; row lA holds kw = kw0+lA-2
    const bool act = lA < NL;

    float2 aA[16];
    // ---- forward P1: FFT16 over n1 + outer twiddle + transposed write ----
    if (act){
        #pragma unroll
        for (int n1 = 0; n1 < 16; ++n1) aA[n1] = zc[lA][lo + 16*n1];
        fft16r<false>(aA); twchain<false>(aA, lo);
    }
    __syncthreads();
    if (act){
        #pragma unroll
        for (int k0 = 0; k0 < 16; ++k0) zc[lA][16*lo + (k0 ^ ((lo&3)<<2))] = aA[k0];
    }
    __syncthreads();
    // ---- forward P2: FFT16 over n0 -> spectrum stays in regs; write mag ----
    if (act){
        #pragma unroll
        for (int n0 = 0; n0 < 16; ++n0) aA[n0] = zc[lA][16*n0 + (lo ^ ((n0&3)<<2))];
        fft16r<false>(aA);
        #pragma unroll
        for (int k1 = 0; k1 < 16; ++k1)
            mag[lA][lo + 16*k1] = (f16)sqrtf(aA[k1].x*aA[k1].x + aA[k1].y*aA[k1].y);
    }
    __syncthreads();   // mag ready; all zc reads of fwd P2 complete

    // ---- conv(K=5) + sigmoid on regs + inverse P1 on regs ----
    const bool own = act && (lA >= 2) && (lA <= nl + 1);
    if (own){
        const int kw = kw0 + lA - 2;
        int shv[5];
        #pragma unroll
        for (int d = 0; d < 5; ++d){
            int kwa = kw + d - 2;
            shv[d] = (kwa < 0) ? -1 : (kwa > 128 ? 1 : 0);
        }
        #pragma unroll
        for (int k1 = 0; k1 < 16; ++k1){
            int h = lo + 16*k1;
            float acc = cb;
            #pragma unroll
            for (int d = 0; d < 5; ++d){
                int h2i = h + shv[d];
                if (h2i >= 0 && h2i < H_) acc += (float)mag[lA-2+d][h2i] * cw[d];
            }
            float g = 1.f + 1.f/(1.f + __expf(-acc));
            aA[k1] = make_float2(aA[k1].x*g, aA[k1].y*g);
        }
        // inverse P1 directly on the register spectrum
        fft16r<true>(aA); twchain<true>(aA, lo);
    }
    __syncthreads();   // order inv-P1 writes after all fwd-P2 zc reads
    if (own){
        #pragma unroll
        for (int n0 = 0; n0 < 16; ++n0)
            zc[lA][16*lo + (n0 ^ ((lo&3)<<2))] = aA[n0];   // FIXED: (lo&3), not (n0&3)
    }
    __syncthreads();
    // ---- inverse P2: FFT16 over k0 -> time domain, store f16 to global ----
    const bool hI = (t >> 4) < nl;
    if (hI){
        const int lI = (t >> 4) + 2;
        #pragma unroll
        for (int k0 = 0; k0 < 16; ++k0) aA[k0] = zc[lI][16*k0 + (lo ^ ((k0&3)<<2))];
        fft16r<true>(aA);
        int kw = kw0 + (t >> 4);
        h2* dst = (kw < 128) ? (D + ((size_t)p*128 + kw)*H_) : (Sx + (size_t)p*H_);
        #pragma unroll
        for (int n1 = 0; n1 < 16; ++n1){
            h2 o; o.x = (f16)aA[n1].x; o.y = (f16)aA[n1].y;
            dst[lo + 16*n1] = o;
        }
    }
}

// ---------------------------------------------------------------------------
// K5: inverse row transform (Hermitian two-for-one), 16x16 register FFT.
// Reads D/Sx (f16 pairs), writes enh (f16, plane-major). grid (P_, H_/32).
// ---------------------------------------------------------------------------
__global__ void __launch_bounds__(256) k5_irow(const h2* __restrict__ D,
                                               const h2* __restrict__ Sx,
                                               f16* __restrict__ enh){
    __shared__ float2 zc[16][258];   // 33 KB

    const int p = blockIdx.x, tile = blockIdx.y, t = threadIdx.x;
    const int h0 = tile * 32;
    const h2* Dp  = D  + (size_t)p*128*H_;
    const h2* Sxp = Sx + (size_t)p*H_;

    // pack: z[kw] = A + iB, z[256-kw] = conj(A) + i conj(B)
    for (int idx = t; idx < WF*16; idx += 256){
        int kw = idx >> 4, qq = idx & 15;
        const h2* src = (kw < 128) ? (Dp + (size_t)kw*H_) : Sxp;
        h4 ab = *(const h4*)&src[h0 + 2*qq];   // A=(x,y) B=(z,w)
        float Ar = (float)ab.x, Ai = (float)ab.y;
        float Br = (float)ab.z, Bi = (float)ab.w;
        zc[qq][kw] = make_float2(Ar - Bi, Ai + Br);
        if (kw > 0 && kw < 128)
            zc[qq][256-kw] = make_float2(Ar + Bi, Br - Ai);
    }
    __syncthreads();

    const int q = t >> 4, lo = t & 15;
    float2 a[16];
    // P1: IFFT16 over k1 + conj outer twiddle + transposed write
    #pragma unroll
    for (int k1 = 0; k1 < 16; ++k1) a[k1] = zc[q][lo + 16*k1];
    fft16r<true>(a);
    twchain<true>(a, lo);
    __syncthreads();
    #pragma unroll
    for (int n0 = 0; n0 < 16; ++n0) zc[q][16*lo + (n0 ^ ((lo&3)<<2))] = a[n0];
    __syncthreads();
    // P2: IFFT16 over k0 -> x[lo + 16n1]
    #pragma unroll
    for (int k0 = 0; k0 < 16; ++k0) a[k0] = zc[q][16*k0 + (lo ^ ((k0&3)<<2))];
    fft16r<true>(a);
    __syncthreads();
    #pragma unroll
    for (int n1 = 0; n1 < 16; ++n1) zc[q][lo + 16*n1] = a[n1];   // natural order
    __syncthreads();

    const float inv = 1.f / 256.f;
    f16* ep = enh + (size_t)p*H_*W_ + (size_t)h0*W_;
    #pragma unroll
    for (int qq = 0; qq < 16; ++qq){
        float2 v = zc[qq][t];
        ep[(2*qq)*W_ + t]   = (f16)(v.x * inv);
        ep[(2*qq+1)*W_ + t] = (f16)(v.y * inv);
    }
}

// ---------------------------------------------------------------------------
// K6: out = x + scale * (mix_w @ enh). enh f16, accum f32.
// ---------------------------------------------------------------------------
__global__ void k6_mix(const float* __restrict__ x, const float* __restrict__ mixw,
                       const float* __restrict__ scale, const f16* __restrict__ enh,
                       float* __restrict__ out){
    __shared__ float Ml[64*64];

    const int b = blockIdx.x, pt = blockIdx.y, t = threadIdx.x;
    const int pix = pt * 256 + t;
    float* op = out + (size_t)b*C_*H_*W_;
    const float* xp = x + (size_t)b*C_*H_*W_;
    const f16* ep = enh + (size_t)b*C_*H_*W_;

    for (int idx = t; idx < 64*64; idx += 256){
        int c = idx >> 6, o = idx & 63;
        Ml[idx] = mixw[o*64 + c];
    }
    __syncthreads();

    float acc[64];
    #pragma unroll
    for (int o = 0; o < 64; ++o) acc[o] = 0.f;

    for (int c = 0; c < 64; ++c){
        float v = (float)ep[(size_t)c*H_*W_ + pix];
        const float4* Mr = (const float4*)&Ml[c*64];
        #pragma unroll
        for (int o4 = 0; o4 < 16; ++o4){
            float4 m = Mr[o4];
            acc[o4*4+0] += m.x * v;
            acc[o4*4+1] += m.y * v;
            acc[o4*4+2] += m.z * v;
            acc[o4*4+3] += m.w * v;
        }
    }
    const float sc = scale[0];
    #pragma unroll
    for (int o = 0; o < 64; ++o){
        size_t ix = (size_t)o*H_*W_ + pix;
        op[ix] = xp[ix] + sc * acc[o];
    }
}

// ---------------------------------------------------------------------------
extern "C" void kernel_launch(void* const* d_in, const int* in_sizes, int n_in,
                              void* d_out, int out_size, void* d_ws, size_t ws_size,
                              hipStream_t stream){
    const float* x    = (const float*)d_in[0];
    const float* fw   = (const float*)d_in[1];
    const float* fb   = (const float*)d_in[2];
    const float* mixw = (const float*)d_in[3];
    const float* scal = (const float*)d_in[4];
    float* out = (float*)d_out;

    // ws: S (h2, P*WF*H = 67.7MB) + Sx (h2, P*H = 0.5MB).
    // enh (f16, 64MB) reuses the S region after k2f is done.
    h2* S   = (h2*)d_ws;
    h2* Sx  = (h2*)((char*)d_ws + (size_t)P_*WF*H_*sizeof(h2));
    f16* enh = (f16*)d_ws;
    // D (h2, 67MB) lives in d_out during the middle of the pipeline.
    h2* Dmid = (h2*)out;

    dim3 blk(256);
    k1_row_rfft <<<dim3(P_, H_/32), blk, 0, stream>>>(x, S);
    k2f_fused   <<<dim3(P_, 11),    blk, 0, stream>>>(S, Dmid, Sx, fw, fb);
    k5_irow     <<<dim3(P_, H_/32), blk, 0, stream>>>(Dmid, Sx, enh);
    k6_mix      <<<dim3(B_, 256),   blk, 0, stream>>>(x, mixw, scal, enh, out);
}

// Round 13
// 274.627 us; speedup vs baseline: 1.9628x; 1.0005x over previous
//
#include <hip/hip_runtime.h>
#include <math.h>

#define B_ 8
#define C_ 64
#define H_ 256
#define W_ 256
#define WF 129
#define P_ (B_*C_)      // 512 planes
#define PI_F 3.14159265358979323846f

typedef _Float16 f16;
struct h2 { f16 x, y; };          // 4 B
struct h4 { f16 x, y, z, w; };    // 8 B

__device__ __forceinline__ float2 cmulf(float2 a, float2 w){
    return make_float2(a.x*w.x - a.y*w.y, a.x*w.y + a.y*w.x);
}
__device__ __forceinline__ float2 cmulK(float2 a, float wr, float wi){
    return make_float2(a.x*wr - a.y*wi, a.x*wi + a.y*wr);
}
// forward DFT4 butterfly (W4 = -i rotation)
__device__ __forceinline__ void bf4f(float2 u0, float2 u1, float2 u2, float2 u3,
                                     float2& y0, float2& y1, float2& y2, float2& y3){
    float2 P = make_float2(u0.x+u2.x, u0.y+u2.y);
    float2 M = make_float2(u0.x-u2.x, u0.y-u2.y);
    float2 Q = make_float2(u1.x+u3.x, u1.y+u3.y);
    float2 R = make_float2(u1.x-u3.x, u1.y-u3.y);
    y0 = make_float2(P.x+Q.x, P.y+Q.y);
    y2 = make_float2(P.x-Q.x, P.y-Q.y);
    y1 = make_float2(M.x+R.y, M.y-R.x);   // M + (-i)R
    y3 = make_float2(M.x-R.y, M.y+R.x);   // M + (+i)R
}
// inverse DFT4 butterfly (+i rotation)
__device__ __forceinline__ void bf4i(float2 u0, float2 u1, float2 u2, float2 u3,
                                     float2& y0, float2& y1, float2& y2, float2& y3){
    float2 P = make_float2(u0.x+u2.x, u0.y+u2.y);
    float2 M = make_float2(u0.x-u2.x, u0.y-u2.y);
    float2 Q = make_float2(u1.x+u3.x, u1.y+u3.y);
    float2 R = make_float2(u1.x-u3.x, u1.y-u3.y);
    y0 = make_float2(P.x+Q.x, P.y+Q.y);
    y2 = make_float2(P.x-Q.x, P.y-Q.y);
    y1 = make_float2(M.x-R.y, M.y+R.x);   // M + iR
    y3 = make_float2(M.x+R.y, M.y-R.x);   // M - iR
}

// full 16-point FFT in registers; radix-4 x 2, constant W16 twiddles.
template<bool INV>
__device__ __forceinline__ void fft16r(float2* a){
    const float C1 = 0.92387953251128674f;   // cos(pi/8)
    const float S1 = 0.38268343236508978f;   // sin(pi/8)
    const float R2 = 0.70710678118654752f;
    float2 b[16];
    #pragma unroll
    for (int m0 = 0; m0 < 4; ++m0){
        float2 y0,y1,y2,y3;
        if (!INV) bf4f(a[m0], a[m0+4], a[m0+8], a[m0+12], y0,y1,y2,y3);
        else      bf4i(a[m0], a[m0+4], a[m0+8], a[m0+12], y0,y1,y2,y3);
        b[m0*4+0]=y0; b[m0*4+1]=y1; b[m0*4+2]=y2; b[m0*4+3]=y3;
    }
    const float sg = INV ? 1.f : -1.f;       // W16^k = (cos, sg*sin)
    b[5]  = cmulK(b[5],  C1,  sg*S1);
    b[6]  = cmulK(b[6],  R2,  sg*R2);
    b[7]  = cmulK(b[7],  S1,  sg*C1);
    b[9]  = cmulK(b[9],  R2,  sg*R2);
    b[10] = cmulK(b[10], 0.f, sg*1.f);
    b[11] = cmulK(b[11], -R2, sg*R2);
    b[13] = cmulK(b[13], S1,  sg*C1);
    b[14] = cmulK(b[14], -R2, sg*R2);
    b[15] = cmulK(b[15], -C1, -sg*S1);
    #pragma unroll
    for (int r0 = 0; r0 < 4; ++r0){
        float2 y0,y1,y2,y3;
        if (!INV) bf4f(b[r0], b[4+r0], b[8+r0], b[12+r0], y0,y1,y2,y3);
        else      bf4i(b[r0], b[4+r0], b[8+r0], b[12+r0], y0,y1,y2,y3);
        a[r0]    = y0;
        a[r0+4]  = y1;
        a[r0+8]  = y2;
        a[r0+12] = y3;
    }
}

// outer twiddle chain: a[k] *= W256^{±lo*k}
template<bool INV>
__device__ __forceinline__ void twchain(float2* a, int lo){
    float sv, cv; sincosf((INV ? 2.f : -2.f)*PI_F*(float)lo/256.f, &sv, &cv);
    float2 wst = make_float2(cv, sv), w = make_float2(1.f, 0.f);
    #pragma unroll
    for (int k = 1; k < 16; ++k){ w = cmulf(w, wst); a[k] = cmulf(a[k], w); }
}

// ---------------------------------------------------------------------------
// K1: row rfft (two-for-one), 16x16 register FFT. grid (P_, H_/32), block 256.
// Writes S[p][kw][h] as f16 pairs (A,B packed as h4), folds ortho 1/256.
// (unchanged R12)
// ---------------------------------------------------------------------------
__global__ void __launch_bounds__(256) k1_row_rfft(const float* __restrict__ x,
                                                   h2* __restrict__ S){
    __shared__ float2 zc[16][258];   // 33 KB

    const int p = blockIdx.x, tile = blockIdx.y, t = threadIdx.x;
    const int h0 = tile * 32;
    const float* xp = x + (size_t)p*H_*W_ + (size_t)h0*W_;

    #pragma unroll
    for (int q = 0; q < 16; ++q)
        zc[q][t] = make_float2(xp[(2*q)*W_ + t], xp[(2*q+1)*W_ + t]);
    __syncthreads();

    const int q = t >> 4, lo = t & 15;
    float2 a[16];
    // P1: FFT16 over n1, outer twiddle, transposed write
    #pragma unroll
    for (int n1 = 0; n1 < 16; ++n1) a[n1] = zc[q][lo + 16*n1];
    fft16r<false>(a);
    twchain<false>(a, lo);
    __syncthreads();
    #pragma unroll
    for (int k0 = 0; k0 < 16; ++k0) zc[q][16*lo + (k0 ^ ((lo&3)<<2))] = a[k0];
    __syncthreads();
    // P2: FFT16 over n0 -> Z[lo + 16k1]
    #pragma unroll
    for (int n0 = 0; n0 < 16; ++n0) a[n0] = zc[q][16*n0 + (lo ^ ((n0&3)<<2))];
    fft16r<false>(a);
    __syncthreads();
    #pragma unroll
    for (int k1 = 0; k1 < 16; ++k1) zc[q][lo + 16*k1] = a[k1];   // natural order
    __syncthreads();

    const float sc = 0.5f / 256.f;
    h2* Sp = S + (size_t)p*WF*H_;
    for (int idx = t; idx < WF*16; idx += 256){
        int kw = idx >> 4, qq = idx & 15;
        float2 Z = zc[qq][kw];
        float2 Y = zc[qq][(256-kw)&255];
        h4 o;
        o.x = (f16)(sc*(Z.x + Y.x));   // A.re  (row 2qq)
        o.y = (f16)(sc*(Z.y - Y.y));   // A.im
        o.z = (f16)(sc*(Z.y + Y.y));   // B.re  (row 2qq+1)
        o.w = (f16)(sc*(Y.x - Z.x));   // B.im
        *(h4*)&Sp[(size_t)kw*H_ + h0 + 2*qq] = o;
    }
}

// ---------------------------------------------------------------------------
// K2F: fused col-FFT + mag + conv(K=5) + sigmoid + inverse col-FFT.
// 11 tiles x (12 own + 4 halo); spectrum register-carried through conv.
// (unchanged R12)
// ---------------------------------------------------------------------------
__global__ void __launch_bounds__(256) k2f_fused(
        const h2* __restrict__ S, h2* __restrict__ D,
        h2* __restrict__ Sx, const float* __restrict__ fw,
        const float* __restrict__ fb){
    __shared__ float2 zc[16][258];        // 33 KB
    __shared__ f16 mag[16][272];          // 8.7 KB
    __shared__ float cw[5];
    __shared__ float cb;

    const int p = blockIdx.x, tile = blockIdx.y, t = threadIdx.x;
    const int kw0 = tile*12;
    const int nl = min(12, WF - kw0);     // 12 (tiles 0..9) or 9 (tile 10)
    const int NL = nl + 4;                // own + 4 halo lines (<=16)
    const int c = p & (C_-1);
    const h2* Sp = S + (size_t)p*WF*H_;
    if (t < 5)  cw[t] = fw[c*5 + t];
    if (t == 5) cb = fb[c];

    // load NL lines (vectorized h4 = 2 complex): row ll <-> kwa = kw0+ll-2
    for (int idx = t; idx < NL*128; idx += 256){
        int ll = idx >> 7, hh = (idx & 127) << 1;
        int kwa = kw0 + ll - 2;
        int phys = kwa < 0 ? kwa + WF : (kwa > 128 ? kwa - WF : kwa);
        h4 v = *(const h4*)&Sp[(size_t)phys*H_ + hh];
        zc[ll][hh]   = make_float2((float)v.x, (float)v.y);
        zc[ll][hh+1] = make_float2((float)v.z, (float)v.w);
    }
    __syncthreads();

    const int lo = t & 15;
    const int lA = t >> 4;                // 0..15; row lA holds kw = kw0+lA-2
    const bool act = lA < NL;

    float2 aA[16];
    // ---- forward P1: FFT16 over n1 + outer twiddle + transposed write ----
    if (act){
        #pragma unroll
        for (int n1 = 0; n1 < 16; ++n1) aA[n1] = zc[lA][lo + 16*n1];
        fft16r<false>(aA); twchain<false>(aA, lo);
    }
    __syncthreads();
    if (act){
        #pragma unroll
        for (int k0 = 0; k0 < 16; ++k0) zc[lA][16*lo + (k0 ^ ((lo&3)<<2))] = aA[k0];
    }
    __syncthreads();
    // ---- forward P2: FFT16 over n0 -> spectrum stays in regs; write mag ----
    if (act){
        #pragma unroll
        for (int n0 = 0; n0 < 16; ++n0) aA[n0] = zc[lA][16*n0 + (lo ^ ((n0&3)<<2))];
        fft16r<false>(aA);
        #pragma unroll
        for (int k1 = 0; k1 < 16; ++k1)
            mag[lA][lo + 16*k1] = (f16)sqrtf(aA[k1].x*aA[k1].x + aA[k1].y*aA[k1].y);
    }
    __syncthreads();   // mag ready; all zc reads of fwd P2 complete

    // ---- conv(K=5) + sigmoid on regs + inverse P1 on regs ----
    const bool own = act && (lA >= 2) && (lA <= nl + 1);
    if (own){
        const int kw = kw0 + lA - 2;
        int shv[5];
        #pragma unroll
        for (int d = 0; d < 5; ++d){
            int kwa = kw + d - 2;
            shv[d] = (kwa < 0) ? -1 : (kwa > 128 ? 1 : 0);
        }
        #pragma unroll
        for (int k1 = 0; k1 < 16; ++k1){
            int h = lo + 16*k1;
            float acc = cb;
            #pragma unroll
            for (int d = 0; d < 5; ++d){
                int h2i = h + shv[d];
                if (h2i >= 0 && h2i < H_) acc += (float)mag[lA-2+d][h2i] * cw[d];
            }
            float g = 1.f + 1.f/(1.f + __expf(-acc));
            aA[k1] = make_float2(aA[k1].x*g, aA[k1].y*g);
        }
        // inverse P1 directly on the register spectrum
        fft16r<true>(aA); twchain<true>(aA, lo);
    }
    __syncthreads();   // order inv-P1 writes after all fwd-P2 zc reads
    if (own){
        #pragma unroll
        for (int n0 = 0; n0 < 16; ++n0)
            zc[lA][16*lo + (n0 ^ ((lo&3)<<2))] = aA[n0];
    }
    __syncthreads();
    // ---- inverse P2: FFT16 over k0 -> time domain, store f16 to global ----
    const bool hI = (t >> 4) < nl;
    if (hI){
        const int lI = (t >> 4) + 2;
        #pragma unroll
        for (int k0 = 0; k0 < 16; ++k0) aA[k0] = zc[lI][16*k0 + (lo ^ ((k0&3)<<2))];
        fft16r<true>(aA);
        int kw = kw0 + (t >> 4);
        h2* dst = (kw < 128) ? (D + ((size_t)p*128 + kw)*H_) : (Sx + (size_t)p*H_);
        #pragma unroll
        for (int n1 = 0; n1 < 16; ++n1){
            h2 o; o.x = (f16)aA[n1].x; o.y = (f16)aA[n1].y;
            dst[lo + 16*n1] = o;
        }
    }
}

// ---------------------------------------------------------------------------
// K5: inverse row transform (Hermitian two-for-one), 16x16 register FFT.
// Reads D/Sx (f16 pairs), writes enh (f16, plane-major). grid (P_, H_/32).
// (unchanged R12)
// ---------------------------------------------------------------------------
__global__ void __launch_bounds__(256) k5_irow(const h2* __restrict__ D,
                                               const h2* __restrict__ Sx,
                                               f16* __restrict__ enh){
    __shared__ float2 zc[16][258];   // 33 KB

    const int p = blockIdx.x, tile = blockIdx.y, t = threadIdx.x;
    const int h0 = tile * 32;
    const h2* Dp  = D  + (size_t)p*128*H_;
    const h2* Sxp = Sx + (size_t)p*H_;

    // pack: z[kw] = A + iB, z[256-kw] = conj(A) + i conj(B)
    for (int idx = t; idx < WF*16; idx += 256){
        int kw = idx >> 4, qq = idx & 15;
        const h2* src = (kw < 128) ? (Dp + (size_t)kw*H_) : Sxp;
        h4 ab = *(const h4*)&src[h0 + 2*qq];   // A=(x,y) B=(z,w)
        float Ar = (float)ab.x, Ai = (float)ab.y;
        float Br = (float)ab.z, Bi = (float)ab.w;
        zc[qq][kw] = make_float2(Ar - Bi, Ai + Br);
        if (kw > 0 && kw < 128)
            zc[qq][256-kw] = make_float2(Ar + Bi, Br - Ai);
    }
    __syncthreads();

    const int q = t >> 4, lo = t & 15;
    float2 a[16];
    // P1: IFFT16 over k1 + conj outer twiddle + transposed write
    #pragma unroll
    for (int k1 = 0; k1 < 16; ++k1) a[k1] = zc[q][lo + 16*k1];
    fft16r<true>(a);
    twchain<true>(a, lo);
    __syncthreads();
    #pragma unroll
    for (int n0 = 0; n0 < 16; ++n0) zc[q][16*lo + (n0 ^ ((lo&3)<<2))] = a[n0];
    __syncthreads();
    // P2: IFFT16 over k0 -> x[lo + 16n1]
    #pragma unroll
    for (int k0 = 0; k0 < 16; ++k0) a[k0] = zc[q][16*k0 + (lo ^ ((k0&3)<<2))];
    fft16r<true>(a);
    __syncthreads();
    #pragma unroll
    for (int n1 = 0; n1 < 16; ++n1) zc[q][lo + 16*n1] = a[n1];   // natural order
    __syncthreads();

    const float inv = 1.f / 256.f;
    f16* ep = enh + (size_t)p*H_*W_ + (size_t)h0*W_;
    #pragma unroll
    for (int qq = 0; qq < 16; ++qq){
        float2 v = zc[qq][t];
        ep[(2*qq)*W_ + t]   = (f16)(v.x * inv);
        ep[(2*qq+1)*W_ + t] = (f16)(v.y * inv);
    }
}

// ---------------------------------------------------------------------------
// K6: out = x + scale * (mix_w @ enh). Each thread: ALL 64 outputs for TWO
// consecutive pixels -> same 16 ds_read_b128/c now feed 256 FMAs (DS count
// halves vs R12). enh h2 loads, x/out float2. grid (B_, 128), block 256.
// ---------------------------------------------------------------------------
__global__ void __launch_bounds__(256, 2) k6_mix(
        const float* __restrict__ x, const float* __restrict__ mixw,
        const float* __restrict__ scale, const f16* __restrict__ enh,
        float* __restrict__ out){
    __shared__ float Ml[64*64];        // Ml[c*64+o] = mix_w[o][c]

    const int b = blockIdx.x, pt = blockIdx.y, t = threadIdx.x;
    const int pix = (pt * 256 + t) * 2;          // two consecutive pixels
    float* op = out + (size_t)b*C_*H_*W_;
    const float* xp = x + (size_t)b*C_*H_*W_;
    const f16* ep = enh + (size_t)b*C_*H_*W_;

    for (int idx = t; idx < 64*64; idx += 256){
        int c = idx >> 6, o = idx & 63;
        Ml[idx] = mixw[o*64 + c];
    }
    __syncthreads();

    float accx[64], accy[64];
    #pragma unroll
    for (int o = 0; o < 64; ++o){ accx[o] = 0.f; accy[o] = 0.f; }

    for (int c = 0; c < 64; ++c){
        h2 e = *(const h2*)&ep[(size_t)c*H_*W_ + pix];   // 2 pixels, 4B
        float vx = (float)e.x, vy = (float)e.y;
        const float4* Mr = (const float4*)&Ml[c*64];     // broadcast rows
        #pragma unroll
        for (int o4 = 0; o4 < 16; ++o4){
            float4 m = Mr[o4];
            accx[o4*4+0] += m.x * vx;  accy[o4*4+0] += m.x * vy;
            accx[o4*4+1] += m.y * vx;  accy[o4*4+1] += m.y * vy;
            accx[o4*4+2] += m.z * vx;  accy[o4*4+2] += m.z * vy;
            accx[o4*4+3] += m.w * vx;  accy[o4*4+3] += m.w * vy;
        }
    }
    const float sc = scale[0];
    #pragma unroll
    for (int o = 0; o < 64; ++o){
        size_t ix = (size_t)o*H_*W_ + pix;
        float2 xv = *(const float2*)&xp[ix];
        float2 ov;
        ov.x = xv.x + sc * accx[o];
        ov.y = xv.y + sc * accy[o];
        *(float2*)&op[ix] = ov;
    }
}

// ---------------------------------------------------------------------------
extern "C" void kernel_launch(void* const* d_in, const int* in_sizes, int n_in,
                              void* d_out, int out_size, void* d_ws, size_t ws_size,
                              hipStream_t stream){
    const float* x    = (const float*)d_in[0];
    const float* fw   = (const float*)d_in[1];
    const float* fb   = (const float*)d_in[2];
    const float* mixw = (const float*)d_in[3];
    const float* scal = (const float*)d_in[4];
    float* out = (float*)d_out;

    // ws: S (h2, P*WF*H = 67.7MB) + Sx (h2, P*H = 0.5MB).
    // enh (f16, 64MB) reuses the S region after k2f is done.
    h2* S   = (h2*)d_ws;
    h2* Sx  = (h2*)((char*)d_ws + (size_t)P_*WF*H_*sizeof(h2));
    f16* enh = (f16*)d_ws;
    // D (h2, 67MB) lives in d_out during the middle of the pipeline.
    h2* Dmid = (h2*)out;

    dim3 blk(256);
    k1_row_rfft <<<dim3(P_, H_/32), blk, 0, stream>>>(x, S);
    k2f_fused   <<<dim3(P_, 11),    blk, 0, stream>>>(S, Dmid, Sx, fw, fb);
    k5_irow     <<<dim3(P_, H_/32), blk, 0, stream>>>(Dmid, Sx, enh);
    k6_mix      <<<dim3(B_, 128),   blk, 0, stream>>>(x, mixw, scal, enh, out);
}

// Round 14
// 264.963 us; speedup vs baseline: 2.0344x; 1.0365x over previous
//
#include <hip/hip_runtime.h>
#include <math.h>

#define B_ 8
#define C_ 64
#define H_ 256
#define W_ 256
#define WF 129
#define P_ (B_*C_)      // 512 planes
#define PI_F 3.14159265358979323846f

typedef _Float16 f16;
struct h2 { f16 x, y; };          // 4 B
struct h4 { f16 x, y, z, w; };    // 8 B

__device__ __forceinline__ float2 cmulf(float2 a, float2 w){
    return make_float2(a.x*w.x - a.y*w.y, a.x*w.y + a.y*w.x);
}
__device__ __forceinline__ float2 cmulK(float2 a, float wr, float wi){
    return make_float2(a.x*wr - a.y*wi, a.x*wi + a.y*wr);
}
// forward DFT4 butterfly (W4 = -i rotation)
__device__ __forceinline__ void bf4f(float2 u0, float2 u1, float2 u2, float2 u3,
                                     float2& y0, float2& y1, float2& y2, float2& y3){
    float2 P = make_float2(u0.x+u2.x, u0.y+u2.y);
    float2 M = make_float2(u0.x-u2.x, u0.y-u2.y);
    float2 Q = make_float2(u1.x+u3.x, u1.y+u3.y);
    float2 R = make_float2(u1.x-u3.x, u1.y-u3.y);
    y0 = make_float2(P.x+Q.x, P.y+Q.y);
    y2 = make_float2(P.x-Q.x, P.y-Q.y);
    y1 = make_float2(M.x+R.y, M.y-R.x);   // M + (-i)R
    y3 = make_float2(M.x-R.y, M.y+R.x);   // M + (+i)R
}
// inverse DFT4 butterfly (+i rotation)
__device__ __forceinline__ void bf4i(float2 u0, float2 u1, float2 u2, float2 u3,
                                     float2& y0, float2& y1, float2& y2, float2& y3){
    float2 P = make_float2(u0.x+u2.x, u0.y+u2.y);
    float2 M = make_float2(u0.x-u2.x, u0.y-u2.y);
    float2 Q = make_float2(u1.x+u3.x, u1.y+u3.y);
    float2 R = make_float2(u1.x-u3.x, u1.y-u3.y);
    y0 = make_float2(P.x+Q.x, P.y+Q.y);
    y2 = make_float2(P.x-Q.x, P.y-Q.y);
    y1 = make_float2(M.x-R.y, M.y+R.x);   // M + iR
    y3 = make_float2(M.x+R.y, M.y-R.x);   // M - iR
}

// full 16-point FFT in registers; radix-4 x 2, constant W16 twiddles.
template<bool INV>
__device__ __forceinline__ void fft16r(float2* a){
    const float C1 = 0.92387953251128674f;   // cos(pi/8)
    const float S1 = 0.38268343236508978f;   // sin(pi/8)
    const float R2 = 0.70710678118654752f;
    float2 b[16];
    #pragma unroll
    for (int m0 = 0; m0 < 4; ++m0){
        float2 y0,y1,y2,y3;
        if (!INV) bf4f(a[m0], a[m0+4], a[m0+8], a[m0+12], y0,y1,y2,y3);
        else      bf4i(a[m0], a[m0+4], a[m0+8], a[m0+12], y0,y1,y2,y3);
        b[m0*4+0]=y0; b[m0*4+1]=y1; b[m0*4+2]=y2; b[m0*4+3]=y3;
    }
    const float sg = INV ? 1.f : -1.f;       // W16^k = (cos, sg*sin)
    b[5]  = cmulK(b[5],  C1,  sg*S1);
    b[6]  = cmulK(b[6],  R2,  sg*R2);
    b[7]  = cmulK(b[7],  S1,  sg*C1);
    b[9]  = cmulK(b[9],  R2,  sg*R2);
    b[10] = cmulK(b[10], 0.f, sg*1.f);
    b[11] = cmulK(b[11], -R2, sg*R2);
    b[13] = cmulK(b[13], S1,  sg*C1);
    b[14] = cmulK(b[14], -R2, sg*R2);
    b[15] = cmulK(b[15], -C1, -sg*S1);
    #pragma unroll
    for (int r0 = 0; r0 < 4; ++r0){
        float2 y0,y1,y2,y3;
        if (!INV) bf4f(b[r0], b[4+r0], b[8+r0], b[12+r0], y0,y1,y2,y3);
        else      bf4i(b[r0], b[4+r0], b[8+r0], b[12+r0], y0,y1,y2,y3);
        a[r0]    = y0;
        a[r0+4]  = y1;
        a[r0+8]  = y2;
        a[r0+12] = y3;
    }
}

// outer twiddle chain: a[k] *= W256^{±lo*k}
template<bool INV>
__device__ __forceinline__ void twchain(float2* a, int lo){
    float sv, cv; sincosf((INV ? 2.f : -2.f)*PI_F*(float)lo/256.f, &sv, &cv);
    float2 wst = make_float2(cv, sv), w = make_float2(1.f, 0.f);
    #pragma unroll
    for (int k = 1; k < 16; ++k){ w = cmulf(w, wst); a[k] = cmulf(a[k], w); }
}

// ---------------------------------------------------------------------------
// K1: row rfft (two-for-one), 16x16 register FFT. grid (P_, H_/32), block 256.
// Writes S[p][kw][h] as f16 pairs (A,B packed as h4), folds ortho 1/256.
// (unchanged R13)
// ---------------------------------------------------------------------------
__global__ void __launch_bounds__(256) k1_row_rfft(const float* __restrict__ x,
                                                   h2* __restrict__ S){
    __shared__ float2 zc[16][258];   // 33 KB

    const int p = blockIdx.x, tile = blockIdx.y, t = threadIdx.x;
    const int h0 = tile * 32;
    const float* xp = x + (size_t)p*H_*W_ + (size_t)h0*W_;

    #pragma unroll
    for (int q = 0; q < 16; ++q)
        zc[q][t] = make_float2(xp[(2*q)*W_ + t], xp[(2*q+1)*W_ + t]);
    __syncthreads();

    const int q = t >> 4, lo = t & 15;
    float2 a[16];
    // P1: FFT16 over n1, outer twiddle, transposed write
    #pragma unroll
    for (int n1 = 0; n1 < 16; ++n1) a[n1] = zc[q][lo + 16*n1];
    fft16r<false>(a);
    twchain<false>(a, lo);
    __syncthreads();
    #pragma unroll
    for (int k0 = 0; k0 < 16; ++k0) zc[q][16*lo + (k0 ^ ((lo&3)<<2))] = a[k0];
    __syncthreads();
    // P2: FFT16 over n0 -> Z[lo + 16k1]
    #pragma unroll
    for (int n0 = 0; n0 < 16; ++n0) a[n0] = zc[q][16*n0 + (lo ^ ((n0&3)<<2))];
    fft16r<false>(a);
    __syncthreads();
    #pragma unroll
    for (int k1 = 0; k1 < 16; ++k1) zc[q][lo + 16*k1] = a[k1];   // natural order
    __syncthreads();

    const float sc = 0.5f / 256.f;
    h2* Sp = S + (size_t)p*WF*H_;
    for (int idx = t; idx < WF*16; idx += 256){
        int kw = idx >> 4, qq = idx & 15;
        float2 Z = zc[qq][kw];
        float2 Y = zc[qq][(256-kw)&255];
        h4 o;
        o.x = (f16)(sc*(Z.x + Y.x));   // A.re  (row 2qq)
        o.y = (f16)(sc*(Z.y - Y.y));   // A.im
        o.z = (f16)(sc*(Z.y + Y.y));   // B.re  (row 2qq+1)
        o.w = (f16)(sc*(Y.x - Z.x));   // B.im
        *(h4*)&Sp[(size_t)kw*H_ + h0 + 2*qq] = o;
    }
}

// ---------------------------------------------------------------------------
// K2F: fused col-FFT + mag + conv(K=5) + sigmoid + inverse col-FFT.
// 11 tiles x (12 own + 4 halo); spectrum register-carried through conv.
// (unchanged R13)
// ---------------------------------------------------------------------------
__global__ void __launch_bounds__(256) k2f_fused(
        const h2* __restrict__ S, h2* __restrict__ D,
        h2* __restrict__ Sx, const float* __restrict__ fw,
        const float* __restrict__ fb){
    __shared__ float2 zc[16][258];        // 33 KB
    __shared__ f16 mag[16][272];          // 8.7 KB
    __shared__ float cw[5];
    __shared__ float cb;

    const int p = blockIdx.x, tile = blockIdx.y, t = threadIdx.x;
    const int kw0 = tile*12;
    const int nl = min(12, WF - kw0);     // 12 (tiles 0..9) or 9 (tile 10)
    const int NL = nl + 4;                // own + 4 halo lines (<=16)
    const int c = p & (C_-1);
    const h2* Sp = S + (size_t)p*WF*H_;
    if (t < 5)  cw[t] = fw[c*5 + t];
    if (t == 5) cb = fb[c];

    // load NL lines (vectorized h4 = 2 complex): row ll <-> kwa = kw0+ll-2
    for (int idx = t; idx < NL*128; idx += 256){
        int ll = idx >> 7, hh = (idx & 127) << 1;
        int kwa = kw0 + ll - 2;
        int phys = kwa < 0 ? kwa + WF : (kwa > 128 ? kwa - WF : kwa);
        h4 v = *(const h4*)&Sp[(size_t)phys*H_ + hh];
        zc[ll][hh]   = make_float2((float)v.x, (float)v.y);
        zc[ll][hh+1] = make_float2((float)v.z, (float)v.w);
    }
    __syncthreads();

    const int lo = t & 15;
    const int lA = t >> 4;                // 0..15; row lA holds kw = kw0+lA-2
    const bool act = lA < NL;

    float2 aA[16];
    // ---- forward P1: FFT16 over n1 + outer twiddle + transposed write ----
    if (act){
        #pragma unroll
        for (int n1 = 0; n1 < 16; ++n1) aA[n1] = zc[lA][lo + 16*n1];
        fft16r<false>(aA); twchain<false>(aA, lo);
    }
    __syncthreads();
    if (act){
        #pragma unroll
        for (int k0 = 0; k0 < 16; ++k0) zc[lA][16*lo + (k0 ^ ((lo&3)<<2))] = aA[k0];
    }
    __syncthreads();
    // ---- forward P2: FFT16 over n0 -> spectrum stays in regs; write mag ----
    if (act){
        #pragma unroll
        for (int n0 = 0; n0 < 16; ++n0) aA[n0] = zc[lA][16*n0 + (lo ^ ((n0&3)<<2))];
        fft16r<false>(aA);
        #pragma unroll
        for (int k1 = 0; k1 < 16; ++k1)
            mag[lA][lo + 16*k1] = (f16)sqrtf(aA[k1].x*aA[k1].x + aA[k1].y*aA[k1].y);
    }
    __syncthreads();   // mag ready; all zc reads of fwd P2 complete

    // ---- conv(K=5) + sigmoid on regs + inverse P1 on regs ----
    const bool own = act && (lA >= 2) && (lA <= nl + 1);
    if (own){
        const int kw = kw0 + lA - 2;
        int shv[5];
        #pragma unroll
        for (int d = 0; d < 5; ++d){
            int kwa = kw + d - 2;
            shv[d] = (kwa < 0) ? -1 : (kwa > 128 ? 1 : 0);
        }
        #pragma unroll
        for (int k1 = 0; k1 < 16; ++k1){
            int h = lo + 16*k1;
            float acc = cb;
            #pragma unroll
            for (int d = 0; d < 5; ++d){
                int h2i = h + shv[d];
                if (h2i >= 0 && h2i < H_) acc += (float)mag[lA-2+d][h2i] * cw[d];
            }
            float g = 1.f + 1.f/(1.f + __expf(-acc));
            aA[k1] = make_float2(aA[k1].x*g, aA[k1].y*g);
        }
        // inverse P1 directly on the register spectrum
        fft16r<true>(aA); twchain<true>(aA, lo);
    }
    __syncthreads();   // order inv-P1 writes after all fwd-P2 zc reads
    if (own){
        #pragma unroll
        for (int n0 = 0; n0 < 16; ++n0)
            zc[lA][16*lo + (n0 ^ ((lo&3)<<2))] = aA[n0];
    }
    __syncthreads();
    // ---- inverse P2: FFT16 over k0 -> time domain, store f16 to global ----
    const bool hI = (t >> 4) < nl;
    if (hI){
        const int lI = (t >> 4) + 2;
        #pragma unroll
        for (int k0 = 0; k0 < 16; ++k0) aA[k0] = zc[lI][16*k0 + (lo ^ ((k0&3)<<2))];
        fft16r<true>(aA);
        int kw = kw0 + (t >> 4);
        h2* dst = (kw < 128) ? (D + ((size_t)p*128 + kw)*H_) : (Sx + (size_t)p*H_);
        #pragma unroll
        for (int n1 = 0; n1 < 16; ++n1){
            h2 o; o.x = (f16)aA[n1].x; o.y = (f16)aA[n1].y;
            dst[lo + 16*n1] = o;
        }
    }
}

// ---------------------------------------------------------------------------
// K5: inverse row transform (Hermitian two-for-one), 16x16 register FFT.
// Reads D/Sx (f16 pairs), writes enh (f16, plane-major). grid (P_, H_/32).
// (unchanged R13)
// ---------------------------------------------------------------------------
__global__ void __launch_bounds__(256) k5_irow(const h2* __restrict__ D,
                                               const h2* __restrict__ Sx,
                                               f16* __restrict__ enh){
    __shared__ float2 zc[16][258];   // 33 KB

    const int p = blockIdx.x, tile = blockIdx.y, t = threadIdx.x;
    const int h0 = tile * 32;
    const h2* Dp  = D  + (size_t)p*128*H_;
    const h2* Sxp = Sx + (size_t)p*H_;

    // pack: z[kw] = A + iB, z[256-kw] = conj(A) + i conj(B)
    for (int idx = t; idx < WF*16; idx += 256){
        int kw = idx >> 4, qq = idx & 15;
        const h2* src = (kw < 128) ? (Dp + (size_t)kw*H_) : Sxp;
        h4 ab = *(const h4*)&src[h0 + 2*qq];   // A=(x,y) B=(z,w)
        float Ar = (float)ab.x, Ai = (float)ab.y;
        float Br = (float)ab.z, Bi = (float)ab.w;
        zc[qq][kw] = make_float2(Ar - Bi, Ai + Br);
        if (kw > 0 && kw < 128)
            zc[qq][256-kw] = make_float2(Ar + Bi, Br - Ai);
    }
    __syncthreads();

    const int q = t >> 4, lo = t & 15;
    float2 a[16];
    // P1: IFFT16 over k1 + conj outer twiddle + transposed write
    #pragma unroll
    for (int k1 = 0; k1 < 16; ++k1) a[k1] = zc[q][lo + 16*k1];
    fft16r<true>(a);
    twchain<true>(a, lo);
    __syncthreads();
    #pragma unroll
    for (int n0 = 0; n0 < 16; ++n0) zc[q][16*lo + (n0 ^ ((lo&3)<<2))] = a[n0];
    __syncthreads();
    // P2: IFFT16 over k0 -> x[lo + 16n1]
    #pragma unroll
    for (int k0 = 0; k0 < 16; ++k0) a[k0] = zc[q][16*k0 + (lo ^ ((k0&3)<<2))];
    fft16r<true>(a);
    __syncthreads();
    #pragma unroll
    for (int n1 = 0; n1 < 16; ++n1) zc[q][lo + 16*n1] = a[n1];   // natural order
    __syncthreads();

    const float inv = 1.f / 256.f;
    f16* ep = enh + (size_t)p*H_*W_ + (size_t)h0*W_;
    #pragma unroll
    for (int qq = 0; qq < 16; ++qq){
        float2 v = zc[qq][t];
        ep[(2*qq)*W_ + t]   = (f16)(v.x * inv);
        ep[(2*qq+1)*W_ + t] = (f16)(v.y * inv);
    }
}

// ---------------------------------------------------------------------------
// K6: out = x + scale * (mix_w @ enh). Thread = 2 consecutive pixels x 32
// outputs (o-half = t>>7): per-wave DS per c = 8 ds_read_b128 (half of R12)
// with R12-class register pressure (acc=64 f32) -> occupancy preserved.
// enh read twice total (once per o-half). grid (B_, 256), block 256.
// ---------------------------------------------------------------------------
__global__ void __launch_bounds__(256) k6_mix(
        const float* __restrict__ x, const float* __restrict__ mixw,
        const float* __restrict__ scale, const f16* __restrict__ enh,
        float* __restrict__ out){
    __shared__ float Ml[64*64];        // Ml[c*64+o] = mix_w[o][c]

    const int b = blockIdx.x, pt = blockIdx.y, t = threadIdx.x;
    const int tp = t & 127;            // pixel-pair index within block tile
    const int oh = t >> 7;             // output half: o in [oh*32, oh*32+32)
    const int pix = pt*256 + tp*2;     // two consecutive pixels
    float* op = out + (size_t)b*C_*H_*W_;
    const float* xp = x + (size_t)b*C_*H_*W_;
    const f16* ep = enh + (size_t)b*C_*H_*W_;

    for (int idx = t; idx < 64*64; idx += 256){
        int c = idx >> 6, o = idx & 63;
        Ml[idx] = mixw[o*64 + c];
    }
    __syncthreads();

    float accx[32], accy[32];
    #pragma unroll
    for (int o = 0; o < 32; ++o){ accx[o] = 0.f; accy[o] = 0.f; }

    for (int c = 0; c < 64; ++c){
        h2 e = *(const h2*)&ep[(size_t)c*H_*W_ + pix];       // 2 pixels, 4B
        float vx = (float)e.x, vy = (float)e.y;
        const float4* Mr = (const float4*)&Ml[c*64 + oh*32]; // broadcast half-row
        #pragma unroll
        for (int o4 = 0; o4 < 8; ++o4){
            float4 m = Mr[o4];
            accx[o4*4+0] += m.x * vx;  accy[o4*4+0] += m.x * vy;
            accx[o4*4+1] += m.y * vx;  accy[o4*4+1] += m.y * vy;
            accx[o4*4+2] += m.z * vx;  accy[o4*4+2] += m.z * vy;
            accx[o4*4+3] += m.w * vx;  accy[o4*4+3] += m.w * vy;
        }
    }
    const float sc = scale[0];
    #pragma unroll
    for (int o = 0; o < 32; ++o){
        size_t ix = (size_t)(oh*32 + o)*H_*W_ + pix;
        float2 xv = *(const float2*)&xp[ix];
        float2 ov;
        ov.x = xv.x + sc * accx[o];
        ov.y = xv.y + sc * accy[o];
        *(float2*)&op[ix] = ov;
    }
}

// ---------------------------------------------------------------------------
extern "C" void kernel_launch(void* const* d_in, const int* in_sizes, int n_in,
                              void* d_out, int out_size, void* d_ws, size_t ws_size,
                              hipStream_t stream){
    const float* x    = (const float*)d_in[0];
    const float* fw   = (const float*)d_in[1];
    const float* fb   = (const float*)d_in[2];
    const float* mixw = (const float*)d_in[3];
    const float* scal = (const float*)d_in[4];
    float* out = (float*)d_out;

    // ws: S (h2, P*WF*H = 67.7MB) + Sx (h2, P*H = 0.5MB).
    // enh (f16, 64MB) reuses the S region after k2f is done.
    h2* S   = (h2*)d_ws;
    h2* Sx  = (h2*)((char*)d_ws + (size_t)P_*WF*H_*sizeof(h2));
    f16* enh = (f16*)d_ws;
    // D (h2, 67MB) lives in d_out during the middle of the pipeline.
    h2* Dmid = (h2*)out;

    dim3 blk(256);
    k1_row_rfft <<<dim3(P_, H_/32), blk, 0, stream>>>(x, S);
    k2f_fused   <<<dim3(P_, 11),    blk, 0, stream>>>(S, Dmid, Sx, fw, fb);
    k5_irow     <<<dim3(P_, H_/32), blk, 0, stream>>>(Dmid, Sx, enh);
    k6_mix      <<<dim3(B_, 256),   blk, 0, stream>>>(x, mixw, scal, enh, out);
}

// Round 15
// 234.621 us; speedup vs baseline: 2.2975x; 1.1293x over previous
//
#include <hip/hip_runtime.h>
#include <math.h>

#define B_ 8
#define C_ 64
#define H_ 256
#define W_ 256
#define WF 129
#define P_ (B_*C_)      // 512 planes
#define PI_F 3.14159265358979323846f

typedef _Float16 f16;
struct h2 { f16 x, y; };          // 4 B
struct h4 { f16 x, y, z, w; };    // 8 B
typedef _Float16 f16x8 __attribute__((ext_vector_type(8)));
typedef float f32x4 __attribute__((ext_vector_type(4)));

__device__ __forceinline__ float2 cmulf(float2 a, float2 w){
    return make_float2(a.x*w.x - a.y*w.y, a.x*w.y + a.y*w.x);
}
__device__ __forceinline__ float2 cmulK(float2 a, float wr, float wi){
    return make_float2(a.x*wr - a.y*wi, a.x*wi + a.y*wr);
}
// forward DFT4 butterfly (W4 = -i rotation)
__device__ __forceinline__ void bf4f(float2 u0, float2 u1, float2 u2, float2 u3,
                                     float2& y0, float2& y1, float2& y2, float2& y3){
    float2 P = make_float2(u0.x+u2.x, u0.y+u2.y);
    float2 M = make_float2(u0.x-u2.x, u0.y-u2.y);
    float2 Q = make_float2(u1.x+u3.x, u1.y+u3.y);
    float2 R = make_float2(u1.x-u3.x, u1.y-u3.y);
    y0 = make_float2(P.x+Q.x, P.y+Q.y);
    y2 = make_float2(P.x-Q.x, P.y-Q.y);
    y1 = make_float2(M.x+R.y, M.y-R.x);   // M + (-i)R
    y3 = make_float2(M.x-R.y, M.y+R.x);   // M + (+i)R
}
// inverse DFT4 butterfly (+i rotation)
__device__ __forceinline__ void bf4i(float2 u0, float2 u1, float2 u2, float2 u3,
                                     float2& y0, float2& y1, float2& y2, float2& y3){
    float2 P = make_float2(u0.x+u2.x, u0.y+u2.y);
    float2 M = make_float2(u0.x-u2.x, u0.y-u2.y);
    float2 Q = make_float2(u1.x+u3.x, u1.y+u3.y);
    float2 R = make_float2(u1.x-u3.x, u1.y-u3.y);
    y0 = make_float2(P.x+Q.x, P.y+Q.y);
    y2 = make_float2(P.x-Q.x, P.y-Q.y);
    y1 = make_float2(M.x-R.y, M.y+R.x);   // M + iR
    y3 = make_float2(M.x+R.y, M.y-R.x);   // M - iR
}

// full 16-point FFT in registers; radix-4 x 2, constant W16 twiddles.
template<bool INV>
__device__ __forceinline__ void fft16r(float2* a){
    const float C1 = 0.92387953251128674f;   // cos(pi/8)
    const float S1 = 0.38268343236508978f;   // sin(pi/8)
    const float R2 = 0.70710678118654752f;
    float2 b[16];
    #pragma unroll
    for (int m0 = 0; m0 < 4; ++m0){
        float2 y0,y1,y2,y3;
        if (!INV) bf4f(a[m0], a[m0+4], a[m0+8], a[m0+12], y0,y1,y2,y3);
        else      bf4i(a[m0], a[m0+4], a[m0+8], a[m0+12], y0,y1,y2,y3);
        b[m0*4+0]=y0; b[m0*4+1]=y1; b[m0*4+2]=y2; b[m0*4+3]=y3;
    }
    const float sg = INV ? 1.f : -1.f;       // W16^k = (cos, sg*sin)
    b[5]  = cmulK(b[5],  C1,  sg*S1);
    b[6]  = cmulK(b[6],  R2,  sg*R2);
    b[7]  = cmulK(b[7],  S1,  sg*C1);
    b[9]  = cmulK(b[9],  R2,  sg*R2);
    b[10] = cmulK(b[10], 0.f, sg*1.f);
    b[11] = cmulK(b[11], -R2, sg*R2);
    b[13] = cmulK(b[13], S1,  sg*C1);
    b[14] = cmulK(b[14], -R2, sg*R2);
    b[15] = cmulK(b[15], -C1, -sg*S1);
    #pragma unroll
    for (int r0 = 0; r0 < 4; ++r0){
        float2 y0,y1,y2,y3;
        if (!INV) bf4f(b[r0], b[4+r0], b[8+r0], b[12+r0], y0,y1,y2,y3);
        else      bf4i(b[r0], b[4+r0], b[8+r0], b[12+r0], y0,y1,y2,y3);
        a[r0]    = y0;
        a[r0+4]  = y1;
        a[r0+8]  = y2;
        a[r0+12] = y3;
    }
}

// outer twiddle chain: a[k] *= W256^{±lo*k}
template<bool INV>
__device__ __forceinline__ void twchain(float2* a, int lo){
    float sv, cv; sincosf((INV ? 2.f : -2.f)*PI_F*(float)lo/256.f, &sv, &cv);
    float2 wst = make_float2(cv, sv), w = make_float2(1.f, 0.f);
    #pragma unroll
    for (int k = 1; k < 16; ++k){ w = cmulf(w, wst); a[k] = cmulf(a[k], w); }
}

// ---------------------------------------------------------------------------
// K1: row rfft (two-for-one), 16x16 register FFT. grid (P_, H_/32), block 256.
// Writes S[p][kw][h] as f16 pairs (A,B packed as h4), folds ortho 1/256.
// (unchanged R14)
// ---------------------------------------------------------------------------
__global__ void __launch_bounds__(256) k1_row_rfft(const float* __restrict__ x,
                                                   h2* __restrict__ S){
    __shared__ float2 zc[16][258];   // 33 KB

    const int p = blockIdx.x, tile = blockIdx.y, t = threadIdx.x;
    const int h0 = tile * 32;
    const float* xp = x + (size_t)p*H_*W_ + (size_t)h0*W_;

    #pragma unroll
    for (int q = 0; q < 16; ++q)
        zc[q][t] = make_float2(xp[(2*q)*W_ + t], xp[(2*q+1)*W_ + t]);
    __syncthreads();

    const int q = t >> 4, lo = t & 15;
    float2 a[16];
    // P1: FFT16 over n1, outer twiddle, transposed write
    #pragma unroll
    for (int n1 = 0; n1 < 16; ++n1) a[n1] = zc[q][lo + 16*n1];
    fft16r<false>(a);
    twchain<false>(a, lo);
    __syncthreads();
    #pragma unroll
    for (int k0 = 0; k0 < 16; ++k0) zc[q][16*lo + (k0 ^ ((lo&3)<<2))] = a[k0];
    __syncthreads();
    // P2: FFT16 over n0 -> Z[lo + 16k1]
    #pragma unroll
    for (int n0 = 0; n0 < 16; ++n0) a[n0] = zc[q][16*n0 + (lo ^ ((n0&3)<<2))];
    fft16r<false>(a);
    __syncthreads();
    #pragma unroll
    for (int k1 = 0; k1 < 16; ++k1) zc[q][lo + 16*k1] = a[k1];   // natural order
    __syncthreads();

    const float sc = 0.5f / 256.f;
    h2* Sp = S + (size_t)p*WF*H_;
    for (int idx = t; idx < WF*16; idx += 256){
        int kw = idx >> 4, qq = idx & 15;
        float2 Z = zc[qq][kw];
        float2 Y = zc[qq][(256-kw)&255];
        h4 o;
        o.x = (f16)(sc*(Z.x + Y.x));   // A.re  (row 2qq)
        o.y = (f16)(sc*(Z.y - Y.y));   // A.im
        o.z = (f16)(sc*(Z.y + Y.y));   // B.re  (row 2qq+1)
        o.w = (f16)(sc*(Y.x - Z.x));   // B.im
        *(h4*)&Sp[(size_t)kw*H_ + h0 + 2*qq] = o;
    }
}

// ---------------------------------------------------------------------------
// K2F: fused col-FFT + mag + conv(K=5) + sigmoid + inverse col-FFT.
// 11 tiles x (12 own + 4 halo); spectrum register-carried through conv.
// (unchanged R14)
// ---------------------------------------------------------------------------
__global__ void __launch_bounds__(256) k2f_fused(
        const h2* __restrict__ S, h2* __restrict__ D,
        h2* __restrict__ Sx, const float* __restrict__ fw,
        const float* __restrict__ fb){
    __shared__ float2 zc[16][258];        // 33 KB
    __shared__ f16 mag[16][272];          // 8.7 KB
    __shared__ float cw[5];
    __shared__ float cb;

    const int p = blockIdx.x, tile = blockIdx.y, t = threadIdx.x;
    const int kw0 = tile*12;
    const int nl = min(12, WF - kw0);     // 12 (tiles 0..9) or 9 (tile 10)
    const int NL = nl + 4;                // own + 4 halo lines (<=16)
    const int c = p & (C_-1);
    const h2* Sp = S + (size_t)p*WF*H_;
    if (t < 5)  cw[t] = fw[c*5 + t];
    if (t == 5) cb = fb[c];

    // load NL lines (vectorized h4 = 2 complex): row ll <-> kwa = kw0+ll-2
    for (int idx = t; idx < NL*128; idx += 256){
        int ll = idx >> 7, hh = (idx & 127) << 1;
        int kwa = kw0 + ll - 2;
        int phys = kwa < 0 ? kwa + WF : (kwa > 128 ? kwa - WF : kwa);
        h4 v = *(const h4*)&Sp[(size_t)phys*H_ + hh];
        zc[ll][hh]   = make_float2((float)v.x, (float)v.y);
        zc[ll][hh+1] = make_float2((float)v.z, (float)v.w);
    }
    __syncthreads();

    const int lo = t & 15;
    const int lA = t >> 4;                // 0..15; row lA holds kw = kw0+lA-2
    const bool act = lA < NL;

    float2 aA[16];
    // ---- forward P1: FFT16 over n1 + outer twiddle + transposed write ----
    if (act){
        #pragma unroll
        for (int n1 = 0; n1 < 16; ++n1) aA[n1] = zc[lA][lo + 16*n1];
        fft16r<false>(aA); twchain<false>(aA, lo);
    }
    __syncthreads();
    if (act){
        #pragma unroll
        for (int k0 = 0; k0 < 16; ++k0) zc[lA][16*lo + (k0 ^ ((lo&3)<<2))] = aA[k0];
    }
    __syncthreads();
    // ---- forward P2: FFT16 over n0 -> spectrum stays in regs; write mag ----
    if (act){
        #pragma unroll
        for (int n0 = 0; n0 < 16; ++n0) aA[n0] = zc[lA][16*n0 + (lo ^ ((n0&3)<<2))];
        fft16r<false>(aA);
        #pragma unroll
        for (int k1 = 0; k1 < 16; ++k1)
            mag[lA][lo + 16*k1] = (f16)sqrtf(aA[k1].x*aA[k1].x + aA[k1].y*aA[k1].y);
    }
    __syncthreads();   // mag ready; all zc reads of fwd P2 complete

    // ---- conv(K=5) + sigmoid on regs + inverse P1 on regs ----
    const bool own = act && (lA >= 2) && (lA <= nl + 1);
    if (own){
        const int kw = kw0 + lA - 2;
        int shv[5];
        #pragma unroll
        for (int d = 0; d < 5; ++d){
            int kwa = kw + d - 2;
            shv[d] = (kwa < 0) ? -1 : (kwa > 128 ? 1 : 0);
        }
        #pragma unroll
        for (int k1 = 0; k1 < 16; ++k1){
            int h = lo + 16*k1;
            float acc = cb;
            #pragma unroll
            for (int d = 0; d < 5; ++d){
                int h2i = h + shv[d];
                if (h2i >= 0 && h2i < H_) acc += (float)mag[lA-2+d][h2i] * cw[d];
            }
            float g = 1.f + 1.f/(1.f + __expf(-acc));
            aA[k1] = make_float2(aA[k1].x*g, aA[k1].y*g);
        }
        // inverse P1 directly on the register spectrum
        fft16r<true>(aA); twchain<true>(aA, lo);
    }
    __syncthreads();   // order inv-P1 writes after all fwd-P2 zc reads
    if (own){
        #pragma unroll
        for (int n0 = 0; n0 < 16; ++n0)
            zc[lA][16*lo + (n0 ^ ((lo&3)<<2))] = aA[n0];
    }
    __syncthreads();
    // ---- inverse P2: FFT16 over k0 -> time domain, store f16 to global ----
    const bool hI = (t >> 4) < nl;
    if (hI){
        const int lI = (t >> 4) + 2;
        #pragma unroll
        for (int k0 = 0; k0 < 16; ++k0) aA[k0] = zc[lI][16*k0 + (lo ^ ((k0&3)<<2))];
        fft16r<true>(aA);
        int kw = kw0 + (t >> 4);
        h2* dst = (kw < 128) ? (D + ((size_t)p*128 + kw)*H_) : (Sx + (size_t)p*H_);
        #pragma unroll
        for (int n1 = 0; n1 < 16; ++n1){
            h2 o; o.x = (f16)aA[n1].x; o.y = (f16)aA[n1].y;
            dst[lo + 16*n1] = o;
        }
    }
}

// ---------------------------------------------------------------------------
// K5: inverse row transform (Hermitian two-for-one), 16x16 register FFT.
// Reads D/Sx (f16 pairs), writes enh (f16, plane-major). grid (P_, H_/32).
// (unchanged R14)
// ---------------------------------------------------------------------------
__global__ void __launch_bounds__(256) k5_irow(const h2* __restrict__ D,
                                               const h2* __restrict__ Sx,
                                               f16* __restrict__ enh){
    __shared__ float2 zc[16][258];   // 33 KB

    const int p = blockIdx.x, tile = blockIdx.y, t = threadIdx.x;
    const int h0 = tile * 32;
    const h2* Dp  = D  + (size_t)p*128*H_;
    const h2* Sxp = Sx + (size_t)p*H_;

    // pack: z[kw] = A + iB, z[256-kw] = conj(A) + i conj(B)
    for (int idx = t; idx < WF*16; idx += 256){
        int kw = idx >> 4, qq = idx & 15;
        const h2* src = (kw < 128) ? (Dp + (size_t)kw*H_) : Sxp;
        h4 ab = *(const h4*)&src[h0 + 2*qq];   // A=(x,y) B=(z,w)
        float Ar = (float)ab.x, Ai = (float)ab.y;
        float Br = (float)ab.z, Bi = (float)ab.w;
        zc[qq][kw] = make_float2(Ar - Bi, Ai + Br);
        if (kw > 0 && kw < 128)
            zc[qq][256-kw] = make_float2(Ar + Bi, Br - Ai);
    }
    __syncthreads();

    const int q = t >> 4, lo = t & 15;
    float2 a[16];
    // P1: IFFT16 over k1 + conj outer twiddle + transposed write
    #pragma unroll
    for (int k1 = 0; k1 < 16; ++k1) a[k1] = zc[q][lo + 16*k1];
    fft16r<true>(a);
    twchain<true>(a, lo);
    __syncthreads();
    #pragma unroll
    for (int n0 = 0; n0 < 16; ++n0) zc[q][16*lo + (n0 ^ ((lo&3)<<2))] = a[n0];
    __syncthreads();
    // P2: IFFT16 over k0 -> x[lo + 16n1]
    #pragma unroll
    for (int k0 = 0; k0 < 16; ++k0) a[k0] = zc[q][16*k0 + (lo ^ ((k0&3)<<2))];
    fft16r<true>(a);
    __syncthreads();
    #pragma unroll
    for (int n1 = 0; n1 < 16; ++n1) zc[q][lo + 16*n1] = a[n1];   // natural order
    __syncthreads();

    const float inv = 1.f / 256.f;
    f16* ep = enh + (size_t)p*H_*W_ + (size_t)h0*W_;
    #pragma unroll
    for (int qq = 0; qq < 16; ++qq){
        float2 v = zc[qq][t];
        ep[(2*qq)*W_ + t]   = (f16)(v.x * inv);
        ep[(2*qq+1)*W_ + t] = (f16)(v.y * inv);
    }
}

// ---------------------------------------------------------------------------
// K6: out = x + scale * (mix_w @ enh) via MFMA f16 16x16x32.
// Wave: 16 pixels x all 64 outputs = 4 o-tiles x 2 k-halves = 8 MFMA.
// A = mix_w (f16, staged in LDS [64][72], 16B-aligned rows, ~2-way banks);
// B = enh fragments (8 x 2B strided loads/lane); C/D per verified layout:
// col=lane&15 (pixel), row=(lane>>4)*4+reg (output). x/out coalesced.
// grid (B_, 1024), block 256 (4 waves x 16 pix = 64 pix/block).
// ---------------------------------------------------------------------------
__global__ void __launch_bounds__(256) k6_mix(
        const float* __restrict__ x, const float* __restrict__ mixw,
        const float* __restrict__ scale, const f16* __restrict__ enh,
        float* __restrict__ out){
    __shared__ f16 Ml[64][72];         // Ml[o][c], row stride 144B (16B-aligned)

    const int b = blockIdx.x, pt = blockIdx.y, t = threadIdx.x;
    float* op = out + (size_t)b*C_*H_*W_;
    const float* xp = x + (size_t)b*C_*H_*W_;
    const f16* ep = enh + (size_t)b*C_*H_*W_;

    // stage mix_w as f16 (one-time, 4096 elements)
    for (int idx = t; idx < 64*64; idx += 256){
        int o = idx >> 6, c = idx & 63;
        Ml[o][c] = (f16)mixw[idx];
    }
    __syncthreads();

    const int w  = t >> 6;             // wave 0..3
    const int l  = t & 63;             // lane
    const int lj = l & 15;             // col index: pixel-in-tile / A-row sel
    const int lk = l >> 4;             // k-group (k = kk*32 + lk*8 + j)
    const int pix = pt*64 + w*16 + lj;

    // A fragments: af[ot][kk] -> lane holds M[ot*16+lj][kk*32+lk*8 .. +8]
    f16x8 af[4][2];
    #pragma unroll
    for (int ot = 0; ot < 4; ++ot){
        #pragma unroll
        for (int kk = 0; kk < 2; ++kk)
            af[ot][kk] = *(const f16x8*)&Ml[ot*16 + lj][kk*32 + lk*8];
    }

    f32x4 acc[4];
    #pragma unroll
    for (int ot = 0; ot < 4; ++ot) acc[ot] = (f32x4){0.f, 0.f, 0.f, 0.f};

    #pragma unroll
    for (int kk = 0; kk < 2; ++kk){
        // B fragment: bf[j] = enh[c = kk*32 + lk*8 + j][pix]
        f16x8 bf;
        #pragma unroll
        for (int j = 0; j < 8; ++j)
            bf[j] = ep[(size_t)(kk*32 + lk*8 + j)*H_*W_ + pix];
        #pragma unroll
        for (int ot = 0; ot < 4; ++ot)
            acc[ot] = __builtin_amdgcn_mfma_f32_16x16x32_f16(af[ot][kk], bf, acc[ot], 0, 0, 0);
    }

    const float sc = scale[0];
    // D layout: col = lj (pixel), row = lk*4 + r (output within o-tile)
    #pragma unroll
    for (int ot = 0; ot < 4; ++ot){
        #pragma unroll
        for (int r = 0; r < 4; ++r){
            int o = ot*16 + lk*4 + r;
            size_t ix = (size_t)o*H_*W_ + pix;
            op[ix] = xp[ix] + sc * acc[ot][r];
        }
    }
}

// ---------------------------------------------------------------------------
extern "C" void kernel_launch(void* const* d_in, const int* in_sizes, int n_in,
                              void* d_out, int out_size, void* d_ws, size_t ws_size,
                              hipStream_t stream){
    const float* x    = (const float*)d_in[0];
    const float* fw   = (const float*)d_in[1];
    const float* fb   = (const float*)d_in[2];
    const float* mixw = (const float*)d_in[3];
    const float* scal = (const float*)d_in[4];
    float* out = (float*)d_out;

    // ws: S (h2, P*WF*H = 67.7MB) + Sx (h2, P*H = 0.5MB).
    // enh (f16, 64MB) reuses the S region after k2f is done.
    h2* S   = (h2*)d_ws;
    h2* Sx  = (h2*)((char*)d_ws + (size_t)P_*WF*H_*sizeof(h2));
    f16* enh = (f16*)d_ws;
    // D (h2, 67MB) lives in d_out during the middle of the pipeline.
    h2* Dmid = (h2*)out;

    dim3 blk(256);
    k1_row_rfft <<<dim3(P_, H_/32), blk, 0, stream>>>(x, S);
    k2f_fused   <<<dim3(P_, 11),    blk, 0, stream>>>(S, Dmid, Sx, fw, fb);
    k5_irow     <<<dim3(P_, H_/32), blk, 0, stream>>>(Dmid, Sx, enh);
    k6_mix      <<<dim3(B_, 1024),  blk, 0, stream>>>(x, mixw, scal, enh, out);
}

// Round 16
// 229.188 us; speedup vs baseline: 2.3519x; 1.0237x over previous
//
#include <hip/hip_runtime.h>
#include <math.h>

#define B_ 8
#define C_ 64
#define H_ 256
#define W_ 256
#define WF 129
#define P_ (B_*C_)      // 512 planes
#define PI_F 3.14159265358979323846f

typedef _Float16 f16;
struct h2 { f16 x, y; };          // 4 B
struct h4 { f16 x, y, z, w; };    // 8 B
typedef _Float16 f16x8 __attribute__((ext_vector_type(8)));
typedef float f32x4 __attribute__((ext_vector_type(4)));
// complex as packed f32 pair -> v_pk_add_f32 / v_pk_fma_f32 (VOP3P)
typedef float cf __attribute__((ext_vector_type(2)));

__device__ __forceinline__ cf cmulv(cf a, cf w){
    cf m = a.yy * w.yx;               // {a.y*w.y, a.y*w.x}
    cf ms = (cf){-m.x, m.y};          // neg_lo folds into pk op
    return a.xx * w + ms;             // {ax*wx - ay*wy, ax*wy + ay*wx}
}
// forward DFT4 butterfly (W4 = -i rotation)
__device__ __forceinline__ void bf4f(cf u0, cf u1, cf u2, cf u3,
                                     cf& y0, cf& y1, cf& y2, cf& y3){
    cf P = u0 + u2, M = u0 - u2;
    cf Q = u1 + u3, R = u1 - u3;
    cf Rr = (cf){R.y, -R.x};          // (-i)*R
    y0 = P + Q;  y2 = P - Q;
    y1 = M + Rr; y3 = M - Rr;
}
// inverse DFT4 butterfly (+i rotation)
__device__ __forceinline__ void bf4i(cf u0, cf u1, cf u2, cf u3,
                                     cf& y0, cf& y1, cf& y2, cf& y3){
    cf P = u0 + u2, M = u0 - u2;
    cf Q = u1 + u3, R = u1 - u3;
    cf Ri = (cf){-R.y, R.x};          // (+i)*R
    y0 = P + Q;  y2 = P - Q;
    y1 = M + Ri; y3 = M - Ri;
}

// full 16-point FFT in registers; radix-4 x 2, constant W16 twiddles.
template<bool INV>
__device__ __forceinline__ void fft16r(cf* a){
    const float C1 = 0.92387953251128674f;   // cos(pi/8)
    const float S1 = 0.38268343236508978f;   // sin(pi/8)
    const float R2 = 0.70710678118654752f;
    cf b[16];
    #pragma unroll
    for (int m0 = 0; m0 < 4; ++m0){
        cf y0,y1,y2,y3;
        if (!INV) bf4f(a[m0], a[m0+4], a[m0+8], a[m0+12], y0,y1,y2,y3);
        else      bf4i(a[m0], a[m0+4], a[m0+8], a[m0+12], y0,y1,y2,y3);
        b[m0*4+0]=y0; b[m0*4+1]=y1; b[m0*4+2]=y2; b[m0*4+3]=y3;
    }
    const float sg = INV ? 1.f : -1.f;       // W16^k = (cos, sg*sin)
    b[5]  = cmulv(b[5],  (cf){C1,  sg*S1});
    b[6]  = cmulv(b[6],  (cf){R2,  sg*R2});
    b[7]  = cmulv(b[7],  (cf){S1,  sg*C1});
    b[9]  = cmulv(b[9],  (cf){R2,  sg*R2});
    b[10] = cmulv(b[10], (cf){0.f, sg*1.f});
    b[11] = cmulv(b[11], (cf){-R2, sg*R2});
    b[13] = cmulv(b[13], (cf){S1,  sg*C1});
    b[14] = cmulv(b[14], (cf){-R2, sg*R2});
    b[15] = cmulv(b[15], (cf){-C1, -sg*S1});
    #pragma unroll
    for (int r0 = 0; r0 < 4; ++r0){
        cf y0,y1,y2,y3;
        if (!INV) bf4f(b[r0], b[4+r0], b[8+r0], b[12+r0], y0,y1,y2,y3);
        else      bf4i(b[r0], b[4+r0], b[8+r0], b[12+r0], y0,y1,y2,y3);
        a[r0]    = y0;
        a[r0+4]  = y1;
        a[r0+8]  = y2;
        a[r0+12] = y3;
    }
}

// outer twiddle chain: a[k] *= W256^{±lo*k}
template<bool INV>
__device__ __forceinline__ void twchain(cf* a, int lo){
    float ang = (INV ? 2.f : -2.f) * PI_F * (float)lo / 256.f;
    cf wst = (cf){__cosf(ang), __sinf(ang)};
    cf w = (cf){1.f, 0.f};
    #pragma unroll
    for (int k = 1; k < 16; ++k){ w = cmulv(w, wst); a[k] = cmulv(a[k], w); }
}

// ---------------------------------------------------------------------------
// K1: row rfft (two-for-one), 16x16 register FFT. grid (P_, H_/32), block 256.
// Writes S[p][kw][h] as f16 pairs (A,B packed as h4), folds ortho 1/256.
// ---------------------------------------------------------------------------
__global__ void __launch_bounds__(256) k1_row_rfft(const float* __restrict__ x,
                                                   h2* __restrict__ S){
    __shared__ cf zc[16][258];   // 33 KB

    const int p = blockIdx.x, tile = blockIdx.y, t = threadIdx.x;
    const int h0 = tile * 32;
    const float* xp = x + (size_t)p*H_*W_ + (size_t)h0*W_;

    #pragma unroll
    for (int q = 0; q < 16; ++q)
        zc[q][t] = (cf){xp[(2*q)*W_ + t], xp[(2*q+1)*W_ + t]};
    __syncthreads();

    const int q = t >> 4, lo = t & 15;
    cf a[16];
    // P1: FFT16 over n1, outer twiddle, transposed write
    #pragma unroll
    for (int n1 = 0; n1 < 16; ++n1) a[n1] = zc[q][lo + 16*n1];
    fft16r<false>(a);
    twchain<false>(a, lo);
    __syncthreads();
    #pragma unroll
    for (int k0 = 0; k0 < 16; ++k0) zc[q][16*lo + (k0 ^ ((lo&3)<<2))] = a[k0];
    __syncthreads();
    // P2: FFT16 over n0 -> Z[lo + 16k1]
    #pragma unroll
    for (int n0 = 0; n0 < 16; ++n0) a[n0] = zc[q][16*n0 + (lo ^ ((n0&3)<<2))];
    fft16r<false>(a);
    __syncthreads();
    #pragma unroll
    for (int k1 = 0; k1 < 16; ++k1) zc[q][lo + 16*k1] = a[k1];   // natural order
    __syncthreads();

    const float sc = 0.5f / 256.f;
    h2* Sp = S + (size_t)p*WF*H_;
    for (int idx = t; idx < WF*16; idx += 256){
        int kw = idx >> 4, qq = idx & 15;
        cf Z = zc[qq][kw];
        cf Y = zc[qq][(256-kw)&255];
        h4 o;
        o.x = (f16)(sc*(Z.x + Y.x));   // A.re  (row 2qq)
        o.y = (f16)(sc*(Z.y - Y.y));   // A.im
        o.z = (f16)(sc*(Z.y + Y.y));   // B.re  (row 2qq+1)
        o.w = (f16)(sc*(Y.x - Z.x));   // B.im
        *(h4*)&Sp[(size_t)kw*H_ + h0 + 2*qq] = o;
    }
}

// ---------------------------------------------------------------------------
// K2F: fused col-FFT + mag + conv(K=5) + sigmoid + inverse col-FFT.
// 11 tiles x (12 own + 4 halo); spectrum register-carried through conv.
// grid (P_, 11), block 256.
// ---------------------------------------------------------------------------
__global__ void __launch_bounds__(256) k2f_fused(
        const h2* __restrict__ S, h2* __restrict__ D,
        h2* __restrict__ Sx, const float* __restrict__ fw,
        const float* __restrict__ fb){
    __shared__ cf zc[16][258];            // 33 KB
    __shared__ f16 mag[16][272];          // 8.7 KB
    __shared__ float cw[5];
    __shared__ float cb;

    const int p = blockIdx.x, tile = blockIdx.y, t = threadIdx.x;
    const int kw0 = tile*12;
    const int nl = min(12, WF - kw0);     // 12 (tiles 0..9) or 9 (tile 10)
    const int NL = nl + 4;                // own + 4 halo lines (<=16)
    const int c = p & (C_-1);
    const h2* Sp = S + (size_t)p*WF*H_;
    if (t < 5)  cw[t] = fw[c*5 + t];
    if (t == 5) cb = fb[c];

    // load NL lines (vectorized h4 = 2 complex): row ll <-> kwa = kw0+ll-2
    for (int idx = t; idx < NL*128; idx += 256){
        int ll = idx >> 7, hh = (idx & 127) << 1;
        int kwa = kw0 + ll - 2;
        int phys = kwa < 0 ? kwa + WF : (kwa > 128 ? kwa - WF : kwa);
        h4 v = *(const h4*)&Sp[(size_t)phys*H_ + hh];
        zc[ll][hh]   = (cf){(float)v.x, (float)v.y};
        zc[ll][hh+1] = (cf){(float)v.z, (float)v.w};
    }
    __syncthreads();

    const int lo = t & 15;
    const int lA = t >> 4;                // 0..15; row lA holds kw = kw0+lA-2
    const bool act = lA < NL;

    cf aA[16];
    // ---- forward P1: FFT16 over n1 + outer twiddle + transposed write ----
    if (act){
        #pragma unroll
        for (int n1 = 0; n1 < 16; ++n1) aA[n1] = zc[lA][lo + 16*n1];
        fft16r<false>(aA); twchain<false>(aA, lo);
    }
    __syncthreads();
    if (act){
        #pragma unroll
        for (int k0 = 0; k0 < 16; ++k0) zc[lA][16*lo + (k0 ^ ((lo&3)<<2))] = aA[k0];
    }
    __syncthreads();
    // ---- forward P2: FFT16 over n0 -> spectrum stays in regs; write mag ----
    if (act){
        #pragma unroll
        for (int n0 = 0; n0 < 16; ++n0) aA[n0] = zc[lA][16*n0 + (lo ^ ((n0&3)<<2))];
        fft16r<false>(aA);
        #pragma unroll
        for (int k1 = 0; k1 < 16; ++k1)
            mag[lA][lo + 16*k1] = (f16)sqrtf(aA[k1].x*aA[k1].x + aA[k1].y*aA[k1].y);
    }
    __syncthreads();   // mag ready; all zc reads of fwd P2 complete

    // ---- conv(K=5) + sigmoid on regs + inverse P1 on regs ----
    const bool own = act && (lA >= 2) && (lA <= nl + 1);
    if (own){
        const int kw = kw0 + lA - 2;
        int shv[5];
        #pragma unroll
        for (int d = 0; d < 5; ++d){
            int kwa = kw + d - 2;
            shv[d] = (kwa < 0) ? -1 : (kwa > 128 ? 1 : 0);
        }
        #pragma unroll
        for (int k1 = 0; k1 < 16; ++k1){
            int h = lo + 16*k1;
            float acc = cb;
            #pragma unroll
            for (int d = 0; d < 5; ++d){
                int h2i = h + shv[d];
                if (h2i >= 0 && h2i < H_) acc += (float)mag[lA-2+d][h2i] * cw[d];
            }
            float g = 1.f + 1.f/(1.f + __expf(-acc));
            aA[k1] = aA[k1] * g;
        }
        // inverse P1 directly on the register spectrum
        fft16r<true>(aA); twchain<true>(aA, lo);
    }
    __syncthreads();   // order inv-P1 writes after all fwd-P2 zc reads
    if (own){
        #pragma unroll
        for (int n0 = 0; n0 < 16; ++n0)
            zc[lA][16*lo + (n0 ^ ((lo&3)<<2))] = aA[n0];
    }
    __syncthreads();
    // ---- inverse P2: FFT16 over k0 -> time domain, store f16 to global ----
    const bool hI = (t >> 4) < nl;
    if (hI){
        const int lI = (t >> 4) + 2;
        #pragma unroll
        for (int k0 = 0; k0 < 16; ++k0) aA[k0] = zc[lI][16*k0 + (lo ^ ((k0&3)<<2))];
        fft16r<true>(aA);
        int kw = kw0 + (t >> 4);
        h2* dst = (kw < 128) ? (D + ((size_t)p*128 + kw)*H_) : (Sx + (size_t)p*H_);
        #pragma unroll
        for (int n1 = 0; n1 < 16; ++n1){
            h2 o; o.x = (f16)aA[n1].x; o.y = (f16)aA[n1].y;
            dst[lo + 16*n1] = o;
        }
    }
}

// ---------------------------------------------------------------------------
// K5: inverse row transform (Hermitian two-for-one), 16x16 register FFT.
// Reads D/Sx (f16 pairs), writes enh (f16, plane-major). grid (P_, H_/32).
// ---------------------------------------------------------------------------
__global__ void __launch_bounds__(256) k5_irow(const h2* __restrict__ D,
                                               const h2* __restrict__ Sx,
                                               f16* __restrict__ enh){
    __shared__ cf zc[16][258];   // 33 KB

    const int p = blockIdx.x, tile = blockIdx.y, t = threadIdx.x;
    const int h0 = tile * 32;
    const h2* Dp  = D  + (size_t)p*128*H_;
    const h2* Sxp = Sx + (size_t)p*H_;

    // pack: z[kw] = A + iB, z[256-kw] = conj(A) + i conj(B)
    for (int idx = t; idx < WF*16; idx += 256){
        int kw = idx >> 4, qq = idx & 15;
        const h2* src = (kw < 128) ? (Dp + (size_t)kw*H_) : Sxp;
        h4 ab = *(const h4*)&src[h0 + 2*qq];   // A=(x,y) B=(z,w)
        float Ar = (float)ab.x, Ai = (float)ab.y;
        float Br = (float)ab.z, Bi = (float)ab.w;
        zc[qq][kw] = (cf){Ar - Bi, Ai + Br};
        if (kw > 0 && kw < 128)
            zc[qq][256-kw] = (cf){Ar + Bi, Br - Ai};
    }
    __syncthreads();

    const int q = t >> 4, lo = t & 15;
    cf a[16];
    // P1: IFFT16 over k1 + conj outer twiddle + transposed write
    #pragma unroll
    for (int k1 = 0; k1 < 16; ++k1) a[k1] = zc[q][lo + 16*k1];
    fft16r<true>(a);
    twchain<true>(a, lo);
    __syncthreads();
    #pragma unroll
    for (int n0 = 0; n0 < 16; ++n0) zc[q][16*lo + (n0 ^ ((lo&3)<<2))] = a[n0];
    __syncthreads();
    // P2: IFFT16 over k0 -> x[lo + 16n1]
    #pragma unroll
    for (int k0 = 0; k0 < 16; ++k0) a[k0] = zc[q][16*k0 + (lo ^ ((k0&3)<<2))];
    fft16r<true>(a);
    __syncthreads();
    #pragma unroll
    for (int n1 = 0; n1 < 16; ++n1) zc[q][lo + 16*n1] = a[n1];   // natural order
    __syncthreads();

    const float inv = 1.f / 256.f;
    f16* ep = enh + (size_t)p*H_*W_ + (size_t)h0*W_;
    #pragma unroll
    for (int qq = 0; qq < 16; ++qq){
        cf v = zc[qq][t];
        ep[(2*qq)*W_ + t]   = (f16)(v.x * inv);
        ep[(2*qq+1)*W_ + t] = (f16)(v.y * inv);
    }
}

// ---------------------------------------------------------------------------
// K6: out = x + scale * (mix_w @ enh) via MFMA f16 16x16x32. (unchanged R15)
// grid (B_, 1024), block 256 (4 waves x 16 pix = 64 pix/block).
// ---------------------------------------------------------------------------
__global__ void __launch_bounds__(256) k6_mix(
        const float* __restrict__ x, const float* __restrict__ mixw,
        const float* __restrict__ scale, const f16* __restrict__ enh,
        float* __restrict__ out){
    __shared__ f16 Ml[64][72];         // Ml[o][c], row stride 144B (16B-aligned)

    const int b = blockIdx.x, pt = blockIdx.y, t = threadIdx.x;
    float* op = out + (size_t)b*C_*H_*W_;
    const float* xp = x + (size_t)b*C_*H_*W_;
    const f16* ep = enh + (size_t)b*C_*H_*W_;

    // stage mix_w as f16 (one-time, 4096 elements)
    for (int idx = t; idx < 64*64; idx += 256){
        int o = idx >> 6, c = idx & 63;
        Ml[o][c] = (f16)mixw[idx];
    }
    __syncthreads();

    const int w  = t >> 6;             // wave 0..3
    const int l  = t & 63;             // lane
    const int lj = l & 15;             // col index: pixel-in-tile / A-row sel
    const int lk = l >> 4;             // k-group (k = kk*32 + lk*8 + j)
    const int pix = pt*64 + w*16 + lj;

    // A fragments: af[ot][kk] -> lane holds M[ot*16+lj][kk*32+lk*8 .. +8]
    f16x8 af[4][2];
    #pragma unroll
    for (int ot = 0; ot < 4; ++ot){
        #pragma unroll
        for (int kk = 0; kk < 2; ++kk)
            af[ot][kk] = *(const f16x8*)&Ml[ot*16 + lj][kk*32 + lk*8];
    }

    f32x4 acc[4];
    #pragma unroll
    for (int ot = 0; ot < 4; ++ot) acc[ot] = (f32x4){0.f, 0.f, 0.f, 0.f};

    #pragma unroll
    for (int kk = 0; kk < 2; ++kk){
        // B fragment: bf[j] = enh[c = kk*32 + lk*8 + j][pix]
        f16x8 bf;
        #pragma unroll
        for (int j = 0; j < 8; ++j)
            bf[j] = ep[(size_t)(kk*32 + lk*8 + j)*H_*W_ + pix];
        #pragma unroll
        for (int ot = 0; ot < 4; ++ot)
            acc[ot] = __builtin_amdgcn_mfma_f32_16x16x32_f16(af[ot][kk], bf, acc[ot], 0, 0, 0);
    }

    const float sc = scale[0];
    // D layout: col = lj (pixel), row = lk*4 + r (output within o-tile)
    #pragma unroll
    for (int ot = 0; ot < 4; ++ot){
        #pragma unroll
        for (int r = 0; r < 4; ++r){
            int o = ot*16 + lk*4 + r;
            size_t ix = (size_t)o*H_*W_ + pix;
            op[ix] = xp[ix] + sc * acc[ot][r];
        }
    }
}

// ---------------------------------------------------------------------------
extern "C" void kernel_launch(void* const* d_in, const int* in_sizes, int n_in,
                              void* d_out, int out_size, void* d_ws, size_t ws_size,
                              hipStream_t stream){
    const float* x    = (const float*)d_in[0];
    const float* fw   = (const float*)d_in[1];
    const float* fb   = (const float*)d_in[2];
    const float* mixw = (const float*)d_in[3];
    const float* scal = (const float*)d_in[4];
    float* out = (float*)d_out;

    // ws: S (h2, P*WF*H = 67.7MB) + Sx (h2, P*H = 0.5MB).
    // enh (f16, 64MB) reuses the S region after k2f is done.
    h2* S   = (h2*)d_ws;
    h2* Sx  = (h2*)((char*)d_ws + (size_t)P_*WF*H_*sizeof(h2));
    f16* enh = (f16*)d_ws;
    // D (h2, 67MB) lives in d_out during the middle of the pipeline.
    h2* Dmid = (h2*)out;

    dim3 blk(256);
    k1_row_rfft <<<dim3(P_, H_/32), blk, 0, stream>>>(x, S);
    k2f_fused   <<<dim3(P_, 11),    blk, 0, stream>>>(S, Dmid, Sx, fw, fb);
    k5_irow     <<<dim3(P_, H_/32), blk, 0, stream>>>(Dmid, Sx, enh);
    k6_mix      <<<dim3(B_, 1024),  blk, 0, stream>>>(x, mixw, scal, enh, out);
}